// Round 1
// baseline (1310.055 us; speedup 1.0000x reference)
//
#include <hip/hip_runtime.h>

namespace {
constexpr int NB = 4;      // batch
constexpr int CI = 128;    // input channels
constexpr int NP = 1024;   // points
constexpr int MM = 4096;   // N*UP
constexpr float EPSBN = 1e-5f;

// workspace offsets (in floats)
constexpr size_t OFF_BIG0 = 0;          // 4194304: dist -> P1,Q1,P2,Q2 -> A
constexpr size_t OFF_BIG1 = 4194304;    // 4194304: F0,G0,H0 -> Y1
constexpr size_t OFF_XN   = 8388608;    // 524288
constexpr size_t OFF_SQ   = 8912896;    // 4096
constexpr size_t OFF_RM   = 8916992;    // 16384
constexpr size_t OFF_Z    = 8933376;    // 16384
constexpr size_t OFF_XATT = 8949760;    // 2129920
constexpr size_t OFF_SUMS = 11079680;   // 1024
constexpr size_t OFF_ABE  = 11080704;   // 1024
constexpr size_t OFF_ABF  = 11081728;   // 64
constexpr size_t OFF_ABG  = 11081792;   // 64
constexpr size_t OFF_ABH  = 11081856;   // 260 (padded)
constexpr size_t OFF_KNN  = 11082368;   // 73728 ints
} // namespace

// ---------------- K1: normalize features, per-point sq ----------------
__global__ __launch_bounds__(256) void k_norm(const float* __restrict__ x,
                                              float* __restrict__ xn,
                                              float* __restrict__ sq) {
  int t = blockIdx.x * 256 + threadIdx.x;   // b*1024+n
  int b = t >> 10, n = t & 1023;
  const float* xb = x + (size_t)b * CI * NP + n;
  float ss = 0.f;
  #pragma unroll 4
  for (int c = 0; c < CI; ++c) { float v = xb[(size_t)c * NP]; ss += v * v; }
  float inv = 1.f / fmaxf(sqrtf(ss), 1e-12f);
  float* xo = xn + (size_t)b * CI * NP + n;
  float s2 = 0.f;
  #pragma unroll 4
  for (int c = 0; c < CI; ++c) { float v = xb[(size_t)c * NP] * inv; xo[(size_t)c * NP] = v; s2 += v * v; }
  sq[t] = s2;
}

// ---------------- K2: pairwise distance, 64x64 tiles ----------------
// grid (16 mtiles, 16 ntiles, 4 b), 256 thr
__global__ __launch_bounds__(256) void k_dist(const float* __restrict__ xn,
                                              const float* __restrict__ sq,
                                              float* __restrict__ dist) {
  __shared__ float As[32][68], Bs[32][68];
  int t = threadIdx.x;
  int m0 = blockIdx.x * 64, n0 = blockIdx.y * 64, b = blockIdx.z;
  int mg = t & 15, ng = t >> 4;
  float acc[16];
  #pragma unroll
  for (int i = 0; i < 16; ++i) acc[i] = 0.f;
  for (int cc = 0; cc < 128; cc += 32) {
    __syncthreads();
    for (int idx = t; idx < 2048; idx += 256) {
      int c = idx >> 6, j = idx & 63;
      As[c][j] = xn[((size_t)b * CI + cc + c) * NP + n0 + j];
      Bs[c][j] = xn[((size_t)b * CI + cc + c) * NP + m0 + j];
    }
    __syncthreads();
    #pragma unroll
    for (int c = 0; c < 32; ++c) {
      float4 avv = *(const float4*)&As[c][ng * 4];
      float4 bvv = *(const float4*)&Bs[c][mg * 4];
      float a[4] = {avv.x, avv.y, avv.z, avv.w};
      float bb[4] = {bvv.x, bvv.y, bvv.z, bvv.w};
      #pragma unroll
      for (int i = 0; i < 4; ++i)
        #pragma unroll
        for (int j = 0; j < 4; ++j) acc[i * 4 + j] += a[i] * bb[j];
    }
  }
  #pragma unroll
  for (int i = 0; i < 4; ++i) {
    int n = n0 + ng * 4 + i;
    float sn = sq[b * NP + n];
    float4 r;
    r.x = sn + sq[b * NP + m0 + mg * 4 + 0] - 2.f * acc[i * 4 + 0];
    r.y = sn + sq[b * NP + m0 + mg * 4 + 1] - 2.f * acc[i * 4 + 1];
    r.z = sn + sq[b * NP + m0 + mg * 4 + 2] - 2.f * acc[i * 4 + 2];
    r.w = sn + sq[b * NP + m0 + mg * 4 + 3] - 2.f * acc[i * 4 + 3];
    *(float4*)&dist[((size_t)b * NP + n) * NP + m0 + mg * 4] = r;
  }
}

// ---------------- K3: top-18 nearest per row (1 wave per row) ----------------
__global__ __launch_bounds__(64) void k_knn(const float* __restrict__ dist,
                                            int* __restrict__ knn) {
  int row = blockIdx.x;  // b*1024+n
  int l = threadIdx.x;
  const float* dr = dist + (size_t)row * NP;
  float d[16];
  #pragma unroll
  for (int i = 0; i < 16; ++i) d[i] = dr[l + 64 * i];
  for (int s = 0; s < 18; ++s) {
    float best = __builtin_inff(); int bslot = -1;
    #pragma unroll
    for (int i = 0; i < 16; ++i) if (d[i] < best) { best = d[i]; bslot = i; }
    int bidx = (bslot >= 0) ? (l + 64 * bslot) : 0x7fffffff;
    float bd = best; int bi = bidx;
    #pragma unroll
    for (int off = 32; off > 0; off >>= 1) {
      float od = __shfl_xor(bd, off);
      int   oi = __shfl_xor(bi, off);
      if (od < bd || (od == bd && oi < bi)) { bd = od; bi = oi; }
    }
    if (l == 0) knn[row * 18 + s] = bi;
    if ((bi & 63) == l) d[bi >> 6] = __builtin_inff();
  }
}

// ---------------- K4: P/Q pre-GEMMs for both edge convs ----------------
// grid (16 ntiles, 4 otiles, 8 = b*2+e), 256 thr
__global__ __launch_bounds__(256) void k_pq(const float* __restrict__ x,
                                            const float* __restrict__ Wa,
                                            const float* __restrict__ Wb,
                                            float* __restrict__ ws) {
  __shared__ float Xs[32][68], Wp[32][68], Wq[32][68];
  int t = threadIdx.x;
  int nt = blockIdx.x, ot = blockIdx.y, bz = blockIdx.z;
  int b = bz >> 1, e = bz & 1;
  const float* W = e ? Wb : Wa;
  float* P = ws + (size_t)e * 2097152 + (size_t)b * 256 * 1024;
  float* Q = P + 1048576;
  int mg = t & 15, og = t >> 4;
  float accp[16], accq[16];
  #pragma unroll
  for (int i = 0; i < 16; ++i) { accp[i] = 0.f; accq[i] = 0.f; }
  for (int cc = 0; cc < 128; cc += 32) {
    __syncthreads();
    for (int idx = t; idx < 2048; idx += 256) {
      int c = idx >> 6, n = idx & 63;
      Xs[c][n] = x[((size_t)b * CI + cc + c) * NP + nt * 64 + n];
    }
    for (int idx = t; idx < 2048; idx += 256) {
      int o = idx >> 5, c = idx & 31;
      float w1 = W[(ot * 64 + o) * 256 + cc + c];
      float w2 = W[(ot * 64 + o) * 256 + 128 + cc + c];
      Wp[c][o] = w1 - w2; Wq[c][o] = w2;
    }
    __syncthreads();
    #pragma unroll
    for (int c = 0; c < 32; ++c) {
      float4 xv = *(const float4*)&Xs[c][mg * 4];
      float4 wp = *(const float4*)&Wp[c][og * 4];
      float4 wq = *(const float4*)&Wq[c][og * 4];
      float xa[4] = {xv.x, xv.y, xv.z, xv.w};
      float pa[4] = {wp.x, wp.y, wp.z, wp.w};
      float qa[4] = {wq.x, wq.y, wq.z, wq.w};
      #pragma unroll
      for (int i = 0; i < 4; ++i)
        #pragma unroll
        for (int j = 0; j < 4; ++j) { accp[i * 4 + j] += pa[i] * xa[j]; accq[i * 4 + j] += qa[i] * xa[j]; }
    }
  }
  #pragma unroll
  for (int i = 0; i < 4; ++i) {
    int o = ot * 64 + og * 4 + i;
    float4 rp = {accp[i*4+0], accp[i*4+1], accp[i*4+2], accp[i*4+3]};
    float4 rq = {accq[i*4+0], accq[i*4+1], accq[i*4+2], accq[i*4+3]};
    *(float4*)&P[(size_t)o * 1024 + nt * 64 + mg * 4] = rp;
    *(float4*)&Q[(size_t)o * 1024 + nt * 64 + mg * 4] = rq;
  }
}

// ---------------- K5: edge conv BN stats (deterministic, block per (e,o)) ----------------
__global__ __launch_bounds__(256) void k_edge_stats(const float* __restrict__ ws,
                                                    const int* __restrict__ knn,
                                                    float* __restrict__ sums) {
  int eo = blockIdx.x; int e = eo >> 8, o = eo & 255;
  const float* Pb = ws + (size_t)e * 2097152;
  const float* Qb = Pb + 1048576;
  int t = threadIdx.x;
  float s = 0.f, s2 = 0.f;
  for (int b = 0; b < NB; ++b) {
    const float* Pr = Pb + ((size_t)b * 256 + o) * 1024;
    const float* Qr = Qb + ((size_t)b * 256 + o) * 1024;
    const int* kb = knn + b * 1024 * 18;
    for (int n = t; n < 1024; n += 256) {
      float p = Pr[n];
      const int* kn = kb + n * 18;
      #pragma unroll
      for (int kk = 0; kk < 9; ++kk) {
        int j = kn[e ? 2 * kk : kk];
        float v = p + Qr[j];
        s += v; s2 += v * v;
      }
    }
  }
  __shared__ float rs[256], rs2[256];
  rs[t] = s; rs2[t] = s2;
  __syncthreads();
  for (int off = 128; off > 0; off >>= 1) {
    if (t < off) { rs[t] += rs[t + off]; rs2[t] += rs2[t + off]; }
    __syncthreads();
  }
  if (t == 0) { sums[eo * 2] = rs[0]; sums[eo * 2 + 1] = rs2[0]; }
}

// ---------------- K6: finalize edge BN -> alpha/beta ----------------
__global__ __launch_bounds__(256) void k_edge_fin(const float* __restrict__ sums,
                                                  const float* __restrict__ gna, const float* __restrict__ bta,
                                                  const float* __restrict__ gnb, const float* __restrict__ btb,
                                                  float* __restrict__ ab) {
  int i = blockIdx.x * 256 + threadIdx.x;
  if (i >= 512) return;
  int e = i >> 8, o = i & 255;
  float cnt = 4.0f * 1024.0f * 9.0f;
  float mean = sums[i * 2] / cnt;
  float var = sums[i * 2 + 1] / cnt - mean * mean;
  float g = e ? gnb[o] : gna[o];
  float bt = e ? btb[o] : bta[o];
  float alpha = g * rsqrtf(var + EPSBN);
  ab[i * 2] = alpha; ab[i * 2 + 1] = bt - mean * alpha;
}

// ---------------- K7: edge conv apply + max-over-k -> Xatt layout ----------------
// grid (4, 256 o, 8 = b*2+e), 256 thr
__global__ __launch_bounds__(256) void k_edge_apply(const float* __restrict__ ws,
                                                    const int* __restrict__ knn,
                                                    const float* __restrict__ ab,
                                                    float* __restrict__ Xatt) {
  int n = blockIdx.x * 256 + threadIdx.x;
  int o = blockIdx.y; int bz = blockIdx.z; int b = bz >> 1, e = bz & 1;
  const float* Pr = ws + (size_t)e * 2097152 + ((size_t)b * 256 + o) * 1024;
  const float* Qr = ws + (size_t)e * 2097152 + 1048576 + ((size_t)b * 256 + o) * 1024;
  float alpha = ab[(e * 256 + o) * 2], bet = ab[(e * 256 + o) * 2 + 1];
  const int* kn = knn + (b * 1024 + n) * 18;
  float p = Pr[n];
  float mx = -__builtin_inff();
  #pragma unroll
  for (int kk = 0; kk < 9; ++kk) {
    int j = kn[e ? 2 * kk : kk];
    float v = alpha * (p + Qr[j]) + bet;
    mx = fmaxf(mx, v);
  }
  float r = fmaxf(mx, 0.0f);
  int u = (e << 1) | (o >> 7); int c = o & 127;
  Xatt[((size_t)b * 130 + c) * MM + 4 * n + u] = r;
}

// ---------------- K8: grid channels ----------------
__global__ __launch_bounds__(256) void k_grid(float* __restrict__ Xatt) {
  int i = blockIdx.x * 256 + threadIdx.x;  // b*4096+m
  int b = i >> 12, m = i & 4095;
  int u = m >> 10;
  Xatt[((size_t)b * 130 + 128) * MM + m] = (u < 2) ? -0.2f : 0.2f;
  Xatt[((size_t)b * 130 + 129) * MM + m] = (u & 1) ? 0.2f : -0.2f;
}

// ---------------- generic 1x1 conv (GEMM over channels), optional relu ----------------
// grid (64 mtiles, otiles, 4 b), 256 thr
template <int CINN, bool RELU>
__global__ __launch_bounds__(256) void k_conv(const float* __restrict__ src,
                                              const float* __restrict__ W,
                                              const float* __restrict__ bias,
                                              float* __restrict__ dst, int Cout) {
  __shared__ float As[32][68], Ws[32][68];
  int t = threadIdx.x;
  int m0 = blockIdx.x * 64, o0 = blockIdx.y * 64, b = blockIdx.z;
  int mg = t & 15, og = t >> 4;
  float acc[16];
  #pragma unroll
  for (int i = 0; i < 16; ++i) acc[i] = 0.f;
  for (int cc = 0; cc < CINN; cc += 32) {
    int cl = (CINN - cc < 32) ? (CINN - cc) : 32;
    __syncthreads();
    for (int idx = t; idx < 2048; idx += 256) {
      int c = idx >> 6, m = idx & 63;
      As[c][m] = (c < cl) ? src[((size_t)b * CINN + cc + c) * MM + m0 + m] : 0.0f;
    }
    for (int idx = t; idx < 2048; idx += 256) {
      int o = idx >> 5, c = idx & 31;
      Ws[c][o] = (c < cl && (o0 + o) < Cout) ? W[(size_t)(o0 + o) * CINN + cc + c] : 0.0f;
    }
    __syncthreads();
    #pragma unroll
    for (int c = 0; c < 32; ++c) {
      float4 avv = *(const float4*)&As[c][mg * 4];
      float4 wvv = *(const float4*)&Ws[c][og * 4];
      float a[4] = {avv.x, avv.y, avv.z, avv.w};
      float w[4] = {wvv.x, wvv.y, wvv.z, wvv.w};
      #pragma unroll
      for (int i = 0; i < 4; ++i)
        #pragma unroll
        for (int j = 0; j < 4; ++j) acc[i * 4 + j] += w[i] * a[j];
    }
  }
  #pragma unroll
  for (int i = 0; i < 4; ++i) {
    int o = o0 + og * 4 + i;
    if (o < Cout) {
      float bb = bias[o];
      float4 r;
      r.x = acc[i * 4 + 0] + bb; r.y = acc[i * 4 + 1] + bb;
      r.z = acc[i * 4 + 2] + bb; r.w = acc[i * 4 + 3] + bb;
      if (RELU) { r.x = fmaxf(r.x, 0.f); r.y = fmaxf(r.y, 0.f); r.z = fmaxf(r.z, 0.f); r.w = fmaxf(r.w, 0.f); }
      *(float4*)&dst[((size_t)b * Cout + o) * MM + m0 + mg * 4] = r;
    }
  }
}

// ---------------- BN stats for attention convs (block per channel) ----------------
__global__ __launch_bounds__(256) void k_bnstats(const float* __restrict__ src,
                                                 const float* __restrict__ g,
                                                 const float* __restrict__ be,
                                                 float* __restrict__ ab, int Cout) {
  int o = blockIdx.x;
  int t = threadIdx.x;
  float s = 0.f, s2 = 0.f;
  for (int b = 0; b < NB; ++b) {
    const float* r = src + ((size_t)b * Cout + o) * MM;
    for (int m = t; m < MM; m += 256) { float v = r[m]; s += v; s2 += v * v; }
  }
  __shared__ float rs[256], rs2[256];
  rs[t] = s; rs2[t] = s2;
  __syncthreads();
  for (int off = 128; off > 0; off >>= 1) {
    if (t < off) { rs[t] += rs[t + off]; rs2[t] += rs2[t + off]; }
    __syncthreads();
  }
  if (t == 0) {
    float cnt = 16384.0f;
    float mean = rs[0] / cnt, var = rs2[0] / cnt - mean * mean;
    float alpha = g[o] * rsqrtf(var + EPSBN);
    ab[o * 2] = alpha; ab[o * 2 + 1] = be[o] - mean * alpha;
  }
}

// ---------------- apply BN + relu elementwise ----------------
__global__ __launch_bounds__(256) void k_bnapply(float* __restrict__ x,
                                                 const float* __restrict__ ab, int Cout) {
  size_t i = (size_t)blockIdx.x * 256 + threadIdx.x;
  size_t total = (size_t)NB * Cout * MM;
  if (i >= total) return;
  int o = (int)((i >> 12) % Cout);
  x[i] = fmaxf(ab[o * 2] * x[i] + ab[o * 2 + 1], 0.0f);
}

// ---------------- K11: softmax rowmax + Z (online over m-tiles) ----------------
// grid (128 rowtiles, 4 b), 256 thr
__global__ __launch_bounds__(256) void k_zpass(const float* __restrict__ F,
                                               const float* __restrict__ G,
                                               float* __restrict__ rowmax,
                                               float* __restrict__ Z) {
  __shared__ float Gs[32][36], Fs[32][132];
  int t = threadIdx.x;
  int b = blockIdx.y, n0 = blockIdx.x * 32;
  for (int idx = t; idx < 1024; idx += 256) {
    int c = idx >> 5, n = idx & 31;
    Gs[c][n] = G[((size_t)b * 32 + c) * MM + n0 + n];
  }
  int rg = t >> 5, cq = t & 31;
  float cm[4], cz[4];
  #pragma unroll
  for (int i = 0; i < 4; ++i) { cm[i] = -__builtin_inff(); cz[i] = 0.f; }
  for (int m0 = 0; m0 < MM; m0 += 128) {
    __syncthreads();
    for (int idx = t; idx < 4096; idx += 256) {
      int c = idx >> 7, m = idx & 127;
      Fs[c][m] = F[((size_t)b * 32 + c) * MM + m0 + m];
    }
    __syncthreads();
    float s[4][4];
    #pragma unroll
    for (int i = 0; i < 4; ++i)
      #pragma unroll
      for (int j = 0; j < 4; ++j) s[i][j] = 0.f;
    #pragma unroll
    for (int c = 0; c < 32; ++c) {
      float4 gvv = *(const float4*)&Gs[c][rg * 4];
      float4 fvv = *(const float4*)&Fs[c][cq * 4];
      float gg2[4] = {gvv.x, gvv.y, gvv.z, gvv.w};
      float ff[4] = {fvv.x, fvv.y, fvv.z, fvv.w};
      #pragma unroll
      for (int i = 0; i < 4; ++i)
        #pragma unroll
        for (int j = 0; j < 4; ++j) s[i][j] += gg2[i] * ff[j];
    }
    #pragma unroll
    for (int i = 0; i < 4; ++i) {
      float tm = fmaxf(fmaxf(s[i][0], s[i][1]), fmaxf(s[i][2], s[i][3]));
      float nm = fmaxf(cm[i], tm);
      float es = __expf(s[i][0] - nm) + __expf(s[i][1] - nm) + __expf(s[i][2] - nm) + __expf(s[i][3] - nm);
      cz[i] = cz[i] * __expf(cm[i] - nm) + es;
      cm[i] = nm;
    }
  }
  #pragma unroll
  for (int i = 0; i < 4; ++i) {
    float m_ = cm[i], z_ = cz[i];
    #pragma unroll
    for (int off = 1; off < 32; off <<= 1) {
      float om = __shfl_xor(m_, off);
      float oz = __shfl_xor(z_, off);
      float nm = fmaxf(m_, om);
      z_ = z_ * __expf(m_ - nm) + oz * __expf(om - nm);
      m_ = nm;
    }
    if (cq == 0) {
      rowmax[(size_t)b * MM + n0 + rg * 4 + i] = m_;
      Z[(size_t)b * MM + n0 + rg * 4 + i] = z_;
    }
  }
}

// ---------------- K12: H /= Z ----------------
__global__ __launch_bounds__(256) void k_hdiv(float* __restrict__ H, const float* __restrict__ Z) {
  size_t i = (size_t)blockIdx.x * 256 + threadIdx.x;
  if (i >= (size_t)NB * 130 * MM) return;
  int m = (int)(i & 4095);
  int bc = (int)(i >> 12);
  int b = bc / 130;
  H[i] = H[i] / Z[(size_t)b * MM + m];
}

// ---------------- K13: O-pass (flash-style) + A = gamma*o + Xatt ----------------
// grid (64 mtiles, 4 b), 256 thr
__global__ __launch_bounds__(256) void k_opass(const float* __restrict__ F,
                                               const float* __restrict__ G,
                                               const float* __restrict__ H,
                                               const float* __restrict__ rowmax,
                                               const float* __restrict__ Xatt,
                                               const float* __restrict__ gma,
                                               float* __restrict__ A) {
  __shared__ float Fs[32][68], Gs[32][34], Hs[32][136], Ps[32][72], Rm[32];
  int t = threadIdx.x;
  int b = blockIdx.y, m0 = blockIdx.x * 64;
  // stage F tile once
  for (int idx = t; idx < 2048; idx += 256) {
    int c = idx >> 6, m = idx & 63;
    Fs[c][m] = F[((size_t)b * 32 + c) * MM + m0 + m];
  }
  int mq = t & 15, cg = t >> 4;       // accum mapping: cols mq*4.., channels cg*8..
  int prg = t >> 4, pcq = t & 15;     // p mapping: rows prg*2.., cols pcq*4..
  float acc[36];
  #pragma unroll
  for (int i = 0; i < 36; ++i) acc[i] = 0.f;
  for (int n0 = 0; n0 < MM; n0 += 32) {
    __syncthreads();
    for (int idx = t; idx < 1024; idx += 256) {
      int c = idx >> 5, n = idx & 31;
      Gs[c][n] = G[((size_t)b * 32 + c) * MM + n0 + n];
    }
    for (int idx = t; idx < 4160; idx += 256) {
      int c = idx >> 5, n = idx & 31;
      Hs[n][c] = H[((size_t)b * 130 + c) * MM + n0 + n];
    }
    if (t < 32) Rm[t] = rowmax[(size_t)b * MM + n0 + t];
    __syncthreads();
    // p-phase: s[2][4] then exp into Ps
    float s[2][4];
    #pragma unroll
    for (int i = 0; i < 2; ++i)
      #pragma unroll
      for (int j = 0; j < 4; ++j) s[i][j] = 0.f;
    #pragma unroll
    for (int c = 0; c < 32; ++c) {
      float2 gv = *(const float2*)&Gs[c][prg * 2];
      float4 fvv = *(const float4*)&Fs[c][pcq * 4];
      float ff[4] = {fvv.x, fvv.y, fvv.z, fvv.w};
      #pragma unroll
      for (int j = 0; j < 4; ++j) { s[0][j] += gv.x * ff[j]; s[1][j] += gv.y * ff[j]; }
    }
    #pragma unroll
    for (int i = 0; i < 2; ++i) {
      float rm = Rm[prg * 2 + i];
      float4 p;
      p.x = __expf(s[i][0] - rm); p.y = __expf(s[i][1] - rm);
      p.z = __expf(s[i][2] - rm); p.w = __expf(s[i][3] - rm);
      *(float4*)&Ps[prg * 2 + i][pcq * 4] = p;
    }
    __syncthreads();
    // accumulate o
    for (int nt = 0; nt < 32; ++nt) {
      float4 pvv = *(const float4*)&Ps[nt][mq * 4];
      float pv[4] = {pvv.x, pvv.y, pvv.z, pvv.w};
      #pragma unroll
      for (int q = 0; q < 2; ++q) {
        float4 hvv = *(const float4*)&Hs[nt][cg * 8 + q * 4];
        float hh[4] = {hvv.x, hvv.y, hvv.z, hvv.w};
        #pragma unroll
        for (int l = 0; l < 4; ++l)
          #pragma unroll
          for (int j = 0; j < 4; ++j) acc[(q * 4 + l) * 4 + j] += hh[l] * pv[j];
      }
      if (cg < 2) {
        float hx = Hs[nt][128 + cg];
        #pragma unroll
        for (int j = 0; j < 4; ++j) acc[32 + j] += hx * pv[j];
      }
    }
  }
  // epilogue: A = gamma*o + Xatt
  float gm = gma[0];
  #pragma unroll
  for (int k = 0; k < 8; ++k) {
    int c = cg * 8 + k;
    float4 xv = *(const float4*)&Xatt[((size_t)b * 130 + c) * MM + m0 + mq * 4];
    float4 r;
    r.x = gm * acc[k * 4 + 0] + xv.x; r.y = gm * acc[k * 4 + 1] + xv.y;
    r.z = gm * acc[k * 4 + 2] + xv.z; r.w = gm * acc[k * 4 + 3] + xv.w;
    *(float4*)&A[((size_t)b * 130 + c) * MM + m0 + mq * 4] = r;
  }
  if (cg < 2) {
    int c = 128 + cg;
    float4 xv = *(const float4*)&Xatt[((size_t)b * 130 + c) * MM + m0 + mq * 4];
    float4 r;
    r.x = gm * acc[32] + xv.x; r.y = gm * acc[33] + xv.y;
    r.z = gm * acc[34] + xv.z; r.w = gm * acc[35] + xv.w;
    *(float4*)&A[((size_t)b * 130 + c) * MM + m0 + mq * 4] = r;
  }
}

extern "C" void kernel_launch(void* const* d_in, const int* in_sizes, int n_in,
                              void* d_out, int out_size, void* d_ws, size_t ws_size,
                              hipStream_t stream) {
  const float* inp = (const float*)d_in[0];
  const float* Wa  = (const float*)d_in[1];
  const float* gna = (const float*)d_in[2];
  const float* bta = (const float*)d_in[3];
  const float* Wb  = (const float*)d_in[4];
  const float* gnb = (const float*)d_in[5];
  const float* btb = (const float*)d_in[6];
  const float* Wf  = (const float*)d_in[7];
  const float* bf  = (const float*)d_in[8];
  const float* gf  = (const float*)d_in[9];
  const float* bef = (const float*)d_in[10];
  const float* Wg  = (const float*)d_in[11];
  const float* bg  = (const float*)d_in[12];
  const float* gg  = (const float*)d_in[13];
  const float* beg = (const float*)d_in[14];
  const float* Wh  = (const float*)d_in[15];
  const float* bh  = (const float*)d_in[16];
  const float* gh  = (const float*)d_in[17];
  const float* beh = (const float*)d_in[18];
  const float* gamma = (const float*)d_in[19];
  const float* W1  = (const float*)d_in[20];
  const float* b1  = (const float*)d_in[21];
  const float* W2  = (const float*)d_in[22];
  const float* b2  = (const float*)d_in[23];
  float* out = (float*)d_out;

  float* ws = (float*)d_ws;
  float* DIST = ws + OFF_BIG0;
  float* PQ   = ws + OFF_BIG0;
  float* A    = ws + OFF_BIG0;
  float* F0   = ws + OFF_BIG1;
  float* G0   = ws + OFF_BIG1 + 524288;
  float* H0   = ws + OFF_BIG1 + 1048576;
  float* Y1   = ws + OFF_BIG1;
  float* XN   = ws + OFF_XN;
  float* SQ   = ws + OFF_SQ;
  float* RM   = ws + OFF_RM;
  float* ZZ   = ws + OFF_Z;
  float* XATT = ws + OFF_XATT;
  float* SUMS = ws + OFF_SUMS;
  float* ABE  = ws + OFF_ABE;
  float* ABF  = ws + OFF_ABF;
  float* ABG  = ws + OFF_ABG;
  float* ABH  = ws + OFF_ABH;
  int*   KNNI = (int*)(ws + OFF_KNN);

  // 1. normalize
  k_norm<<<16, 256, 0, stream>>>(inp, XN, SQ);
  // 2. pairwise dist
  k_dist<<<dim3(16, 16, 4), 256, 0, stream>>>(XN, SQ, DIST);
  // 3. knn top-18
  k_knn<<<4096, 64, 0, stream>>>(DIST, KNNI);
  // 4. P/Q (overwrites DIST)
  k_pq<<<dim3(16, 4, 8), 256, 0, stream>>>(inp, Wa, Wb, PQ);
  // 5-6. edge BN stats + finalize
  k_edge_stats<<<512, 256, 0, stream>>>(PQ, KNNI, SUMS);
  k_edge_fin<<<2, 256, 0, stream>>>(SUMS, gna, bta, gnb, btb, ABE);
  // 7. edge apply + max -> Xatt ; 8. grid channels
  k_edge_apply<<<dim3(4, 256, 8), 256, 0, stream>>>(PQ, KNNI, ABE, XATT);
  k_grid<<<64, 256, 0, stream>>>(XATT);
  // 9. attention convs f,g,h (raw conv + bias)
  k_conv<130, false><<<dim3(64, 1, 4), 256, 0, stream>>>(XATT, Wf, bf, F0, 32);
  k_conv<130, false><<<dim3(64, 1, 4), 256, 0, stream>>>(XATT, Wg, bg, G0, 32);
  k_conv<130, false><<<dim3(64, 3, 4), 256, 0, stream>>>(XATT, Wh, bh, H0, 130);
  // 10. BN stats + apply
  k_bnstats<<<32, 256, 0, stream>>>(F0, gf, bef, ABF, 32);
  k_bnstats<<<32, 256, 0, stream>>>(G0, gg, beg, ABG, 32);
  k_bnstats<<<130, 256, 0, stream>>>(H0, gh, beh, ABH, 130);
  k_bnapply<<<2048, 256, 0, stream>>>(F0, ABF, 32);
  k_bnapply<<<2048, 256, 0, stream>>>(G0, ABG, 32);
  k_bnapply<<<8320, 256, 0, stream>>>(H0, ABH, 130);
  // 11. softmax rowmax/Z
  k_zpass<<<dim3(128, 4), 256, 0, stream>>>(F0, G0, RM, ZZ);
  // 12. H /= Z
  k_hdiv<<<8320, 256, 0, stream>>>(H0, ZZ);
  // 13. O-pass + residual (writes A over PQ region)
  k_opass<<<dim3(64, 4), 256, 0, stream>>>(F0, G0, H0, RM, XATT, gamma, A);
  // 14. conv1 130->256 relu (Y1 overwrites F0/G0/H0)
  k_conv<130, true><<<dim3(64, 4, 4), 256, 0, stream>>>(A, W1, b1, Y1, 256);
  // 15. conv2 256->128 relu -> out
  k_conv<256, true><<<dim3(64, 2, 4), 256, 0, stream>>>(Y1, W2, b2, out, 128);
}

// Round 2
// 614.851 us; speedup vs baseline: 2.1307x; 2.1307x over previous
//
#include <hip/hip_runtime.h>

namespace {
constexpr int NB = 4;      // batch
constexpr int CI = 128;    // input channels
constexpr int NP = 1024;   // points
constexpr int MM = 4096;   // N*UP
constexpr float EPSBN = 1e-5f;
constexpr float LOG2E = 1.4426950408889634f;

// workspace offsets (in floats)
constexpr size_t OFF_BIG0 = 0;          // 4194304: dist -> P1,Q1,P2,Q2 -> A(first 2129920) + Ft/Gt/Hb
constexpr size_t OFF_FT   = 2129920;    // bf16 F (B,4096,32): 262144 floats
constexpr size_t OFF_GT   = 2392064;    // bf16 G (B,4096,32): 262144 floats
constexpr size_t OFF_HB   = 2654208;    // bf16 H (B,144,4096): 1179648 floats (ends 3833856 < 4194304)
constexpr size_t OFF_BIG1 = 4194304;    // F0,G0,H0 raw -> Opart(2x2129920, spills into XN) -> Y1
constexpr size_t OFF_OP   = 4194304;    // Opart, ends 8454144 (< 8912896)
constexpr size_t OFF_XN   = 8388608;    // 524288 (dead after k_dist; Opart tail reuses)
constexpr size_t OFF_SQ   = 8912896;    // 4096
constexpr size_t OFF_LSE  = 8916992;    // 16384 (was RM)
constexpr size_t OFF_XATT = 8949760;    // 2129920
constexpr size_t OFF_SUMS = 11079680;   // 1024
constexpr size_t OFF_ABE  = 11080704;   // 1024
constexpr size_t OFF_ABF  = 11081728;   // 64
constexpr size_t OFF_ABG  = 11081792;   // 64
constexpr size_t OFF_ABH  = 11081856;   // 260 (padded)
constexpr size_t OFF_KNN  = 11082368;   // 73728 ints
} // namespace

typedef __attribute__((ext_vector_type(8))) short short8;
typedef __attribute__((ext_vector_type(4))) float f32x4;
#define MFMA16(A, B, C) __builtin_amdgcn_mfma_f32_16x16x32_bf16(A, B, C, 0, 0, 0)

__device__ inline unsigned short f2bf(float x) {
  unsigned int u = __float_as_uint(x);
  unsigned int r = u + 0x7fff + ((u >> 16) & 1);
  return (unsigned short)(r >> 16);
}

// ---------------- K1: normalize features, per-point sq ----------------
__global__ __launch_bounds__(256) void k_norm(const float* __restrict__ x,
                                              float* __restrict__ xn,
                                              float* __restrict__ sq) {
  int t = blockIdx.x * 256 + threadIdx.x;   // b*1024+n
  int b = t >> 10, n = t & 1023;
  const float* xb = x + (size_t)b * CI * NP + n;
  float ss = 0.f;
  #pragma unroll 4
  for (int c = 0; c < CI; ++c) { float v = xb[(size_t)c * NP]; ss += v * v; }
  float inv = 1.f / fmaxf(sqrtf(ss), 1e-12f);
  float* xo = xn + (size_t)b * CI * NP + n;
  float s2 = 0.f;
  #pragma unroll 4
  for (int c = 0; c < CI; ++c) { float v = xb[(size_t)c * NP] * inv; xo[(size_t)c * NP] = v; s2 += v * v; }
  sq[t] = s2;
}

// ---------------- K2: pairwise distance, 64x64 tiles ----------------
__global__ __launch_bounds__(256) void k_dist(const float* __restrict__ xn,
                                              const float* __restrict__ sq,
                                              float* __restrict__ dist) {
  __shared__ float As[32][68], Bs[32][68];
  int t = threadIdx.x;
  int m0 = blockIdx.x * 64, n0 = blockIdx.y * 64, b = blockIdx.z;
  int mg = t & 15, ng = t >> 4;
  float acc[16];
  #pragma unroll
  for (int i = 0; i < 16; ++i) acc[i] = 0.f;
  for (int cc = 0; cc < 128; cc += 32) {
    __syncthreads();
    for (int idx = t; idx < 2048; idx += 256) {
      int c = idx >> 6, j = idx & 63;
      As[c][j] = xn[((size_t)b * CI + cc + c) * NP + n0 + j];
      Bs[c][j] = xn[((size_t)b * CI + cc + c) * NP + m0 + j];
    }
    __syncthreads();
    #pragma unroll
    for (int c = 0; c < 32; ++c) {
      float4 avv = *(const float4*)&As[c][ng * 4];
      float4 bvv = *(const float4*)&Bs[c][mg * 4];
      float a[4] = {avv.x, avv.y, avv.z, avv.w};
      float bb[4] = {bvv.x, bvv.y, bvv.z, bvv.w};
      #pragma unroll
      for (int i = 0; i < 4; ++i)
        #pragma unroll
        for (int j = 0; j < 4; ++j) acc[i * 4 + j] += a[i] * bb[j];
    }
  }
  #pragma unroll
  for (int i = 0; i < 4; ++i) {
    int n = n0 + ng * 4 + i;
    float sn = sq[b * NP + n];
    float4 r;
    r.x = sn + sq[b * NP + m0 + mg * 4 + 0] - 2.f * acc[i * 4 + 0];
    r.y = sn + sq[b * NP + m0 + mg * 4 + 1] - 2.f * acc[i * 4 + 1];
    r.z = sn + sq[b * NP + m0 + mg * 4 + 2] - 2.f * acc[i * 4 + 2];
    r.w = sn + sq[b * NP + m0 + mg * 4 + 3] - 2.f * acc[i * 4 + 3];
    *(float4*)&dist[((size_t)b * NP + n) * NP + m0 + mg * 4] = r;
  }
}

// ---------------- K3: top-18 nearest per row ----------------
__global__ __launch_bounds__(64) void k_knn(const float* __restrict__ dist,
                                            int* __restrict__ knn) {
  int row = blockIdx.x;  // b*1024+n
  int l = threadIdx.x;
  const float* dr = dist + (size_t)row * NP;
  float d[16];
  #pragma unroll
  for (int i = 0; i < 16; ++i) d[i] = dr[l + 64 * i];
  for (int s = 0; s < 18; ++s) {
    float best = __builtin_inff(); int bslot = -1;
    #pragma unroll
    for (int i = 0; i < 16; ++i) if (d[i] < best) { best = d[i]; bslot = i; }
    int bidx = (bslot >= 0) ? (l + 64 * bslot) : 0x7fffffff;
    float bd = best; int bi = bidx;
    #pragma unroll
    for (int off = 32; off > 0; off >>= 1) {
      float od = __shfl_xor(bd, off);
      int   oi = __shfl_xor(bi, off);
      if (od < bd || (od == bd && oi < bi)) { bd = od; bi = oi; }
    }
    if (l == 0) knn[row * 18 + s] = bi;
    if ((bi & 63) == l) d[bi >> 6] = __builtin_inff();
  }
}

// ---------------- K4: P/Q pre-GEMMs for both edge convs ----------------
__global__ __launch_bounds__(256) void k_pq(const float* __restrict__ x,
                                            const float* __restrict__ Wa,
                                            const float* __restrict__ Wb,
                                            float* __restrict__ ws) {
  __shared__ float Xs[32][68], Wp[32][68], Wq[32][68];
  int t = threadIdx.x;
  int nt = blockIdx.x, ot = blockIdx.y, bz = blockIdx.z;
  int b = bz >> 1, e = bz & 1;
  const float* W = e ? Wb : Wa;
  float* P = ws + (size_t)e * 2097152 + (size_t)b * 256 * 1024;
  float* Q = P + 1048576;
  int mg = t & 15, og = t >> 4;
  float accp[16], accq[16];
  #pragma unroll
  for (int i = 0; i < 16; ++i) { accp[i] = 0.f; accq[i] = 0.f; }
  for (int cc = 0; cc < 128; cc += 32) {
    __syncthreads();
    for (int idx = t; idx < 2048; idx += 256) {
      int c = idx >> 6, n = idx & 63;
      Xs[c][n] = x[((size_t)b * CI + cc + c) * NP + nt * 64 + n];
    }
    for (int idx = t; idx < 2048; idx += 256) {
      int o = idx >> 5, c = idx & 31;
      float w1 = W[(ot * 64 + o) * 256 + cc + c];
      float w2 = W[(ot * 64 + o) * 256 + 128 + cc + c];
      Wp[c][o] = w1 - w2; Wq[c][o] = w2;
    }
    __syncthreads();
    #pragma unroll
    for (int c = 0; c < 32; ++c) {
      float4 xv = *(const float4*)&Xs[c][mg * 4];
      float4 wp = *(const float4*)&Wp[c][og * 4];
      float4 wq = *(const float4*)&Wq[c][og * 4];
      float xa[4] = {xv.x, xv.y, xv.z, xv.w};
      float pa[4] = {wp.x, wp.y, wp.z, wp.w};
      float qa[4] = {wq.x, wq.y, wq.z, wq.w};
      #pragma unroll
      for (int i = 0; i < 4; ++i)
        #pragma unroll
        for (int j = 0; j < 4; ++j) { accp[i * 4 + j] += pa[i] * xa[j]; accq[i * 4 + j] += qa[i] * xa[j]; }
    }
  }
  #pragma unroll
  for (int i = 0; i < 4; ++i) {
    int o = ot * 64 + og * 4 + i;
    float4 rp = {accp[i*4+0], accp[i*4+1], accp[i*4+2], accp[i*4+3]};
    float4 rq = {accq[i*4+0], accq[i*4+1], accq[i*4+2], accq[i*4+3]};
    *(float4*)&P[(size_t)o * 1024 + nt * 64 + mg * 4] = rp;
    *(float4*)&Q[(size_t)o * 1024 + nt * 64 + mg * 4] = rq;
  }
}

// ---------------- K5: edge conv BN stats ----------------
__global__ __launch_bounds__(256) void k_edge_stats(const float* __restrict__ ws,
                                                    const int* __restrict__ knn,
                                                    float* __restrict__ sums) {
  int eo = blockIdx.x; int e = eo >> 8, o = eo & 255;
  const float* Pb = ws + (size_t)e * 2097152;
  const float* Qb = Pb + 1048576;
  int t = threadIdx.x;
  float s = 0.f, s2 = 0.f;
  for (int b = 0; b < NB; ++b) {
    const float* Pr = Pb + ((size_t)b * 256 + o) * 1024;
    const float* Qr = Qb + ((size_t)b * 256 + o) * 1024;
    const int* kb = knn + b * 1024 * 18;
    for (int n = t; n < 1024; n += 256) {
      float p = Pr[n];
      const int* kn = kb + n * 18;
      #pragma unroll
      for (int kk = 0; kk < 9; ++kk) {
        int j = kn[e ? 2 * kk : kk];
        float v = p + Qr[j];
        s += v; s2 += v * v;
      }
    }
  }
  __shared__ float rs[256], rs2[256];
  rs[t] = s; rs2[t] = s2;
  __syncthreads();
  for (int off = 128; off > 0; off >>= 1) {
    if (t < off) { rs[t] += rs[t + off]; rs2[t] += rs2[t + off]; }
    __syncthreads();
  }
  if (t == 0) { sums[eo * 2] = rs[0]; sums[eo * 2 + 1] = rs2[0]; }
}

// ---------------- K6: finalize edge BN ----------------
__global__ __launch_bounds__(256) void k_edge_fin(const float* __restrict__ sums,
                                                  const float* __restrict__ gna, const float* __restrict__ bta,
                                                  const float* __restrict__ gnb, const float* __restrict__ btb,
                                                  float* __restrict__ ab) {
  int i = blockIdx.x * 256 + threadIdx.x;
  if (i >= 512) return;
  int e = i >> 8, o = i & 255;
  float cnt = 4.0f * 1024.0f * 9.0f;
  float mean = sums[i * 2] / cnt;
  float var = sums[i * 2 + 1] / cnt - mean * mean;
  float g = e ? gnb[o] : gna[o];
  float bt = e ? btb[o] : bta[o];
  float alpha = g * rsqrtf(var + EPSBN);
  ab[i * 2] = alpha; ab[i * 2 + 1] = bt - mean * alpha;
}

// ---------------- K7: edge conv apply + max-over-k ----------------
__global__ __launch_bounds__(256) void k_edge_apply(const float* __restrict__ ws,
                                                    const int* __restrict__ knn,
                                                    const float* __restrict__ ab,
                                                    float* __restrict__ Xatt) {
  int n = blockIdx.x * 256 + threadIdx.x;
  int o = blockIdx.y; int bz = blockIdx.z; int b = bz >> 1, e = bz & 1;
  const float* Pr = ws + (size_t)e * 2097152 + ((size_t)b * 256 + o) * 1024;
  const float* Qr = ws + (size_t)e * 2097152 + 1048576 + ((size_t)b * 256 + o) * 1024;
  float alpha = ab[(e * 256 + o) * 2], bet = ab[(e * 256 + o) * 2 + 1];
  const int* kn = knn + (b * 1024 + n) * 18;
  float p = Pr[n];
  float mx = -__builtin_inff();
  #pragma unroll
  for (int kk = 0; kk < 9; ++kk) {
    int j = kn[e ? 2 * kk : kk];
    float v = alpha * (p + Qr[j]) + bet;
    mx = fmaxf(mx, v);
  }
  float r = fmaxf(mx, 0.0f);
  int u = (e << 1) | (o >> 7); int c = o & 127;
  Xatt[((size_t)b * 130 + c) * MM + 4 * n + u] = r;
}

// ---------------- K8: grid channels ----------------
__global__ __launch_bounds__(256) void k_grid(float* __restrict__ Xatt) {
  int i = blockIdx.x * 256 + threadIdx.x;  // b*4096+m
  int b = i >> 12, m = i & 4095;
  int u = m >> 10;
  Xatt[((size_t)b * 130 + 128) * MM + m] = (u < 2) ? -0.2f : 0.2f;
  Xatt[((size_t)b * 130 + 129) * MM + m] = (u & 1) ? 0.2f : -0.2f;
}

// ---------------- generic 1x1 conv (GEMM over channels) ----------------
template <int CINN, bool RELU>
__global__ __launch_bounds__(256) void k_conv(const float* __restrict__ src,
                                              const float* __restrict__ W,
                                              const float* __restrict__ bias,
                                              float* __restrict__ dst, int Cout) {
  __shared__ float As[32][68], Ws[32][68];
  int t = threadIdx.x;
  int m0 = blockIdx.x * 64, o0 = blockIdx.y * 64, b = blockIdx.z;
  int mg = t & 15, og = t >> 4;
  float acc[16];
  #pragma unroll
  for (int i = 0; i < 16; ++i) acc[i] = 0.f;
  for (int cc = 0; cc < CINN; cc += 32) {
    int cl = (CINN - cc < 32) ? (CINN - cc) : 32;
    __syncthreads();
    for (int idx = t; idx < 2048; idx += 256) {
      int c = idx >> 6, m = idx & 63;
      As[c][m] = (c < cl) ? src[((size_t)b * CINN + cc + c) * MM + m0 + m] : 0.0f;
    }
    for (int idx = t; idx < 2048; idx += 256) {
      int o = idx >> 5, c = idx & 31;
      Ws[c][o] = (c < cl && (o0 + o) < Cout) ? W[(size_t)(o0 + o) * CINN + cc + c] : 0.0f;
    }
    __syncthreads();
    #pragma unroll
    for (int c = 0; c < 32; ++c) {
      float4 avv = *(const float4*)&As[c][mg * 4];
      float4 wvv = *(const float4*)&Ws[c][og * 4];
      float a[4] = {avv.x, avv.y, avv.z, avv.w};
      float w[4] = {wvv.x, wvv.y, wvv.z, wvv.w};
      #pragma unroll
      for (int i = 0; i < 4; ++i)
        #pragma unroll
        for (int j = 0; j < 4; ++j) acc[i * 4 + j] += w[i] * a[j];
    }
  }
  #pragma unroll
  for (int i = 0; i < 4; ++i) {
    int o = o0 + og * 4 + i;
    if (o < Cout) {
      float bb = bias[o];
      float4 r;
      r.x = acc[i * 4 + 0] + bb; r.y = acc[i * 4 + 1] + bb;
      r.z = acc[i * 4 + 2] + bb; r.w = acc[i * 4 + 3] + bb;
      if (RELU) { r.x = fmaxf(r.x, 0.f); r.y = fmaxf(r.y, 0.f); r.z = fmaxf(r.z, 0.f); r.w = fmaxf(r.w, 0.f); }
      *(float4*)&dst[((size_t)b * Cout + o) * MM + m0 + mg * 4] = r;
    }
  }
}

// ---------------- BN stats for attention convs ----------------
__global__ __launch_bounds__(256) void k_bnstats(const float* __restrict__ src,
                                                 const float* __restrict__ g,
                                                 const float* __restrict__ be,
                                                 float* __restrict__ ab, int Cout) {
  int o = blockIdx.x;
  int t = threadIdx.x;
  float s = 0.f, s2 = 0.f;
  for (int b = 0; b < NB; ++b) {
    const float* r = src + ((size_t)b * Cout + o) * MM;
    for (int m = t; m < MM; m += 256) { float v = r[m]; s += v; s2 += v * v; }
  }
  __shared__ float rs[256], rs2[256];
  rs[t] = s; rs2[t] = s2;
  __syncthreads();
  for (int off = 128; off > 0; off >>= 1) {
    if (t < off) { rs[t] += rs[t + off]; rs2[t] += rs2[t + off]; }
    __syncthreads();
  }
  if (t == 0) {
    float cnt = 16384.0f;
    float mean = rs[0] / cnt, var = rs2[0] / cnt - mean * mean;
    float alpha = g[o] * rsqrtf(var + EPSBN);
    ab[o * 2] = alpha; ab[o * 2 + 1] = be[o] - mean * alpha;
  }
}

// ---------------- BN+relu+cvt, transposed layout: (B,32,MM) f32 -> (B,MM,32) bf16 ----------------
__global__ __launch_bounds__(256) void k_cvt_t(const float* __restrict__ src,
                                               const float* __restrict__ ab,
                                               unsigned short* __restrict__ dst) {
  int t = blockIdx.x * 256 + threadIdx.x;  // b*4096 + m
  int b = t >> 12, m = t & 4095;
  unsigned int row[16];
  #pragma unroll
  for (int c2 = 0; c2 < 16; ++c2) {
    int c0 = c2 * 2, c1 = c2 * 2 + 1;
    float v0 = fmaxf(fmaf(ab[c0 * 2], src[((size_t)b * 32 + c0) * MM + m], ab[c0 * 2 + 1]), 0.f);
    float v1 = fmaxf(fmaf(ab[c1 * 2], src[((size_t)b * 32 + c1) * MM + m], ab[c1 * 2 + 1]), 0.f);
    row[c2] = (unsigned int)f2bf(v0) | ((unsigned int)f2bf(v1) << 16);
  }
  uint4* dp = (uint4*)(dst + (size_t)t * 32);
  #pragma unroll
  for (int q = 0; q < 4; ++q) {
    uint4 v = {row[q * 4 + 0], row[q * 4 + 1], row[q * 4 + 2], row[q * 4 + 3]};
    dp[q] = v;
  }
}

// ---------------- BN+relu+cvt H: (B,130,MM) f32 -> (B,144,MM) bf16 (pad zeros) ----------------
__global__ __launch_bounds__(256) void k_cvtH(const float* __restrict__ src,
                                              const float* __restrict__ ab,
                                              unsigned short* __restrict__ dst) {
  int i = blockIdx.x * 256 + threadIdx.x;  // (b*144 + c)*1024 + m4
  int m4 = i & 1023; int c = (i >> 10) % 144; int b = i / (144 * 1024);
  ushort4 ov = {0, 0, 0, 0};
  if (c < 130) {
    float4 v = *(const float4*)&src[((size_t)b * 130 + c) * MM + m4 * 4];
    float a = ab[c * 2], be = ab[c * 2 + 1];
    ov.x = f2bf(fmaxf(fmaf(a, v.x, be), 0.f));
    ov.y = f2bf(fmaxf(fmaf(a, v.y, be), 0.f));
    ov.z = f2bf(fmaxf(fmaf(a, v.z, be), 0.f));
    ov.w = f2bf(fmaxf(fmaf(a, v.w, be), 0.f));
  }
  *(ushort4*)&dst[((size_t)b * 144 + c) * MM + m4 * 4] = ov;
}

// ---------------- K-LSE: MFMA S-tiles + online log2 max/sum -> LSE2 ----------------
// grid (64, NB), 256 thr (4 waves); wave w: rows n0 = bx*64 + w*16
__global__ __launch_bounds__(256) void k_zlse(const unsigned short* __restrict__ Ft,
                                              const unsigned short* __restrict__ Gt,
                                              float* __restrict__ LSE) {
  int t = threadIdx.x; int w = t >> 6; int l = t & 63;
  int b = blockIdx.y; int n0 = blockIdx.x * 64 + w * 16;
  int lm = l & 15, g = l >> 4;
  f32x4 z4 = {0.f, 0.f, 0.f, 0.f};
  short8 af = *(const short8*)&Gt[((size_t)b * MM + n0 + lm) * 32 + 8 * g];
  float rm[4], zz[4];
  #pragma unroll
  for (int r = 0; r < 4; ++r) { rm[r] = -__builtin_inff(); zz[r] = 0.f; }
  for (int m0 = 0; m0 < MM; m0 += 64) {
    short8 bf[4];
    #pragma unroll
    for (int mi = 0; mi < 4; ++mi)
      bf[mi] = *(const short8*)&Ft[((size_t)b * MM + m0 + mi * 16 + lm) * 32 + 8 * g];
    #pragma unroll
    for (int mi = 0; mi < 4; ++mi) {
      f32x4 d = MFMA16(af, bf[mi], z4);
      #pragma unroll
      for (int r = 0; r < 4; ++r) {
        float v = d[r] * LOG2E;
        float nm = fmaxf(rm[r], v);
        zz[r] = zz[r] * exp2f(rm[r] - nm) + exp2f(v - nm);
        rm[r] = nm;
      }
    }
  }
  // merge across the 16 m-lanes (same g group)
  #pragma unroll
  for (int off = 1; off < 16; off <<= 1) {
    #pragma unroll
    for (int r = 0; r < 4; ++r) {
      float om = __shfl_xor(rm[r], off);
      float oz = __shfl_xor(zz[r], off);
      float nm = fmaxf(rm[r], om);
      zz[r] = zz[r] * exp2f(rm[r] - nm) + oz * exp2f(om - nm);
      rm[r] = nm;
    }
  }
  if (lm == 0) {
    float4 o;
    o.x = rm[0] + log2f(zz[0]); o.y = rm[1] + log2f(zz[1]);
    o.z = rm[2] + log2f(zz[2]); o.w = rm[3] + log2f(zz[3]);
    *(float4*)&LSE[(size_t)b * MM + n0 + 4 * g] = o;
  }
}

// ---------------- K-O: MFMA O-pass (S recompute -> P -> PV), n-split partials ----------------
// grid (64 mtiles, NB, 2 splits), 256 thr (4 indep waves); wave w: cols m0 = bx*64 + w*16
__global__ __launch_bounds__(256) void k_omfma(const unsigned short* __restrict__ Ft,
                                               const unsigned short* __restrict__ Gt,
                                               const unsigned short* __restrict__ Hb,
                                               const float* __restrict__ LSE,
                                               float* __restrict__ Opart) {
  __shared__ __align__(16) unsigned short Pt[4][16][32];  // per-wave, XOR-swizzled
  int t = threadIdx.x; int w = t >> 6; int l = t & 63;
  int b = blockIdx.y; int split = blockIdx.z;
  int lm = l & 15, g = l >> 4;
  int mcol = blockIdx.x * 64 + w * 16 + lm;
  f32x4 z4 = {0.f, 0.f, 0.f, 0.f};
  short8 Ff = *(const short8*)&Ft[((size_t)b * MM + mcol) * 32 + 8 * g];
  f32x4 acc[9];
  #pragma unroll
  for (int ct = 0; ct < 9; ++ct) acc[ct] = z4;
  const int start = split * 2048, end = start + 2048;
  const unsigned short* gbase = Gt + (size_t)b * MM * 32 + lm * 32 + 8 * g;
  const unsigned short* hbase = Hb + ((size_t)b * 144 + lm) * MM + 8 * g;
  const float* lbase = LSE + (size_t)b * MM + 4 * g;
  char* ptb = (char*)&Pt[w][0][0];
  unsigned int wswz = (unsigned int)(lm * 64) ^ (((unsigned int)lm & 3u) << 4);

  short8 a0 = *(const short8*)(gbase + (size_t)start * 32);
  short8 a1 = *(const short8*)(gbase + (size_t)(start + 16) * 32);
  float4 l0 = *(const float4*)(lbase + start);
  float4 l1 = *(const float4*)(lbase + start + 16);

  for (int n0 = start; n0 < end; n0 += 32) {
    f32x4 s0 = MFMA16(a0, Ff, z4);
    f32x4 s1 = MFMA16(a1, Ff, z4);
    int nn = (n0 + 32 < end) ? (n0 + 32) : start;
    a0 = *(const short8*)(gbase + (size_t)nn * 32);
    a1 = *(const short8*)(gbase + (size_t)(nn + 16) * 32);
    float4 nl0 = *(const float4*)(lbase + nn);
    float4 nl1 = *(const float4*)(lbase + nn + 16);
    // p = exp2(s*log2e - lse2), pack to bf16
    float le0[4] = {l0.x, l0.y, l0.z, l0.w};
    float le1[4] = {l1.x, l1.y, l1.z, l1.w};
    unsigned int pk0[2], pk1[2];
    #pragma unroll
    for (int h = 0; h < 2; ++h) {
      float p0a = exp2f(fmaf(s0[2 * h], LOG2E, -le0[2 * h]));
      float p0b = exp2f(fmaf(s0[2 * h + 1], LOG2E, -le0[2 * h + 1]));
      float p1a = exp2f(fmaf(s1[2 * h], LOG2E, -le1[2 * h]));
      float p1b = exp2f(fmaf(s1[2 * h + 1], LOG2E, -le1[2 * h + 1]));
      pk0[h] = (unsigned int)f2bf(p0a) | ((unsigned int)f2bf(p0b) << 16);
      pk1[h] = (unsigned int)f2bf(p1a) | ((unsigned int)f2bf(p1b) << 16);
    }
    l0 = nl0; l1 = nl1;
    // Pt[m=lm][4g..4g+3] = tile0 rows; [16+4g..] = tile1 rows (XOR-swz bits 4-5)
    uint2 w0 = {pk0[0], pk0[1]}, w1 = {pk1[0], pk1[1]};
    *(uint2*)(ptb + (((unsigned int)(g * 8)) ^ wswz)) = w0;
    *(uint2*)(ptb + (((unsigned int)(32 + g * 8)) ^ wswz)) = w1;
    short8 bfrag = *(const short8*)(ptb + (((unsigned int)(g * 16)) ^ wswz));
    const unsigned short* hp = hbase + n0;
    #pragma unroll
    for (int ct = 0; ct < 9; ++ct) {
      short8 hf = *(const short8*)(hp + (size_t)ct * 16 * MM);
      acc[ct] = MFMA16(hf, bfrag, acc[ct]);
    }
  }
  float* op = Opart + (size_t)split * 2129920 + (size_t)b * 130 * MM + mcol;
  #pragma unroll
  for (int ct = 0; ct < 9; ++ct) {
    #pragma unroll
    for (int r = 0; r < 4; ++r) {
      int c = ct * 16 + 4 * g + r;
      if (c < 130) op[(size_t)c * MM] = acc[ct][r];
    }
  }
}

// ---------------- O reduce: A = gamma*(O0+O1) + Xatt ----------------
__global__ __launch_bounds__(256) void k_ored(const float* __restrict__ Op,
                                              const float* __restrict__ Xatt,
                                              const float* __restrict__ gma,
                                              float* __restrict__ A) {
  size_t i = ((size_t)blockIdx.x * 256 + threadIdx.x) * 4;
  if (i >= (size_t)NB * 130 * MM) return;
  float gm = gma[0];
  float4 o0 = *(const float4*)&Op[i];
  float4 o1 = *(const float4*)&Op[2129920 + i];
  float4 xv = *(const float4*)&Xatt[i];
  float4 r;
  r.x = gm * (o0.x + o1.x) + xv.x;
  r.y = gm * (o0.y + o1.y) + xv.y;
  r.z = gm * (o0.z + o1.z) + xv.z;
  r.w = gm * (o0.w + o1.w) + xv.w;
  *(float4*)&A[i] = r;
}

extern "C" void kernel_launch(void* const* d_in, const int* in_sizes, int n_in,
                              void* d_out, int out_size, void* d_ws, size_t ws_size,
                              hipStream_t stream) {
  const float* inp = (const float*)d_in[0];
  const float* Wa  = (const float*)d_in[1];
  const float* gna = (const float*)d_in[2];
  const float* bta = (const float*)d_in[3];
  const float* Wb  = (const float*)d_in[4];
  const float* gnb = (const float*)d_in[5];
  const float* btb = (const float*)d_in[6];
  const float* Wf  = (const float*)d_in[7];
  const float* bf  = (const float*)d_in[8];
  const float* gf  = (const float*)d_in[9];
  const float* bef = (const float*)d_in[10];
  const float* Wg  = (const float*)d_in[11];
  const float* bg  = (const float*)d_in[12];
  const float* gg  = (const float*)d_in[13];
  const float* beg = (const float*)d_in[14];
  const float* Wh  = (const float*)d_in[15];
  const float* bh  = (const float*)d_in[16];
  const float* gh  = (const float*)d_in[17];
  const float* beh = (const float*)d_in[18];
  const float* gamma = (const float*)d_in[19];
  const float* W1  = (const float*)d_in[20];
  const float* b1  = (const float*)d_in[21];
  const float* W2  = (const float*)d_in[22];
  const float* b2  = (const float*)d_in[23];
  float* out = (float*)d_out;

  float* ws = (float*)d_ws;
  float* DIST = ws + OFF_BIG0;
  float* PQ   = ws + OFF_BIG0;
  float* A    = ws + OFF_BIG0;
  unsigned short* FT = (unsigned short*)(ws + OFF_FT);
  unsigned short* GT = (unsigned short*)(ws + OFF_GT);
  unsigned short* HB = (unsigned short*)(ws + OFF_HB);
  float* F0   = ws + OFF_BIG1;
  float* G0   = ws + OFF_BIG1 + 524288;
  float* H0   = ws + OFF_BIG1 + 1048576;
  float* OP   = ws + OFF_OP;
  float* Y1   = ws + OFF_BIG1;
  float* XN   = ws + OFF_XN;
  float* SQ   = ws + OFF_SQ;
  float* LSEB = ws + OFF_LSE;
  float* XATT = ws + OFF_XATT;
  float* SUMS = ws + OFF_SUMS;
  float* ABE  = ws + OFF_ABE;
  float* ABF  = ws + OFF_ABF;
  float* ABG  = ws + OFF_ABG;
  float* ABH  = ws + OFF_ABH;
  int*   KNNI = (int*)(ws + OFF_KNN);

  // 1. normalize ; 2. pairwise dist ; 3. knn
  k_norm<<<16, 256, 0, stream>>>(inp, XN, SQ);
  k_dist<<<dim3(16, 16, 4), 256, 0, stream>>>(XN, SQ, DIST);
  k_knn<<<4096, 64, 0, stream>>>(DIST, KNNI);
  // 4. P/Q ; 5-6. edge BN ; 7-8. apply + grid
  k_pq<<<dim3(16, 4, 8), 256, 0, stream>>>(inp, Wa, Wb, PQ);
  k_edge_stats<<<512, 256, 0, stream>>>(PQ, KNNI, SUMS);
  k_edge_fin<<<2, 256, 0, stream>>>(SUMS, gna, bta, gnb, btb, ABE);
  k_edge_apply<<<dim3(4, 256, 8), 256, 0, stream>>>(PQ, KNNI, ABE, XATT);
  k_grid<<<64, 256, 0, stream>>>(XATT);
  // 9. attention convs f,g,h (raw conv + bias)
  k_conv<130, false><<<dim3(64, 1, 4), 256, 0, stream>>>(XATT, Wf, bf, F0, 32);
  k_conv<130, false><<<dim3(64, 1, 4), 256, 0, stream>>>(XATT, Wg, bg, G0, 32);
  k_conv<130, false><<<dim3(64, 3, 4), 256, 0, stream>>>(XATT, Wh, bh, H0, 130);
  // 10. BN stats + fused apply/cvt to bf16 MFMA layouts
  k_bnstats<<<32, 256, 0, stream>>>(F0, gf, bef, ABF, 32);
  k_bnstats<<<32, 256, 0, stream>>>(G0, gg, beg, ABG, 32);
  k_bnstats<<<130, 256, 0, stream>>>(H0, gh, beh, ABH, 130);
  k_cvt_t<<<64, 256, 0, stream>>>(F0, ABF, FT);
  k_cvt_t<<<64, 256, 0, stream>>>(G0, ABG, GT);
  k_cvtH<<<2304, 256, 0, stream>>>(H0, ABH, HB);
  // 11. LSE ; 12. O-pass ; 13. reduce + residual
  k_zlse<<<dim3(64, 4), 256, 0, stream>>>(FT, GT, LSEB);
  k_omfma<<<dim3(64, 4, 2), 256, 0, stream>>>(FT, GT, HB, LSEB, OP);
  k_ored<<<2080, 256, 0, stream>>>(OP, XATT, gamma, A);
  // 14-15. final convs
  k_conv<130, true><<<dim3(64, 4, 4), 256, 0, stream>>>(A, W1, b1, Y1, 256);
  k_conv<256, true><<<dim3(64, 2, 4), 256, 0, stream>>>(Y1, W2, b2, out, 128);
}

// Round 3
// 442.530 us; speedup vs baseline: 2.9604x; 1.3894x over previous
//
#include <hip/hip_runtime.h>

namespace {
constexpr int NB = 4;      // batch
constexpr int CI = 128;    // input channels
constexpr int NP = 1024;   // points
constexpr int MM = 4096;   // N*UP
constexpr float EPSBN = 1e-5f;
constexpr float LOG2E = 1.4426950408889634f;

constexpr size_t OPS = 2162688;          // Opart split stride (B*MM*132)
// workspace offsets (floats)
constexpr size_t OFF_OP   = 0;           // 3*OPS = 6488064 (overlaid: DIST / Pm,Qm / Hraw,FGraw / Y1)
constexpr size_t OFF_DIST = 0;           // 4194304
constexpr size_t OFF_PM   = 0;           // 2097152
constexpr size_t OFF_QM   = 2097152;     // 2097152
constexpr size_t OFF_HRAW = 0;           // 2359296 (B,144,MM) f32
constexpr size_t OFF_FGRAW= 2359296;     // 1048576 (B,MM,64) f32  -> ends 3407872
constexpr size_t OFF_Y1   = 0;           // 2097152 shorts*? (B,MM,256) bf16 = 2097152 floats
constexpr size_t OFF_FGT  = 6488064;     // (B,MM,64) bf16 = 524288 floats
constexpr size_t OFF_HB   = 7012352;     // (B,144,MM) bf16 = 1179648 floats
constexpr size_t OFF_A16  = 6488064;     // (B,MM,160) bf16 = 1310720 floats (over FGT/HB after omfma)
constexpr size_t OFF_X16  = 8192000;     // (B,MM,160) bf16 = 1310720 floats
constexpr size_t OFF_LSE  = 9502720;     // 16384
constexpr size_t OFF_LSEP = 9519104;     // 4*16384*2 = 131072
constexpr size_t OFF_STATS= 9650176;     // 65536
constexpr size_t OFF_ABE  = 9715712;     // 1024
constexpr size_t OFF_ABFG = 9716736;     // 128
constexpr size_t OFF_ABH  = 9716864;     // 512
constexpr size_t OFF_FGP  = 9717376;     // 8192
constexpr size_t OFF_BIAS = 9725568;     // 640
constexpr size_t OFF_W16  = 9726208;     // 53504 (107008 shorts)
constexpr size_t OFF_KNN  = 9779712;     // 73728 ints
constexpr size_t OFF_XN   = 9853440;     // 524288
constexpr size_t OFF_SQ   = 10377728;    // 4096 -> ends 10381824
// W16 sub-offsets (shorts)
constexpr size_t W16_FG = 0;       // 64x160
constexpr size_t W16_H  = 10240;   // 144x160
constexpr size_t W16_C1 = 33280;   // 256x160
constexpr size_t W16_C2 = 74240;   // 128x256
// BIAS sub-offsets (floats)
constexpr size_t B_FG = 0, B_H = 64, B_C1 = 208, B_C2 = 464;
} // namespace

typedef __attribute__((ext_vector_type(8))) short short8;
typedef __attribute__((ext_vector_type(4))) float f32x4;
#define MFMA16(A, B, C) __builtin_amdgcn_mfma_f32_16x16x32_bf16(A, B, C, 0, 0, 0)

__device__ inline unsigned short f2bf(float x) {
  unsigned int u = __float_as_uint(x);
  unsigned int r = u + 0x7fff + ((u >> 16) & 1);
  return (unsigned short)(r >> 16);
}
__device__ inline float bf2f(unsigned short s) {
  return __uint_as_float(((unsigned int)s) << 16);
}

// ---------------- prep: weights/biases -> padded bf16 ----------------
__global__ __launch_bounds__(256) void k_prep(const float* __restrict__ Wf, const float* __restrict__ Wg,
                                              const float* __restrict__ Wh, const float* __restrict__ W1,
                                              const float* __restrict__ W2, const float* __restrict__ bf,
                                              const float* __restrict__ bg, const float* __restrict__ bh,
                                              const float* __restrict__ b1, const float* __restrict__ b2,
                                              unsigned short* __restrict__ W16, float* __restrict__ BIAS) {
  int i = blockIdx.x * 256 + threadIdx.x;
  if (i < 107008) {
    float v = 0.f;
    if (i < 10240) { int o = i / 160, c = i % 160; if (c < 130) v = (o < 32) ? Wf[o * 130 + c] : Wg[(o - 32) * 130 + c]; }
    else if (i < 33280) { int r = i - 10240; int o = r / 160, c = r % 160; if (o < 130 && c < 130) v = Wh[o * 130 + c]; }
    else if (i < 74240) { int r = i - 33280; int o = r / 160, c = r % 160; if (c < 130) v = W1[o * 130 + c]; }
    else { int r = i - 74240; int o = r / 256, c = r % 256; v = W2[o * 256 + c]; }
    W16[i] = f2bf(v);
  } else if (i < 107648) {
    int j = i - 107008; float v = 0.f;
    if (j < 64) v = (j < 32) ? bf[j] : bg[j - 32];
    else if (j < 208) { int c = j - 64; if (c < 130) v = bh[c]; }
    else if (j < 464) v = b1[j - 208];
    else if (j < 592) v = b2[j - 464];
    BIAS[j] = v;
  }
}

// ---------------- K1: normalize features, per-point sq ----------------
__global__ __launch_bounds__(256) void k_norm(const float* __restrict__ x,
                                              float* __restrict__ xn,
                                              float* __restrict__ sq) {
  int t = blockIdx.x * 256 + threadIdx.x;
  int b = t >> 10, n = t & 1023;
  const float* xb = x + (size_t)b * CI * NP + n;
  float ss = 0.f;
  #pragma unroll 4
  for (int c = 0; c < CI; ++c) { float v = xb[(size_t)c * NP]; ss += v * v; }
  float inv = 1.f / fmaxf(sqrtf(ss), 1e-12f);
  float* xo = xn + (size_t)b * CI * NP + n;
  float s2 = 0.f;
  #pragma unroll 4
  for (int c = 0; c < CI; ++c) { float v = xb[(size_t)c * NP] * inv; xo[(size_t)c * NP] = v; s2 += v * v; }
  sq[t] = s2;
}

// ---------------- K2: pairwise distance ----------------
__global__ __launch_bounds__(256) void k_dist(const float* __restrict__ xn,
                                              const float* __restrict__ sq,
                                              float* __restrict__ dist) {
  __shared__ float As[32][68], Bs[32][68];
  int t = threadIdx.x;
  int m0 = blockIdx.x * 64, n0 = blockIdx.y * 64, b = blockIdx.z;
  int mg = t & 15, ng = t >> 4;
  float acc[16];
  #pragma unroll
  for (int i = 0; i < 16; ++i) acc[i] = 0.f;
  for (int cc = 0; cc < 128; cc += 32) {
    __syncthreads();
    for (int idx = t; idx < 2048; idx += 256) {
      int c = idx >> 6, j = idx & 63;
      As[c][j] = xn[((size_t)b * CI + cc + c) * NP + n0 + j];
      Bs[c][j] = xn[((size_t)b * CI + cc + c) * NP + m0 + j];
    }
    __syncthreads();
    #pragma unroll
    for (int c = 0; c < 32; ++c) {
      float4 avv = *(const float4*)&As[c][ng * 4];
      float4 bvv = *(const float4*)&Bs[c][mg * 4];
      float a[4] = {avv.x, avv.y, avv.z, avv.w};
      float bb[4] = {bvv.x, bvv.y, bvv.z, bvv.w};
      #pragma unroll
      for (int i = 0; i < 4; ++i)
        #pragma unroll
        for (int j = 0; j < 4; ++j) acc[i * 4 + j] += a[i] * bb[j];
    }
  }
  #pragma unroll
  for (int i = 0; i < 4; ++i) {
    int n = n0 + ng * 4 + i;
    float sn = sq[b * NP + n];
    float4 r;
    r.x = sn + sq[b * NP + m0 + mg * 4 + 0] - 2.f * acc[i * 4 + 0];
    r.y = sn + sq[b * NP + m0 + mg * 4 + 1] - 2.f * acc[i * 4 + 1];
    r.z = sn + sq[b * NP + m0 + mg * 4 + 2] - 2.f * acc[i * 4 + 2];
    r.w = sn + sq[b * NP + m0 + mg * 4 + 3] - 2.f * acc[i * 4 + 3];
    *(float4*)&dist[((size_t)b * NP + n) * NP + m0 + mg * 4] = r;
  }
}

// ---------------- K3: top-18 nearest per row ----------------
__global__ __launch_bounds__(64) void k_knn(const float* __restrict__ dist,
                                            int* __restrict__ knn) {
  int row = blockIdx.x;
  int l = threadIdx.x;
  const float* dr = dist + (size_t)row * NP;
  float d[16];
  #pragma unroll
  for (int i = 0; i < 16; ++i) d[i] = dr[l + 64 * i];
  for (int s = 0; s < 18; ++s) {
    float best = __builtin_inff(); int bslot = -1;
    #pragma unroll
    for (int i = 0; i < 16; ++i) if (d[i] < best) { best = d[i]; bslot = i; }
    int bidx = (bslot >= 0) ? (l + 64 * bslot) : 0x7fffffff;
    float bd = best; int bi = bidx;
    #pragma unroll
    for (int off = 32; off > 0; off >>= 1) {
      float od = __shfl_xor(bd, off);
      int   oi = __shfl_xor(bi, off);
      if (od < bd || (od == bd && oi < bi)) { bd = od; bi = oi; }
    }
    if (l == 0) knn[row * 18 + s] = bi;
    if ((bi & 63) == l) d[bi >> 6] = __builtin_inff();
  }
}

// ---------------- K4: P/Q pre-GEMMs, m-major output ----------------
// grid (16 ntiles, 4 otiles, 8 = b*2+e), 256 thr. Pm/Qm: [e*4+b][n][o(256)]
__global__ __launch_bounds__(256) void k_pq(const float* __restrict__ x,
                                            const float* __restrict__ Wa,
                                            const float* __restrict__ Wb,
                                            float* __restrict__ Pm,
                                            float* __restrict__ Qm) {
  __shared__ float Xs[32][68], Wp[32][68], Wq[32][68];
  int t = threadIdx.x;
  int nt = blockIdx.x, ot = blockIdx.y, bz = blockIdx.z;
  int b = bz >> 1, e = bz & 1;
  const float* W = e ? Wb : Wa;
  int eb = e * 4 + b;
  int mg = t & 15, og = t >> 4;
  float accp[16], accq[16];
  #pragma unroll
  for (int i = 0; i < 16; ++i) { accp[i] = 0.f; accq[i] = 0.f; }
  for (int cc = 0; cc < 128; cc += 32) {
    __syncthreads();
    for (int idx = t; idx < 2048; idx += 256) {
      int c = idx >> 6, n = idx & 63;
      Xs[c][n] = x[((size_t)b * CI + cc + c) * NP + nt * 64 + n];
    }
    for (int idx = t; idx < 2048; idx += 256) {
      int o = idx >> 5, c = idx & 31;
      float w1 = W[(ot * 64 + o) * 256 + cc + c];
      float w2 = W[(ot * 64 + o) * 256 + 128 + cc + c];
      Wp[c][o] = w1 - w2; Wq[c][o] = w2;
    }
    __syncthreads();
    #pragma unroll
    for (int c = 0; c < 32; ++c) {
      float4 xv = *(const float4*)&Xs[c][mg * 4];
      float4 wp = *(const float4*)&Wp[c][og * 4];
      float4 wq = *(const float4*)&Wq[c][og * 4];
      float xa[4] = {xv.x, xv.y, xv.z, xv.w};
      float pa[4] = {wp.x, wp.y, wp.z, wp.w};
      float qa[4] = {wq.x, wq.y, wq.z, wq.w};
      #pragma unroll
      for (int i = 0; i < 4; ++i)
        #pragma unroll
        for (int j = 0; j < 4; ++j) { accp[i * 4 + j] += pa[i] * xa[j]; accq[i * 4 + j] += qa[i] * xa[j]; }
    }
  }
  #pragma unroll
  for (int j = 0; j < 4; ++j) {
    int n = nt * 64 + mg * 4 + j;
    int o0 = ot * 64 + og * 4;
    float4 rp = {accp[j], accp[4 + j], accp[8 + j], accp[12 + j]};
    float4 rq = {accq[j], accq[4 + j], accq[8 + j], accq[12 + j]};
    *(float4*)&Pm[((size_t)eb * 1024 + n) * 256 + o0] = rp;
    *(float4*)&Qm[((size_t)eb * 1024 + n) * 256 + o0] = rq;
  }
}

// ---------------- K5: edge BN stats partials ----------------
// grid (16 nchunks, 4 b, 2 e), 256 thr = o
__global__ __launch_bounds__(256) void k_edge_stats(const float* __restrict__ Pm,
                                                    const float* __restrict__ Qm,
                                                    const int* __restrict__ knn,
                                                    float* __restrict__ stats) {
  int o = threadIdx.x;
  int chunk = blockIdx.x, b = blockIdx.y, e = blockIdx.z;
  int eb = e * 4 + b;
  float s = 0.f, s2 = 0.f;
  for (int nn = 0; nn < 64; ++nn) {
    int n = chunk * 64 + nn;
    float p = Pm[((size_t)eb * 1024 + n) * 256 + o];
    const int* kn = knn + (b * 1024 + n) * 18;
    #pragma unroll
    for (int kk = 0; kk < 9; ++kk) {
      int j = kn[e ? 2 * kk : kk];
      float v = p + Qm[((size_t)eb * 1024 + j) * 256 + o];
      s += v; s2 += v * v;
    }
  }
  size_t idx = ((((size_t)e * 4 + b) * 16 + chunk) * 256 + o) * 2;
  stats[idx] = s; stats[idx + 1] = s2;
}

// ---------------- K6: finalize edge BN ----------------
__global__ __launch_bounds__(256) void k_edge_fin(const float* __restrict__ stats,
                                                  const float* __restrict__ gna, const float* __restrict__ bta,
                                                  const float* __restrict__ gnb, const float* __restrict__ btb,
                                                  float* __restrict__ ab) {
  int i = blockIdx.x * 256 + threadIdx.x;
  if (i >= 512) return;
  int e = i >> 8, o = i & 255;
  float s = 0.f, s2 = 0.f;
  for (int b = 0; b < 4; ++b)
    for (int ch = 0; ch < 16; ++ch) {
      size_t idx = ((((size_t)e * 4 + b) * 16 + ch) * 256 + o) * 2;
      s += stats[idx]; s2 += stats[idx + 1];
    }
  float cnt = 4.0f * 1024.0f * 9.0f;
  float mean = s / cnt;
  float var = s2 / cnt - mean * mean;
  float g = e ? gnb[o] : gna[o];
  float bt = e ? btb[o] : bta[o];
  float alpha = g * rsqrtf(var + EPSBN);
  ab[i * 2] = alpha; ab[i * 2 + 1] = bt - mean * alpha;
}

// ---------------- K7: edge apply + max-over-k -> X16 (B,MM,160) bf16 ----------------
// grid (1024 n, 4 b), 256 thr: t>>7 = e, t&127 = oo
__global__ __launch_bounds__(256) void k_edge_apply(const float* __restrict__ Pm,
                                                    const float* __restrict__ Qm,
                                                    const int* __restrict__ knn,
                                                    const float* __restrict__ ab,
                                                    unsigned short* __restrict__ X16) {
  __shared__ int knl[18];
  int t = threadIdx.x;
  int n = blockIdx.x, b = blockIdx.y;
  if (t < 18) knl[t] = knn[(b * 1024 + n) * 18 + t];
  __syncthreads();
  int e = t >> 7, oo = t & 127;
  int eb = e * 4 + b;
  const float* Pr = Pm + ((size_t)eb * 1024 + n) * 256;
  const float* Qb = Qm + (size_t)eb * 1024 * 256;
  float p0 = Pr[oo], p1 = Pr[oo + 128];
  float a0 = ab[(e * 256 + oo) * 2], be0 = ab[(e * 256 + oo) * 2 + 1];
  float a1 = ab[(e * 256 + oo + 128) * 2], be1 = ab[(e * 256 + oo + 128) * 2 + 1];
  float mx0 = -__builtin_inff(), mx1 = -__builtin_inff();
  #pragma unroll
  for (int kk = 0; kk < 9; ++kk) {
    int j = knl[e ? 2 * kk : kk];
    const float* Qr = Qb + (size_t)j * 256;
    mx0 = fmaxf(mx0, fmaf(a0, p0 + Qr[oo], be0));
    mx1 = fmaxf(mx1, fmaf(a1, p1 + Qr[oo + 128], be1));
  }
  int u0 = e << 1, u1 = (e << 1) | 1;
  X16[((size_t)b * MM + 4 * n + u0) * 160 + oo] = f2bf(fmaxf(mx0, 0.f));
  X16[((size_t)b * MM + 4 * n + u1) * 160 + oo] = f2bf(fmaxf(mx1, 0.f));
  // grid + pad channels (c 128..159) for all 4 u rows
  if (t < 128) {
    int u = t >> 5, c = 128 + (t & 31);
    int gr = n >> 8;
    float v = (c == 128) ? ((gr < 2) ? -0.2f : 0.2f) : (c == 129) ? ((gr & 1) ? 0.2f : -0.2f) : 0.f;
    X16[((size_t)b * MM + 4 * n + u) * 160 + c] = f2bf(v);
  }
}

// ---------------- MFMA 1x1 conv ----------------
// OUTMODE 0: f32 m-major (dstF, ld=outld) | 1: bf16 m-major relu | 2: f32 ch-major (rows param)
template <int KSTEPS, int CTPER, int OUTMODE, bool RELU>
__global__ __launch_bounds__(256) void k_convm(const unsigned short* __restrict__ src,
                                               const unsigned short* __restrict__ W16,
                                               const float* __restrict__ bias,
                                               float* __restrict__ dstF,
                                               unsigned short* __restrict__ dstB,
                                               int outld, int rows) {
  constexpr int LD = KSTEPS * 32;
  int t = threadIdx.x; int w = t >> 6; int l = t & 63;
  int lm = l & 15, g = l >> 4;
  int b = blockIdx.z; int ct0 = blockIdx.y * CTPER;
  int srow = blockIdx.x * 64 + w * 16 + lm;
  const unsigned short* sp = src + ((size_t)b * MM + srow) * LD + 8 * g;
  const unsigned short* wp = W16 + ((size_t)ct0 * 16 + lm) * LD + 8 * g;
  f32x4 acc[CTPER];
  #pragma unroll
  for (int i = 0; i < CTPER; ++i) acc[i] = {0.f, 0.f, 0.f, 0.f};
  #pragma unroll
  for (int cc = 0; cc < KSTEPS; ++cc) {
    short8 bfr = *(const short8*)(sp + cc * 32);
    #pragma unroll
    for (int ct = 0; ct < CTPER; ++ct) {
      short8 af = *(const short8*)(wp + (size_t)ct * 16 * LD + cc * 32);
      acc[ct] = MFMA16(af, bfr, acc[ct]);
    }
  }
  #pragma unroll
  for (int ct = 0; ct < CTPER; ++ct) {
    int o0 = (ct0 + ct) * 16 + 4 * g;
    float4 bv = *(const float4*)&bias[o0];
    float v[4] = {acc[ct][0] + bv.x, acc[ct][1] + bv.y, acc[ct][2] + bv.z, acc[ct][3] + bv.w};
    if (RELU) { v[0] = fmaxf(v[0], 0.f); v[1] = fmaxf(v[1], 0.f); v[2] = fmaxf(v[2], 0.f); v[3] = fmaxf(v[3], 0.f); }
    if (OUTMODE == 0) {
      float4 r = {v[0], v[1], v[2], v[3]};
      *(float4*)&dstF[((size_t)b * MM + srow) * outld + o0] = r;
    } else if (OUTMODE == 1) {
      uint2 pk;
      pk.x = (unsigned)f2bf(v[0]) | ((unsigned)f2bf(v[1]) << 16);
      pk.y = (unsigned)f2bf(v[2]) | ((unsigned)f2bf(v[3]) << 16);
      *(uint2*)&dstB[((size_t)b * MM + srow) * outld + o0] = pk;
    } else {
      #pragma unroll
      for (int r = 0; r < 4; ++r)
        dstF[((size_t)b * rows + o0 + r) * MM + srow] = v[r];
    }
  }
}

// ---------------- f/g BN stats partials over FGraw (B,MM,64) ----------------
__global__ __launch_bounds__(256) void k_fgstats(const float* __restrict__ FGraw,
                                                 float* __restrict__ FGP) {
  __shared__ float red[4][64][2];
  int t = threadIdx.x; int c = t & 63, rq = t >> 6;
  int blk = blockIdx.x;
  float s = 0.f, s2 = 0.f;
  for (int k = 0; k < 64; ++k) {
    int r = blk * 256 + rq + 4 * k;
    float v = FGraw[(size_t)r * 64 + c];
    s += v; s2 += v * v;
  }
  red[rq][c][0] = s; red[rq][c][1] = s2;
  __syncthreads();
  if (t < 64) {
    float a = 0.f, a2 = 0.f;
    #pragma unroll
    for (int q = 0; q < 4; ++q) { a += red[q][t][0]; a2 += red[q][t][1]; }
    FGP[((size_t)blk * 64 + t) * 2] = a; FGP[((size_t)blk * 64 + t) * 2 + 1] = a2;
  }
}

__global__ __launch_bounds__(64) void k_fgfin(const float* __restrict__ FGP,
                                              const float* __restrict__ gf, const float* __restrict__ bef,
                                              const float* __restrict__ gg, const float* __restrict__ beg,
                                              float* __restrict__ ab) {
  int c = threadIdx.x;
  float s = 0.f, s2 = 0.f;
  for (int blk = 0; blk < 64; ++blk) { s += FGP[((size_t)blk * 64 + c) * 2]; s2 += FGP[((size_t)blk * 64 + c) * 2 + 1]; }
  float cnt = 16384.f;
  float mean = s / cnt, var = s2 / cnt - mean * mean;
  float gv = (c < 32) ? gf[c] : gg[c - 32];
  float bv = (c < 32) ? bef[c] : beg[c - 32];
  float alpha = gv * rsqrtf(var + EPSBN);
  ab[c * 2] = alpha; ab[c * 2 + 1] = bv - mean * alpha;
}

// ---------------- H BN stats (ch-major) ----------------
__global__ __launch_bounds__(256) void k_bnstats(const float* __restrict__ src,
                                                 const float* __restrict__ g,
                                                 const float* __restrict__ be,
                                                 float* __restrict__ ab, int ldC) {
  int o = blockIdx.x;
  int t = threadIdx.x;
  float s = 0.f, s2 = 0.f;
  for (int b = 0; b < NB; ++b) {
    const float* r = src + ((size_t)b * ldC + o) * MM;
    for (int m = t; m < MM; m += 256) { float v = r[m]; s += v; s2 += v * v; }
  }
  __shared__ float rs[256], rs2[256];
  rs[t] = s; rs2[t] = s2;
  __syncthreads();
  for (int off = 128; off > 0; off >>= 1) {
    if (t < off) { rs[t] += rs[t + off]; rs2[t] += rs2[t + off]; }
    __syncthreads();
  }
  if (t == 0) {
    float cnt = 16384.0f;
    float mean = rs[0] / cnt, var = rs2[0] / cnt - mean * mean;
    float alpha = g[o] * rsqrtf(var + EPSBN);
    ab[o * 2] = alpha; ab[o * 2 + 1] = be[o] - mean * alpha;
  }
}

// ---------------- cvt FGraw -> FGT bf16 (BN+relu) ----------------
__global__ __launch_bounds__(256) void k_cvtFG(const float* __restrict__ FGraw,
                                               const float* __restrict__ ab,
                                               unsigned short* __restrict__ FGT) {
  int i = blockIdx.x * 256 + threadIdx.x;  // < 131072
  int row = i >> 3, c0 = (i & 7) * 8;
  float vv[8];
  float4 u0 = *(const float4*)&FGraw[(size_t)row * 64 + c0];
  float4 u1 = *(const float4*)&FGraw[(size_t)row * 64 + c0 + 4];
  vv[0] = u0.x; vv[1] = u0.y; vv[2] = u0.z; vv[3] = u0.w;
  vv[4] = u1.x; vv[5] = u1.y; vv[6] = u1.z; vv[7] = u1.w;
  uint4 pk;
  unsigned pw[4];
  #pragma unroll
  for (int h = 0; h < 4; ++h) {
    int c = c0 + 2 * h;
    float a0 = ab[c * 2], b0 = ab[c * 2 + 1];
    float a1 = ab[(c + 1) * 2], b1 = ab[(c + 1) * 2 + 1];
    float x0 = fmaxf(fmaf(a0, vv[2 * h], b0), 0.f);
    float x1 = fmaxf(fmaf(a1, vv[2 * h + 1], b1), 0.f);
    pw[h] = (unsigned)f2bf(x0) | ((unsigned)f2bf(x1) << 16);
  }
  pk.x = pw[0]; pk.y = pw[1]; pk.z = pw[2]; pk.w = pw[3];
  *(uint4*)&FGT[(size_t)row * 64 + c0] = pk;
}

// ---------------- cvt Hraw -> HB bf16 (BN+relu, ch-major) ----------------
__global__ __launch_bounds__(256) void k_cvtH(const float* __restrict__ src,
                                              const float* __restrict__ ab,
                                              unsigned short* __restrict__ dst) {
  int i = blockIdx.x * 256 + threadIdx.x;  // (b*144 + c)*1024 + m4
  int m4 = i & 1023; int c = (i >> 10) % 144; int b = i / (144 * 1024);
  ushort4 ov = {0, 0, 0, 0};
  if (c < 130) {
    float4 v = *(const float4*)&src[((size_t)b * 144 + c) * MM + m4 * 4];
    float a = ab[c * 2], be = ab[c * 2 + 1];
    ov.x = f2bf(fmaxf(fmaf(a, v.x, be), 0.f));
    ov.y = f2bf(fmaxf(fmaf(a, v.y, be), 0.f));
    ov.z = f2bf(fmaxf(fmaf(a, v.z, be), 0.f));
    ov.w = f2bf(fmaxf(fmaf(a, v.w, be), 0.f));
  }
  *(ushort4*)&dst[((size_t)b * 144 + c) * MM + m4 * 4] = ov;
}

// ---------------- K-LSE: MFMA S-tiles + online log2 max/sum, m-split partials ----------------
// grid (64 ntiles, 4 msplit, 4 b), 256 thr
__global__ __launch_bounds__(256) void k_zlse(const unsigned short* __restrict__ FGT,
                                              float* __restrict__ LSEP) {
  int t = threadIdx.x; int w = t >> 6; int l = t & 63;
  int b = blockIdx.z; int ms = blockIdx.y;
  int n0 = blockIdx.x * 64 + w * 16;
  int lm = l & 15, g = l >> 4;
  f32x4 z4 = {0.f, 0.f, 0.f, 0.f};
  short8 af = *(const short8*)&FGT[((size_t)b * MM + n0 + lm) * 64 + 32 + 8 * g];
  float rm[4], zz[4];
  #pragma unroll
  for (int r = 0; r < 4; ++r) { rm[r] = -__builtin_inff(); zz[r] = 0.f; }
  for (int it = 0; it < 16; ++it) {
    int m0 = ms * 1024 + it * 64;
    short8 bfr[4];
    #pragma unroll
    for (int mi = 0; mi < 4; ++mi)
      bfr[mi] = *(const short8*)&FGT[((size_t)b * MM + m0 + mi * 16 + lm) * 64 + 8 * g];
    #pragma unroll
    for (int mi = 0; mi < 4; ++mi) {
      f32x4 d = MFMA16(af, bfr[mi], z4);
      #pragma unroll
      for (int r = 0; r < 4; ++r) {
        float v = d[r] * LOG2E;
        float nm = fmaxf(rm[r], v);
        zz[r] = zz[r] * exp2f(rm[r] - nm) + exp2f(v - nm);
        rm[r] = nm;
      }
    }
  }
  #pragma unroll
  for (int off = 1; off < 16; off <<= 1) {
    #pragma unroll
    for (int r = 0; r < 4; ++r) {
      float om = __shfl_xor(rm[r], off);
      float oz = __shfl_xor(zz[r], off);
      float nm = fmaxf(rm[r], om);
      zz[r] = zz[r] * exp2f(rm[r] - nm) + oz * exp2f(om - nm);
      rm[r] = nm;
    }
  }
  if (lm == 0) {
    #pragma unroll
    for (int r = 0; r < 4; ++r) {
      int n = n0 + 4 * g + r;
      size_t idx = ((size_t)ms * 16384 + (size_t)b * MM + n) * 2;
      LSEP[idx] = rm[r]; LSEP[idx + 1] = zz[r];
    }
  }
}

// ---------------- merge LSE partials ----------------
__global__ __launch_bounds__(256) void k_lsered(const float* __restrict__ LSEP,
                                                float* __restrict__ LSE) {
  int bn = blockIdx.x * 256 + threadIdx.x;  // < 16384
  float rm = -__builtin_inff(), zz = 0.f;
  #pragma unroll
  for (int ms = 0; ms < 4; ++ms) {
    float m = LSEP[((size_t)ms * 16384 + bn) * 2];
    float z = LSEP[((size_t)ms * 16384 + bn) * 2 + 1];
    float nm = fmaxf(rm, m);
    zz = zz * exp2f(rm - nm) + z * exp2f(m - nm);
    rm = nm;
  }
  LSE[bn] = rm + log2f(zz);
}

// ---------------- K-O: MFMA O-pass, register shuffle P-transpose, 3 n-splits ----------------
// grid (64 mtiles, 4 b, 3 splits), 256 thr (4 indep waves)
__global__ __launch_bounds__(256) void k_omfma(const unsigned short* __restrict__ FGT,
                                               const unsigned short* __restrict__ HB,
                                               const float* __restrict__ LSE,
                                               float* __restrict__ Opart) {
  int t = threadIdx.x; int w = t >> 6; int l = t & 63;
  int b = blockIdx.y; int split = blockIdx.z;
  int lm = l & 15, g = l >> 4;
  int mcol = blockIdx.x * 64 + w * 16 + lm;
  f32x4 z4 = {0.f, 0.f, 0.f, 0.f};
  short8 Ff = *(const short8*)&FGT[((size_t)b * MM + mcol) * 64 + 8 * g];
  f32x4 acc[9];
  #pragma unroll
  for (int ct = 0; ct < 9; ++ct) acc[ct] = z4;
  const int start = split * 1376;
  const int len = (split == 2) ? 1344 : 1376;
  const int end = start + len;
  const unsigned short* gptr = FGT + ((size_t)b * MM + lm) * 64 + 32 + 8 * g;
  const unsigned short* hbase = HB + ((size_t)b * 144 + lm) * MM + 8 * g;
  const float* lbase = LSE + (size_t)b * MM + 4 * g;
  int src01 = lm + 16 * (2 * (g & 1));
  int src23 = src01 + 16;
  bool hi = g >= 2;

  short8 a0 = *(const short8*)(gptr + (size_t)start * 64);
  short8 a1 = *(const short8*)(gptr + (size_t)(start + 16) * 64);
  float4 l0 = *(const float4*)(lbase + start);
  float4 l1 = *(const float4*)(lbase + start + 16);

  for (int n0 = start; n0 < end; n0 += 32) {
    f32x4 s0 = MFMA16(a0, Ff, z4);
    f32x4 s1 = MFMA16(a1, Ff, z4);
    // H fragments for this n-chunk (independent of s)
    const unsigned short* hp = hbase + n0;
    short8 hf[9];
    #pragma unroll
    for (int ct = 0; ct < 9; ++ct) hf[ct] = *(const short8*)(hp + (size_t)ct * 16 * MM);
    // prefetch next chunk's a/l
    int nn = (n0 + 32 < end) ? (n0 + 32) : start;
    short8 na0 = *(const short8*)(gptr + (size_t)nn * 64);
    short8 na1 = *(const short8*)(gptr + (size_t)(nn + 16) * 64);
    float4 nl0 = *(const float4*)(lbase + nn);
    float4 nl1 = *(const float4*)(lbase + nn + 16);
    // p = exp2(s*log2e - lse2) -> packed bf16 pairs
    float le0[4] = {l0.x, l0.y, l0.z, l0.w};
    float le1[4] = {l1.x, l1.y, l1.z, l1.w};
    unsigned pk0[2], pk1[2];
    #pragma unroll
    for (int h2 = 0; h2 < 2; ++h2) {
      float p0a = exp2f(fmaf(s0[2 * h2], LOG2E, -le0[2 * h2]));
      float p0b = exp2f(fmaf(s0[2 * h2 + 1], LOG2E, -le0[2 * h2 + 1]));
      float p1a = exp2f(fmaf(s1[2 * h2], LOG2E, -le1[2 * h2]));
      float p1b = exp2f(fmaf(s1[2 * h2 + 1], LOG2E, -le1[2 * h2 + 1]));
      pk0[h2] = (unsigned)f2bf(p0a) | ((unsigned)f2bf(p0b) << 16);
      pk1[h2] = (unsigned)f2bf(p1a) | ((unsigned)f2bf(p1b) << 16);
    }
    a0 = na0; a1 = na1; l0 = nl0; l1 = nl1;
    // register P-transpose: B-frag words via lane shuffles (same lm, varying g)
    unsigned a0w = (unsigned)__shfl((int)pk0[0], src01);
    unsigned b0w = (unsigned)__shfl((int)pk1[0], src01);
    unsigned a1w = (unsigned)__shfl((int)pk0[1], src01);
    unsigned b1w = (unsigned)__shfl((int)pk1[1], src01);
    unsigned a2w = (unsigned)__shfl((int)pk0[0], src23);
    unsigned b2w = (unsigned)__shfl((int)pk1[0], src23);
    unsigned a3w = (unsigned)__shfl((int)pk0[1], src23);
    unsigned b3w = (unsigned)__shfl((int)pk1[1], src23);
    union { unsigned u[4]; short8 s; } bu;
    bu.u[0] = hi ? b0w : a0w; bu.u[1] = hi ? b1w : a1w;
    bu.u[2] = hi ? b2w : a2w; bu.u[3] = hi ? b3w : a3w;
    short8 bfrag = bu.s;
    #pragma unroll
    for (int ct = 0; ct < 9; ++ct) acc[ct] = MFMA16(hf[ct], bfrag, acc[ct]);
  }
  float* op = Opart + (size_t)split * OPS + ((size_t)b * MM + mcol) * 132;
  #pragma unroll
  for (int ct = 0; ct < 9; ++ct) {
    int c0 = ct * 16 + 4 * g;
    if (c0 < 132) {
      float4 r = {acc[ct][0], acc[ct][1], acc[ct][2], acc[ct][3]};
      *(float4*)&op[c0] = r;
    }
  }
}

// ---------------- O reduce: A16 = bf16(gamma*(O0+O1+O2) + X) ----------------
__global__ __launch_bounds__(256) void k_ored(const float* __restrict__ Op,
                                              const unsigned short* __restrict__ X16,
                                              const float* __restrict__ gma,
                                              unsigned short* __restrict__ A16) {
  int i = blockIdx.x * 256 + threadIdx.x;  // < 327680
  int row = i / 20, c8 = i % 20;
  int c0 = c8 * 8;
  unsigned short* ap = A16 + (size_t)row * 160 + c0;
  if (c0 >= 136) {
    uint4 z = {0, 0, 0, 0};
    *(uint4*)ap = z;
    return;
  }
  float gm = gma[0];
  float ov[8] = {0.f, 0.f, 0.f, 0.f, 0.f, 0.f, 0.f, 0.f};
  #pragma unroll
  for (int s = 0; s < 3; ++s) {
    const float* base = Op + (size_t)s * OPS + (size_t)row * 132 + c0;
    float4 u = *(const float4*)base;
    ov[0] += u.x; ov[1] += u.y; ov[2] += u.z; ov[3] += u.w;
    if (c0 + 4 < 132) {
      float4 v = *(const float4*)(base + 4);
      ov[4] += v.x; ov[5] += v.y; ov[6] += v.z; ov[7] += v.w;
    }
  }
  short8 xv = *(const short8*)(X16 + (size_t)row * 160 + c0);
  unsigned pw[4];
  #pragma unroll
  for (int h = 0; h < 4; ++h) {
    int ca = c0 + 2 * h, cb = c0 + 2 * h + 1;
    float xa = bf2f((unsigned short)xv[2 * h]);
    float xb = bf2f((unsigned short)xv[2 * h + 1]);
    float va = (ca < 132) ? (gm * ov[2 * h] + xa) : 0.f;
    float vb = (cb < 132) ? (gm * ov[2 * h + 1] + xb) : 0.f;
    pw[h] = (unsigned)f2bf(va) | ((unsigned)f2bf(vb) << 16);
  }
  uint4 pk = {pw[0], pw[1], pw[2], pw[3]};
  *(uint4*)ap = pk;
}

extern "C" void kernel_launch(void* const* d_in, const int* in_sizes, int n_in,
                              void* d_out, int out_size, void* d_ws, size_t ws_size,
                              hipStream_t stream) {
  const float* inp = (const float*)d_in[0];
  const float* Wa  = (const float*)d_in[1];
  const float* gna = (const float*)d_in[2];
  const float* bta = (const float*)d_in[3];
  const float* Wb  = (const float*)d_in[4];
  const float* gnb = (const float*)d_in[5];
  const float* btb = (const float*)d_in[6];
  const float* Wf  = (const float*)d_in[7];
  const float* bf  = (const float*)d_in[8];
  const float* gf  = (const float*)d_in[9];
  const float* bef = (const float*)d_in[10];
  const float* Wg  = (const float*)d_in[11];
  const float* bg  = (const float*)d_in[12];
  const float* gg  = (const float*)d_in[13];
  const float* beg = (const float*)d_in[14];
  const float* Wh  = (const float*)d_in[15];
  const float* bh  = (const float*)d_in[16];
  const float* gh  = (const float*)d_in[17];
  const float* beh = (const float*)d_in[18];
  const float* gamma = (const float*)d_in[19];
  const float* W1  = (const float*)d_in[20];
  const float* b1  = (const float*)d_in[21];
  const float* W2  = (const float*)d_in[22];
  const float* b2  = (const float*)d_in[23];
  float* out = (float*)d_out;

  float* ws = (float*)d_ws;
  float* DIST = ws + OFF_DIST;
  float* PM   = ws + OFF_PM;
  float* QM   = ws + OFF_QM;
  float* HRAW = ws + OFF_HRAW;
  float* FGRAW= ws + OFF_FGRAW;
  float* OP   = ws + OFF_OP;
  unsigned short* FGT = (unsigned short*)(ws + OFF_FGT);
  unsigned short* HBB = (unsigned short*)(ws + OFF_HB);
  unsigned short* A16 = (unsigned short*)(ws + OFF_A16);
  unsigned short* X16 = (unsigned short*)(ws + OFF_X16);
  unsigned short* Y1  = (unsigned short*)(ws + OFF_Y1);
  float* LSEB = ws + OFF_LSE;
  float* LSEP = ws + OFF_LSEP;
  float* STATS= ws + OFF_STATS;
  float* ABE  = ws + OFF_ABE;
  float* ABFG = ws + OFF_ABFG;
  float* ABH  = ws + OFF_ABH;
  float* FGP  = ws + OFF_FGP;
  float* BIAS = ws + OFF_BIAS;
  unsigned short* W16 = (unsigned short*)(ws + OFF_W16);
  int*   KNNI = (int*)(ws + OFF_KNN);
  float* XN   = ws + OFF_XN;
  float* SQ   = ws + OFF_SQ;

  // 0. weight prep (independent)
  k_prep<<<421, 256, 0, stream>>>(Wf, Wg, Wh, W1, W2, bf, bg, bh, b1, b2, W16, BIAS);
  // 1-3. normalize, dist, knn
  k_norm<<<16, 256, 0, stream>>>(inp, XN, SQ);
  k_dist<<<dim3(16, 16, 4), 256, 0, stream>>>(XN, SQ, DIST);
  k_knn<<<4096, 64, 0, stream>>>(DIST, KNNI);
  // 4. P/Q m-major (overwrites DIST) ; 5-6. edge BN ; 7. apply -> X16
  k_pq<<<dim3(16, 4, 8), 256, 0, stream>>>(inp, Wa, Wb, PM, QM);
  k_edge_stats<<<dim3(16, 4, 2), 256, 0, stream>>>(PM, QM, KNNI, STATS);
  k_edge_fin<<<2, 256, 0, stream>>>(STATS, gna, bta, gnb, btb, ABE);
  k_edge_apply<<<dim3(1024, 4), 256, 0, stream>>>(PM, QM, KNNI, ABE, X16);
  // 8. f+g conv (Cout 64) and h conv via MFMA (overwrite PM/QM region)
  k_convm<5, 2, 0, false><<<dim3(64, 2, 4), 256, 0, stream>>>(X16, W16 + W16_FG, BIAS + B_FG, FGRAW, nullptr, 64, 0);
  k_convm<5, 3, 2, false><<<dim3(64, 3, 4), 256, 0, stream>>>(X16, W16 + W16_H, BIAS + B_H, HRAW, nullptr, 0, 144);
  // 9. BN stats + cvt to bf16
  k_fgstats<<<64, 256, 0, stream>>>(FGRAW, FGP);
  k_fgfin<<<1, 64, 0, stream>>>(FGP, gf, bef, gg, beg, ABFG);
  k_bnstats<<<130, 256, 0, stream>>>(HRAW, gh, beh, ABH, 144);
  k_cvtFG<<<512, 256, 0, stream>>>(FGRAW, ABFG, FGT);
  k_cvtH<<<2304, 256, 0, stream>>>(HRAW, ABH, HBB);
  // 10. LSE (m-split) + merge ; 11. O-pass (3 n-splits) ; 12. reduce -> A16
  k_zlse<<<dim3(64, 4, 4), 256, 0, stream>>>(FGT, LSEP);
  k_lsered<<<64, 256, 0, stream>>>(LSEP, LSEB);
  k_omfma<<<dim3(64, 4, 3), 256, 0, stream>>>(FGT, HBB, LSEB, OP);
  k_ored<<<1280, 256, 0, stream>>>(OP, X16, gamma, A16);
  // 13-14. final convs (MFMA): conv1 -> Y1 bf16 (over OP), conv2 -> out
  k_convm<5, 8, 1, true><<<dim3(64, 2, 4), 256, 0, stream>>>(A16, W16 + W16_C1, BIAS + B_C1, nullptr, Y1, 256, 0);
  k_convm<8, 4, 2, true><<<dim3(64, 2, 4), 256, 0, stream>>>(Y1, W16 + W16_C2, BIAS + B_C2, out, nullptr, 0, 128);
}

// Round 4
// 366.320 us; speedup vs baseline: 3.5763x; 1.2080x over previous
//
#include <hip/hip_runtime.h>

namespace {
constexpr int NB = 4;      // batch
constexpr int CI = 128;    // input channels
constexpr int NP = 1024;   // points
constexpr int MM = 4096;   // N*UP
constexpr float EPSBN = 1e-5f;
constexpr float LOG2E = 1.4426950408889634f;

constexpr size_t OPS_SH = 2162688;       // Opart split stride in SHORTS (B*MM*132)
// workspace offsets (floats)
constexpr size_t OFF_OP   = 0;           // 6 bf16 splits = 6488064 floats exactly (overlaid: DIST / Pm,Qm / Hraw,FGraw / Y1)
constexpr size_t OFF_DIST = 0;           // 4194304
constexpr size_t OFF_PM   = 0;           // 2097152
constexpr size_t OFF_QM   = 2097152;     // 2097152
constexpr size_t OFF_HRAW = 0;           // 2359296 (B,144,MM) f32
constexpr size_t OFF_FGRAW= 2359296;     // 1048576 (B,MM,64) f32  -> ends 3407872
constexpr size_t OFF_Y1   = 0;           // (B,MM,256) bf16 = 2097152 floats
constexpr size_t OFF_FGT  = 6488064;     // (B,MM,64) bf16 = 524288 floats
constexpr size_t OFF_HB   = 7012352;     // (B,144,MM) bf16 = 1179648 floats
constexpr size_t OFF_A16  = 6488064;     // (B,MM,160) bf16 = 1310720 floats (over FGT/HB after omfma)
constexpr size_t OFF_X16  = 8192000;     // (B,MM,160) bf16 = 1310720 floats
constexpr size_t OFF_LSE  = 9502720;     // 16384
constexpr size_t OFF_LSEP = 9519104;     // 4*16384*2 = 131072
constexpr size_t OFF_STATS= 9650176;     // 65536
constexpr size_t OFF_ABE  = 9715712;     // 1024
constexpr size_t OFF_ABFG = 9716736;     // 128
constexpr size_t OFF_ABH  = 9716864;     // 512
constexpr size_t OFF_FGP  = 9717376;     // 8192
constexpr size_t OFF_BIAS = 9725568;     // 640
constexpr size_t OFF_W16  = 9726208;     // 53504 (107008 shorts)
constexpr size_t OFF_KNN  = 9779712;     // 73728 ints
constexpr size_t OFF_XN   = 9853440;     // 524288
constexpr size_t OFF_SQ   = 10377728;    // 4096 -> ends 10381824
// W16 sub-offsets (shorts)
constexpr size_t W16_FG = 0;       // 64x160
constexpr size_t W16_H  = 10240;   // 144x160
constexpr size_t W16_C1 = 33280;   // 256x160
constexpr size_t W16_C2 = 74240;   // 128x256
// BIAS sub-offsets (floats)
constexpr size_t B_FG = 0, B_H = 64, B_C1 = 208, B_C2 = 464;
} // namespace

typedef __attribute__((ext_vector_type(8))) short short8;
typedef __attribute__((ext_vector_type(4))) float f32x4;
#define MFMA16(A, B, C) __builtin_amdgcn_mfma_f32_16x16x32_bf16(A, B, C, 0, 0, 0)

__device__ inline unsigned short f2bf(float x) {
  unsigned int u = __float_as_uint(x);
  unsigned int r = u + 0x7fff + ((u >> 16) & 1);
  return (unsigned short)(r >> 16);
}
__device__ inline float bf2f(unsigned short s) {
  return __uint_as_float(((unsigned int)s) << 16);
}

// ---------------- prep: weights/biases -> padded bf16 ----------------
__global__ __launch_bounds__(256) void k_prep(const float* __restrict__ Wf, const float* __restrict__ Wg,
                                              const float* __restrict__ Wh, const float* __restrict__ W1,
                                              const float* __restrict__ W2, const float* __restrict__ bf,
                                              const float* __restrict__ bg, const float* __restrict__ bh,
                                              const float* __restrict__ b1, const float* __restrict__ b2,
                                              unsigned short* __restrict__ W16, float* __restrict__ BIAS) {
  int i = blockIdx.x * 256 + threadIdx.x;
  if (i < 107008) {
    float v = 0.f;
    if (i < 10240) { int o = i / 160, c = i % 160; if (c < 130) v = (o < 32) ? Wf[o * 130 + c] : Wg[(o - 32) * 130 + c]; }
    else if (i < 33280) { int r = i - 10240; int o = r / 160, c = r % 160; if (o < 130 && c < 130) v = Wh[o * 130 + c]; }
    else if (i < 74240) { int r = i - 33280; int o = r / 160, c = r % 160; if (c < 130) v = W1[o * 130 + c]; }
    else { int r = i - 74240; int o = r / 256, c = r % 256; v = W2[o * 256 + c]; }
    W16[i] = f2bf(v);
  } else if (i < 107648) {
    int j = i - 107008; float v = 0.f;
    if (j < 64) v = (j < 32) ? bf[j] : bg[j - 32];
    else if (j < 208) { int c = j - 64; if (c < 130) v = bh[c]; }
    else if (j < 464) v = b1[j - 208];
    else if (j < 592) v = b2[j - 464];
    BIAS[j] = v;
  }
}

// ---------------- K1: normalize features, per-point sq ----------------
__global__ __launch_bounds__(256) void k_norm(const float* __restrict__ x,
                                              float* __restrict__ xn,
                                              float* __restrict__ sq) {
  int t = blockIdx.x * 256 + threadIdx.x;
  int b = t >> 10, n = t & 1023;
  const float* xb = x + (size_t)b * CI * NP + n;
  float ss = 0.f;
  #pragma unroll 4
  for (int c = 0; c < CI; ++c) { float v = xb[(size_t)c * NP]; ss += v * v; }
  float inv = 1.f / fmaxf(sqrtf(ss), 1e-12f);
  float* xo = xn + (size_t)b * CI * NP + n;
  float s2 = 0.f;
  #pragma unroll 4
  for (int c = 0; c < CI; ++c) { float v = xb[(size_t)c * NP] * inv; xo[(size_t)c * NP] = v; s2 += v * v; }
  sq[t] = s2;
}

// ---------------- K2: pairwise distance ----------------
__global__ __launch_bounds__(256) void k_dist(const float* __restrict__ xn,
                                              const float* __restrict__ sq,
                                              float* __restrict__ dist) {
  __shared__ float As[32][68], Bs[32][68];
  int t = threadIdx.x;
  int m0 = blockIdx.x * 64, n0 = blockIdx.y * 64, b = blockIdx.z;
  int mg = t & 15, ng = t >> 4;
  float acc[16];
  #pragma unroll
  for (int i = 0; i < 16; ++i) acc[i] = 0.f;
  for (int cc = 0; cc < 128; cc += 32) {
    __syncthreads();
    for (int idx = t; idx < 2048; idx += 256) {
      int c = idx >> 6, j = idx & 63;
      As[c][j] = xn[((size_t)b * CI + cc + c) * NP + n0 + j];
      Bs[c][j] = xn[((size_t)b * CI + cc + c) * NP + m0 + j];
    }
    __syncthreads();
    #pragma unroll
    for (int c = 0; c < 32; ++c) {
      float4 avv = *(const float4*)&As[c][ng * 4];
      float4 bvv = *(const float4*)&Bs[c][mg * 4];
      float a[4] = {avv.x, avv.y, avv.z, avv.w};
      float bb[4] = {bvv.x, bvv.y, bvv.z, bvv.w};
      #pragma unroll
      for (int i = 0; i < 4; ++i)
        #pragma unroll
        for (int j = 0; j < 4; ++j) acc[i * 4 + j] += a[i] * bb[j];
    }
  }
  #pragma unroll
  for (int i = 0; i < 4; ++i) {
    int n = n0 + ng * 4 + i;
    float sn = sq[b * NP + n];
    float4 r;
    r.x = sn + sq[b * NP + m0 + mg * 4 + 0] - 2.f * acc[i * 4 + 0];
    r.y = sn + sq[b * NP + m0 + mg * 4 + 1] - 2.f * acc[i * 4 + 1];
    r.z = sn + sq[b * NP + m0 + mg * 4 + 2] - 2.f * acc[i * 4 + 2];
    r.w = sn + sq[b * NP + m0 + mg * 4 + 3] - 2.f * acc[i * 4 + 3];
    *(float4*)&dist[((size_t)b * NP + n) * NP + m0 + mg * 4] = r;
  }
}

// ---------------- K3: top-18 nearest per row ----------------
__global__ __launch_bounds__(64) void k_knn(const float* __restrict__ dist,
                                            int* __restrict__ knn) {
  int row = blockIdx.x;
  int l = threadIdx.x;
  const float* dr = dist + (size_t)row * NP;
  float d[16];
  #pragma unroll
  for (int i = 0; i < 16; ++i) d[i] = dr[l + 64 * i];
  for (int s = 0; s < 18; ++s) {
    float best = __builtin_inff(); int bslot = -1;
    #pragma unroll
    for (int i = 0; i < 16; ++i) if (d[i] < best) { best = d[i]; bslot = i; }
    int bidx = (bslot >= 0) ? (l + 64 * bslot) : 0x7fffffff;
    float bd = best; int bi = bidx;
    #pragma unroll
    for (int off = 32; off > 0; off >>= 1) {
      float od = __shfl_xor(bd, off);
      int   oi = __shfl_xor(bi, off);
      if (od < bd || (od == bd && oi < bi)) { bd = od; bi = oi; }
    }
    if (l == 0) knn[row * 18 + s] = bi;
    if ((bi & 63) == l) d[bi >> 6] = __builtin_inff();
  }
}

// ---------------- K4: P/Q pre-GEMMs, m-major output ----------------
__global__ __launch_bounds__(256) void k_pq(const float* __restrict__ x,
                                            const float* __restrict__ Wa,
                                            const float* __restrict__ Wb,
                                            float* __restrict__ Pm,
                                            float* __restrict__ Qm) {
  __shared__ float Xs[32][68], Wp[32][68], Wq[32][68];
  int t = threadIdx.x;
  int nt = blockIdx.x, ot = blockIdx.y, bz = blockIdx.z;
  int b = bz >> 1, e = bz & 1;
  const float* W = e ? Wb : Wa;
  int eb = e * 4 + b;
  int mg = t & 15, og = t >> 4;
  float accp[16], accq[16];
  #pragma unroll
  for (int i = 0; i < 16; ++i) { accp[i] = 0.f; accq[i] = 0.f; }
  for (int cc = 0; cc < 128; cc += 32) {
    __syncthreads();
    for (int idx = t; idx < 2048; idx += 256) {
      int c = idx >> 6, n = idx & 63;
      Xs[c][n] = x[((size_t)b * CI + cc + c) * NP + nt * 64 + n];
    }
    for (int idx = t; idx < 2048; idx += 256) {
      int o = idx >> 5, c = idx & 31;
      float w1 = W[(ot * 64 + o) * 256 + cc + c];
      float w2 = W[(ot * 64 + o) * 256 + 128 + cc + c];
      Wp[c][o] = w1 - w2; Wq[c][o] = w2;
    }
    __syncthreads();
    #pragma unroll
    for (int c = 0; c < 32; ++c) {
      float4 xv = *(const float4*)&Xs[c][mg * 4];
      float4 wp = *(const float4*)&Wp[c][og * 4];
      float4 wq = *(const float4*)&Wq[c][og * 4];
      float xa[4] = {xv.x, xv.y, xv.z, xv.w};
      float pa[4] = {wp.x, wp.y, wp.z, wp.w};
      float qa[4] = {wq.x, wq.y, wq.z, wq.w};
      #pragma unroll
      for (int i = 0; i < 4; ++i)
        #pragma unroll
        for (int j = 0; j < 4; ++j) { accp[i * 4 + j] += pa[i] * xa[j]; accq[i * 4 + j] += qa[i] * xa[j]; }
    }
  }
  #pragma unroll
  for (int j = 0; j < 4; ++j) {
    int n = nt * 64 + mg * 4 + j;
    int o0 = ot * 64 + og * 4;
    float4 rp = {accp[j], accp[4 + j], accp[8 + j], accp[12 + j]};
    float4 rq = {accq[j], accq[4 + j], accq[8 + j], accq[12 + j]};
    *(float4*)&Pm[((size_t)eb * 1024 + n) * 256 + o0] = rp;
    *(float4*)&Qm[((size_t)eb * 1024 + n) * 256 + o0] = rq;
  }
}

// ---------------- K5: edge BN stats partials ----------------
__global__ __launch_bounds__(256) void k_edge_stats(const float* __restrict__ Pm,
                                                    const float* __restrict__ Qm,
                                                    const int* __restrict__ knn,
                                                    float* __restrict__ stats) {
  int o = threadIdx.x;
  int chunk = blockIdx.x, b = blockIdx.y, e = blockIdx.z;
  int eb = e * 4 + b;
  float s = 0.f, s2 = 0.f;
  for (int nn = 0; nn < 64; ++nn) {
    int n = chunk * 64 + nn;
    float p = Pm[((size_t)eb * 1024 + n) * 256 + o];
    const int* kn = knn + (b * 1024 + n) * 18;
    #pragma unroll
    for (int kk = 0; kk < 9; ++kk) {
      int j = kn[e ? 2 * kk : kk];
      float v = p + Qm[((size_t)eb * 1024 + j) * 256 + o];
      s += v; s2 += v * v;
    }
  }
  size_t idx = ((((size_t)e * 4 + b) * 16 + chunk) * 256 + o) * 2;
  stats[idx] = s; stats[idx + 1] = s2;
}

// ---------------- K6: finalize edge BN ----------------
__global__ __launch_bounds__(256) void k_edge_fin(const float* __restrict__ stats,
                                                  const float* __restrict__ gna, const float* __restrict__ bta,
                                                  const float* __restrict__ gnb, const float* __restrict__ btb,
                                                  float* __restrict__ ab) {
  int i = blockIdx.x * 256 + threadIdx.x;
  if (i >= 512) return;
  int e = i >> 8, o = i & 255;
  float s = 0.f, s2 = 0.f;
  for (int b = 0; b < 4; ++b)
    for (int ch = 0; ch < 16; ++ch) {
      size_t idx = ((((size_t)e * 4 + b) * 16 + ch) * 256 + o) * 2;
      s += stats[idx]; s2 += stats[idx + 1];
    }
  float cnt = 4.0f * 1024.0f * 9.0f;
  float mean = s / cnt;
  float var = s2 / cnt - mean * mean;
  float g = e ? gnb[o] : gna[o];
  float bt = e ? btb[o] : bta[o];
  float alpha = g * rsqrtf(var + EPSBN);
  ab[i * 2] = alpha; ab[i * 2 + 1] = bt - mean * alpha;
}

// ---------------- K7: edge apply + max-over-k -> X16 (B,MM,160) bf16 ----------------
__global__ __launch_bounds__(256) void k_edge_apply(const float* __restrict__ Pm,
                                                    const float* __restrict__ Qm,
                                                    const int* __restrict__ knn,
                                                    const float* __restrict__ ab,
                                                    unsigned short* __restrict__ X16) {
  __shared__ int knl[18];
  int t = threadIdx.x;
  int n = blockIdx.x, b = blockIdx.y;
  if (t < 18) knl[t] = knn[(b * 1024 + n) * 18 + t];
  __syncthreads();
  int e = t >> 7, oo = t & 127;
  int eb = e * 4 + b;
  const float* Pr = Pm + ((size_t)eb * 1024 + n) * 256;
  const float* Qb = Qm + (size_t)eb * 1024 * 256;
  float p0 = Pr[oo], p1 = Pr[oo + 128];
  float a0 = ab[(e * 256 + oo) * 2], be0 = ab[(e * 256 + oo) * 2 + 1];
  float a1 = ab[(e * 256 + oo + 128) * 2], be1 = ab[(e * 256 + oo + 128) * 2 + 1];
  float mx0 = -__builtin_inff(), mx1 = -__builtin_inff();
  #pragma unroll
  for (int kk = 0; kk < 9; ++kk) {
    int j = knl[e ? 2 * kk : kk];
    const float* Qr = Qb + (size_t)j * 256;
    mx0 = fmaxf(mx0, fmaf(a0, p0 + Qr[oo], be0));
    mx1 = fmaxf(mx1, fmaf(a1, p1 + Qr[oo + 128], be1));
  }
  int u0 = e << 1, u1 = (e << 1) | 1;
  X16[((size_t)b * MM + 4 * n + u0) * 160 + oo] = f2bf(fmaxf(mx0, 0.f));
  X16[((size_t)b * MM + 4 * n + u1) * 160 + oo] = f2bf(fmaxf(mx1, 0.f));
  if (t < 128) {
    int u = t >> 5, c = 128 + (t & 31);
    int gr = n >> 8;
    float v = (c == 128) ? ((gr < 2) ? -0.2f : 0.2f) : (c == 129) ? ((gr & 1) ? 0.2f : -0.2f) : 0.f;
    X16[((size_t)b * MM + 4 * n + u) * 160 + c] = f2bf(v);
  }
}

// ---------------- MFMA 1x1 conv ----------------
// OUTMODE 0: f32 m-major (dstF, ld=outld) | 1: bf16 m-major relu | 2: f32 ch-major (rows param)
template <int KSTEPS, int CTPER, int OUTMODE, bool RELU>
__global__ __launch_bounds__(256) void k_convm(const unsigned short* __restrict__ src,
                                               const unsigned short* __restrict__ W16,
                                               const float* __restrict__ bias,
                                               float* __restrict__ dstF,
                                               unsigned short* __restrict__ dstB,
                                               int outld, int rows) {
  constexpr int LD = KSTEPS * 32;
  int t = threadIdx.x; int w = t >> 6; int l = t & 63;
  int lm = l & 15, g = l >> 4;
  int b = blockIdx.z; int ct0 = blockIdx.y * CTPER;
  int srow = blockIdx.x * 64 + w * 16 + lm;
  const unsigned short* sp = src + ((size_t)b * MM + srow) * LD + 8 * g;
  const unsigned short* wp = W16 + ((size_t)ct0 * 16 + lm) * LD + 8 * g;
  f32x4 acc[CTPER];
  #pragma unroll
  for (int i = 0; i < CTPER; ++i) acc[i] = {0.f, 0.f, 0.f, 0.f};
  #pragma unroll
  for (int cc = 0; cc < KSTEPS; ++cc) {
    short8 bfr = *(const short8*)(sp + cc * 32);
    #pragma unroll
    for (int ct = 0; ct < CTPER; ++ct) {
      short8 af = *(const short8*)(wp + (size_t)ct * 16 * LD + cc * 32);
      acc[ct] = MFMA16(af, bfr, acc[ct]);
    }
  }
  #pragma unroll
  for (int ct = 0; ct < CTPER; ++ct) {
    int o0 = (ct0 + ct) * 16 + 4 * g;
    float4 bv = *(const float4*)&bias[o0];
    float v[4] = {acc[ct][0] + bv.x, acc[ct][1] + bv.y, acc[ct][2] + bv.z, acc[ct][3] + bv.w};
    if (RELU) { v[0] = fmaxf(v[0], 0.f); v[1] = fmaxf(v[1], 0.f); v[2] = fmaxf(v[2], 0.f); v[3] = fmaxf(v[3], 0.f); }
    if (OUTMODE == 0) {
      float4 r = {v[0], v[1], v[2], v[3]};
      *(float4*)&dstF[((size_t)b * MM + srow) * outld + o0] = r;
    } else if (OUTMODE == 1) {
      uint2 pk;
      pk.x = (unsigned)f2bf(v[0]) | ((unsigned)f2bf(v[1]) << 16);
      pk.y = (unsigned)f2bf(v[2]) | ((unsigned)f2bf(v[3]) << 16);
      *(uint2*)&dstB[((size_t)b * MM + srow) * outld + o0] = pk;
    } else {
      #pragma unroll
      for (int r = 0; r < 4; ++r)
        dstF[((size_t)b * rows + o0 + r) * MM + srow] = v[r];
    }
  }
}

// ---------------- f/g BN stats partials over FGraw (B,MM,64) ----------------
__global__ __launch_bounds__(256) void k_fgstats(const float* __restrict__ FGraw,
                                                 float* __restrict__ FGP) {
  __shared__ float red[4][64][2];
  int t = threadIdx.x; int c = t & 63, rq = t >> 6;
  int blk = blockIdx.x;
  float s = 0.f, s2 = 0.f;
  for (int k = 0; k < 64; ++k) {
    int r = blk * 256 + rq + 4 * k;
    float v = FGraw[(size_t)r * 64 + c];
    s += v; s2 += v * v;
  }
  red[rq][c][0] = s; red[rq][c][1] = s2;
  __syncthreads();
  if (t < 64) {
    float a = 0.f, a2 = 0.f;
    #pragma unroll
    for (int q = 0; q < 4; ++q) { a += red[q][t][0]; a2 += red[q][t][1]; }
    FGP[((size_t)blk * 64 + t) * 2] = a; FGP[((size_t)blk * 64 + t) * 2 + 1] = a2;
  }
}

__global__ __launch_bounds__(64) void k_fgfin(const float* __restrict__ FGP,
                                              const float* __restrict__ gf, const float* __restrict__ bef,
                                              const float* __restrict__ gg, const float* __restrict__ beg,
                                              float* __restrict__ ab) {
  int c = threadIdx.x;
  float s = 0.f, s2 = 0.f;
  for (int blk = 0; blk < 64; ++blk) { s += FGP[((size_t)blk * 64 + c) * 2]; s2 += FGP[((size_t)blk * 64 + c) * 2 + 1]; }
  float cnt = 16384.f;
  float mean = s / cnt, var = s2 / cnt - mean * mean;
  float gv = (c < 32) ? gf[c] : gg[c - 32];
  float bv = (c < 32) ? bef[c] : beg[c - 32];
  float alpha = gv * rsqrtf(var + EPSBN);
  ab[c * 2] = alpha; ab[c * 2 + 1] = bv - mean * alpha;
}

// ---------------- H BN stats (ch-major) ----------------
__global__ __launch_bounds__(256) void k_bnstats(const float* __restrict__ src,
                                                 const float* __restrict__ g,
                                                 const float* __restrict__ be,
                                                 float* __restrict__ ab, int ldC) {
  int o = blockIdx.x;
  int t = threadIdx.x;
  float s = 0.f, s2 = 0.f;
  for (int b = 0; b < NB; ++b) {
    const float* r = src + ((size_t)b * ldC + o) * MM;
    for (int m = t; m < MM; m += 256) { float v = r[m]; s += v; s2 += v * v; }
  }
  __shared__ float rs[256], rs2[256];
  rs[t] = s; rs2[t] = s2;
  __syncthreads();
  for (int off = 128; off > 0; off >>= 1) {
    if (t < off) { rs[t] += rs[t + off]; rs2[t] += rs2[t + off]; }
    __syncthreads();
  }
  if (t == 0) {
    float cnt = 16384.0f;
    float mean = rs[0] / cnt, var = rs2[0] / cnt - mean * mean;
    float alpha = g[o] * rsqrtf(var + EPSBN);
    ab[o * 2] = alpha; ab[o * 2 + 1] = be[o] - mean * alpha;
  }
}

// ---------------- cvt FGraw -> FGT bf16 (BN+relu) ----------------
__global__ __launch_bounds__(256) void k_cvtFG(const float* __restrict__ FGraw,
                                               const float* __restrict__ ab,
                                               unsigned short* __restrict__ FGT) {
  int i = blockIdx.x * 256 + threadIdx.x;  // < 131072
  int row = i >> 3, c0 = (i & 7) * 8;
  float vv[8];
  float4 u0 = *(const float4*)&FGraw[(size_t)row * 64 + c0];
  float4 u1 = *(const float4*)&FGraw[(size_t)row * 64 + c0 + 4];
  vv[0] = u0.x; vv[1] = u0.y; vv[2] = u0.z; vv[3] = u0.w;
  vv[4] = u1.x; vv[5] = u1.y; vv[6] = u1.z; vv[7] = u1.w;
  uint4 pk;
  unsigned pw[4];
  #pragma unroll
  for (int h = 0; h < 4; ++h) {
    int c = c0 + 2 * h;
    float a0 = ab[c * 2], b0 = ab[c * 2 + 1];
    float a1 = ab[(c + 1) * 2], b1 = ab[(c + 1) * 2 + 1];
    float x0 = fmaxf(fmaf(a0, vv[2 * h], b0), 0.f);
    float x1 = fmaxf(fmaf(a1, vv[2 * h + 1], b1), 0.f);
    pw[h] = (unsigned)f2bf(x0) | ((unsigned)f2bf(x1) << 16);
  }
  pk.x = pw[0]; pk.y = pw[1]; pk.z = pw[2]; pk.w = pw[3];
  *(uint4*)&FGT[(size_t)row * 64 + c0] = pk;
}

// ---------------- cvt Hraw -> HB bf16 (BN+relu, ch-major) ----------------
__global__ __launch_bounds__(256) void k_cvtH(const float* __restrict__ src,
                                              const float* __restrict__ ab,
                                              unsigned short* __restrict__ dst) {
  int i = blockIdx.x * 256 + threadIdx.x;  // (b*144 + c)*1024 + m4
  int m4 = i & 1023; int c = (i >> 10) % 144; int b = i / (144 * 1024);
  ushort4 ov = {0, 0, 0, 0};
  if (c < 130) {
    float4 v = *(const float4*)&src[((size_t)b * 144 + c) * MM + m4 * 4];
    float a = ab[c * 2], be = ab[c * 2 + 1];
    ov.x = f2bf(fmaxf(fmaf(a, v.x, be), 0.f));
    ov.y = f2bf(fmaxf(fmaf(a, v.y, be), 0.f));
    ov.z = f2bf(fmaxf(fmaf(a, v.z, be), 0.f));
    ov.w = f2bf(fmaxf(fmaf(a, v.w, be), 0.f));
  }
  *(ushort4*)&dst[((size_t)b * 144 + c) * MM + m4 * 4] = ov;
}

// ---------------- K-LSE: MFMA S-tiles + online log2 max/sum, m-split partials ----------------
__global__ __launch_bounds__(256) void k_zlse(const unsigned short* __restrict__ FGT,
                                              float* __restrict__ LSEP) {
  int t = threadIdx.x; int w = t >> 6; int l = t & 63;
  int b = blockIdx.z; int ms = blockIdx.y;
  int n0 = blockIdx.x * 64 + w * 16;
  int lm = l & 15, g = l >> 4;
  f32x4 z4 = {0.f, 0.f, 0.f, 0.f};
  short8 af = *(const short8*)&FGT[((size_t)b * MM + n0 + lm) * 64 + 32 + 8 * g];
  float rm[4], zz[4];
  #pragma unroll
  for (int r = 0; r < 4; ++r) { rm[r] = -__builtin_inff(); zz[r] = 0.f; }
  for (int it = 0; it < 16; ++it) {
    int m0 = ms * 1024 + it * 64;
    short8 bfr[4];
    #pragma unroll
    for (int mi = 0; mi < 4; ++mi)
      bfr[mi] = *(const short8*)&FGT[((size_t)b * MM + m0 + mi * 16 + lm) * 64 + 8 * g];
    #pragma unroll
    for (int mi = 0; mi < 4; ++mi) {
      f32x4 d = MFMA16(af, bfr[mi], z4);
      #pragma unroll
      for (int r = 0; r < 4; ++r) {
        float v = d[r] * LOG2E;
        float nm = fmaxf(rm[r], v);
        zz[r] = zz[r] * exp2f(rm[r] - nm) + exp2f(v - nm);
        rm[r] = nm;
      }
    }
  }
  #pragma unroll
  for (int off = 1; off < 16; off <<= 1) {
    #pragma unroll
    for (int r = 0; r < 4; ++r) {
      float om = __shfl_xor(rm[r], off);
      float oz = __shfl_xor(zz[r], off);
      float nm = fmaxf(rm[r], om);
      zz[r] = zz[r] * exp2f(rm[r] - nm) + oz * exp2f(om - nm);
      rm[r] = nm;
    }
  }
  if (lm == 0) {
    #pragma unroll
    for (int r = 0; r < 4; ++r) {
      int n = n0 + 4 * g + r;
      size_t idx = ((size_t)ms * 16384 + (size_t)b * MM + n) * 2;
      LSEP[idx] = rm[r]; LSEP[idx + 1] = zz[r];
    }
  }
}

// ---------------- merge LSE partials ----------------
__global__ __launch_bounds__(256) void k_lsered(const float* __restrict__ LSEP,
                                                float* __restrict__ LSE) {
  int bn = blockIdx.x * 256 + threadIdx.x;  // < 16384
  float rm = -__builtin_inff(), zz = 0.f;
  #pragma unroll
  for (int ms = 0; ms < 4; ++ms) {
    float m = LSEP[((size_t)ms * 16384 + bn) * 2];
    float z = LSEP[((size_t)ms * 16384 + bn) * 2 + 1];
    float nm = fmaxf(rm, m);
    zz = zz * exp2f(rm - nm) + z * exp2f(m - nm);
    rm = nm;
  }
  LSE[bn] = rm + log2f(zz);
}

// ---------------- K-O: MFMA O-pass, 2 m-tiles/wave, 6 n-splits, bf16 partials ----------------
// grid (32 mblocks, 4 b, 6 splits), 256 thr (4 waves); wave w: cols bx*128 + w*32 + {0..15, 16..31}
__global__ __launch_bounds__(256) void k_omfma(const unsigned short* __restrict__ FGT,
                                               const unsigned short* __restrict__ HB,
                                               const float* __restrict__ LSE,
                                               unsigned short* __restrict__ Opart) {
  int t = threadIdx.x; int w = t >> 6; int l = t & 63;
  int b = blockIdx.y; int split = blockIdx.z;
  int lm = l & 15, g = l >> 4;
  int mcol0 = blockIdx.x * 128 + w * 32 + lm;
  int mcol1 = mcol0 + 16;
  f32x4 z4 = {0.f, 0.f, 0.f, 0.f};
  short8 Ff0 = *(const short8*)&FGT[((size_t)b * MM + mcol0) * 64 + 8 * g];
  short8 Ff1 = *(const short8*)&FGT[((size_t)b * MM + mcol1) * 64 + 8 * g];
  f32x4 acc0[9], acc1[9];
  #pragma unroll
  for (int ct = 0; ct < 9; ++ct) { acc0[ct] = z4; acc1[ct] = z4; }
  // split n-ranges: splits 0,1 -> 22 chunks of 32; splits 2..5 -> 21 chunks
  const int nchunks = (split < 2) ? 22 : 21;
  const int startc = split * 21 + ((split < 2) ? split : 2);
  const int start = startc * 32;
  const int end = start + nchunks * 32;
  const unsigned short* gptr = FGT + ((size_t)b * MM + lm) * 64 + 32 + 8 * g;
  const unsigned short* hbase = HB + ((size_t)b * 144 + lm) * MM + 8 * g;
  const float* lbase = LSE + (size_t)b * MM + 4 * g;
  int src01 = lm + 16 * (2 * (g & 1));
  int src23 = src01 + 16;
  bool hi = g >= 2;

  short8 a0 = *(const short8*)(gptr + (size_t)start * 64);
  short8 a1 = *(const short8*)(gptr + (size_t)(start + 16) * 64);
  float4 l0 = *(const float4*)(lbase + start);
  float4 l1 = *(const float4*)(lbase + start + 16);

  for (int n0 = start; n0 < end; n0 += 32) {
    // H fragments for this chunk (shared by both m-tiles)
    const unsigned short* hp = hbase + n0;
    short8 hf[9];
    #pragma unroll
    for (int ct = 0; ct < 9; ++ct) hf[ct] = *(const short8*)(hp + (size_t)ct * 16 * MM);
    // S tiles: 4 independent MFMAs
    f32x4 s00 = MFMA16(a0, Ff0, z4);
    f32x4 s10 = MFMA16(a1, Ff0, z4);
    f32x4 s01 = MFMA16(a0, Ff1, z4);
    f32x4 s11 = MFMA16(a1, Ff1, z4);
    // prefetch next chunk's G-frags / LSE
    int nn = (n0 + 32 < end) ? (n0 + 32) : start;
    short8 na0 = *(const short8*)(gptr + (size_t)nn * 64);
    short8 na1 = *(const short8*)(gptr + (size_t)(nn + 16) * 64);
    float4 nl0 = *(const float4*)(lbase + nn);
    float4 nl1 = *(const float4*)(lbase + nn + 16);
    // p = exp2(s*log2e - lse2) -> packed bf16 pairs
    float le0[4] = {l0.x, l0.y, l0.z, l0.w};
    float le1[4] = {l1.x, l1.y, l1.z, l1.w};
    unsigned pk00[2], pk10[2], pk01[2], pk11[2];
    #pragma unroll
    for (int h2 = 0; h2 < 2; ++h2) {
      float e00a = exp2f(fmaf(s00[2 * h2], LOG2E, -le0[2 * h2]));
      float e00b = exp2f(fmaf(s00[2 * h2 + 1], LOG2E, -le0[2 * h2 + 1]));
      float e10a = exp2f(fmaf(s10[2 * h2], LOG2E, -le1[2 * h2]));
      float e10b = exp2f(fmaf(s10[2 * h2 + 1], LOG2E, -le1[2 * h2 + 1]));
      float e01a = exp2f(fmaf(s01[2 * h2], LOG2E, -le0[2 * h2]));
      float e01b = exp2f(fmaf(s01[2 * h2 + 1], LOG2E, -le0[2 * h2 + 1]));
      float e11a = exp2f(fmaf(s11[2 * h2], LOG2E, -le1[2 * h2]));
      float e11b = exp2f(fmaf(s11[2 * h2 + 1], LOG2E, -le1[2 * h2 + 1]));
      pk00[h2] = (unsigned)f2bf(e00a) | ((unsigned)f2bf(e00b) << 16);
      pk10[h2] = (unsigned)f2bf(e10a) | ((unsigned)f2bf(e10b) << 16);
      pk01[h2] = (unsigned)f2bf(e01a) | ((unsigned)f2bf(e01b) << 16);
      pk11[h2] = (unsigned)f2bf(e11a) | ((unsigned)f2bf(e11b) << 16);
    }
    a0 = na0; a1 = na1; l0 = nl0; l1 = nl1;
    // register P-transpose for m-tile 0
    unsigned a0w = (unsigned)__shfl((int)pk00[0], src01);
    unsigned b0w = (unsigned)__shfl((int)pk10[0], src01);
    unsigned a1w = (unsigned)__shfl((int)pk00[1], src01);
    unsigned b1w = (unsigned)__shfl((int)pk10[1], src01);
    unsigned a2w = (unsigned)__shfl((int)pk00[0], src23);
    unsigned b2w = (unsigned)__shfl((int)pk10[0], src23);
    unsigned a3w = (unsigned)__shfl((int)pk00[1], src23);
    unsigned b3w = (unsigned)__shfl((int)pk10[1], src23);
    union { unsigned u[4]; short8 s; } bu0;
    bu0.u[0] = hi ? b0w : a0w; bu0.u[1] = hi ? b1w : a1w;
    bu0.u[2] = hi ? b2w : a2w; bu0.u[3] = hi ? b3w : a3w;
    short8 bfrag0 = bu0.s;
    // register P-transpose for m-tile 1
    unsigned c0w = (unsigned)__shfl((int)pk01[0], src01);
    unsigned d0w = (unsigned)__shfl((int)pk11[0], src01);
    unsigned c1w = (unsigned)__shfl((int)pk01[1], src01);
    unsigned d1w = (unsigned)__shfl((int)pk11[1], src01);
    unsigned c2w = (unsigned)__shfl((int)pk01[0], src23);
    unsigned d2w = (unsigned)__shfl((int)pk11[0], src23);
    unsigned c3w = (unsigned)__shfl((int)pk01[1], src23);
    unsigned d3w = (unsigned)__shfl((int)pk11[1], src23);
    union { unsigned u[4]; short8 s; } bu1;
    bu1.u[0] = hi ? d0w : c0w; bu1.u[1] = hi ? d1w : c1w;
    bu1.u[2] = hi ? d2w : c2w; bu1.u[3] = hi ? d3w : c3w;
    short8 bfrag1 = bu1.s;
    #pragma unroll
    for (int ct = 0; ct < 9; ++ct) {
      acc0[ct] = MFMA16(hf[ct], bfrag0, acc0[ct]);
      acc1[ct] = MFMA16(hf[ct], bfrag1, acc1[ct]);
    }
  }
  unsigned short* op0 = Opart + (size_t)split * OPS_SH + ((size_t)b * MM + mcol0) * 132;
  unsigned short* op1 = Opart + (size_t)split * OPS_SH + ((size_t)b * MM + mcol1) * 132;
  #pragma unroll
  for (int ct = 0; ct < 9; ++ct) {
    int c0 = ct * 16 + 4 * g;
    if (c0 < 132) {
      uint2 p0, p1;
      p0.x = (unsigned)f2bf(acc0[ct][0]) | ((unsigned)f2bf(acc0[ct][1]) << 16);
      p0.y = (unsigned)f2bf(acc0[ct][2]) | ((unsigned)f2bf(acc0[ct][3]) << 16);
      p1.x = (unsigned)f2bf(acc1[ct][0]) | ((unsigned)f2bf(acc1[ct][1]) << 16);
      p1.y = (unsigned)f2bf(acc1[ct][2]) | ((unsigned)f2bf(acc1[ct][3]) << 16);
      *(uint2*)&op0[c0] = p0;
      *(uint2*)&op1[c0] = p1;
    }
  }
}

// ---------------- O reduce: A16 = bf16(gamma*sum(Oparts) + X) ----------------
__global__ __launch_bounds__(256) void k_ored(const unsigned short* __restrict__ Op,
                                              const unsigned short* __restrict__ X16,
                                              const float* __restrict__ gma,
                                              unsigned short* __restrict__ A16) {
  int i = blockIdx.x * 256 + threadIdx.x;  // < 327680
  int row = i / 20, c8 = i % 20;
  int c0 = c8 * 8;
  unsigned short* ap = A16 + (size_t)row * 160 + c0;
  if (c0 >= 136) {
    uint4 z = {0, 0, 0, 0};
    *(uint4*)ap = z;
    return;
  }
  float gm = gma[0];
  float ov[8] = {0.f, 0.f, 0.f, 0.f, 0.f, 0.f, 0.f, 0.f};
  #pragma unroll
  for (int s = 0; s < 6; ++s) {
    const unsigned short* base = Op + (size_t)s * OPS_SH + (size_t)row * 132 + c0;
    uint2 u = *(const uint2*)base;
    ov[0] += bf2f((unsigned short)(u.x & 0xffff));
    ov[1] += bf2f((unsigned short)(u.x >> 16));
    ov[2] += bf2f((unsigned short)(u.y & 0xffff));
    ov[3] += bf2f((unsigned short)(u.y >> 16));
    if (c0 + 4 < 132) {
      uint2 v = *(const uint2*)(base + 4);
      ov[4] += bf2f((unsigned short)(v.x & 0xffff));
      ov[5] += bf2f((unsigned short)(v.x >> 16));
      ov[6] += bf2f((unsigned short)(v.y & 0xffff));
      ov[7] += bf2f((unsigned short)(v.y >> 16));
    }
  }
  short8 xv = *(const short8*)(X16 + (size_t)row * 160 + c0);
  unsigned pw[4];
  #pragma unroll
  for (int h = 0; h < 4; ++h) {
    int ca = c0 + 2 * h, cb = c0 + 2 * h + 1;
    float xa = bf2f((unsigned short)xv[2 * h]);
    float xb = bf2f((unsigned short)xv[2 * h + 1]);
    float va = (ca < 132) ? (gm * ov[2 * h] + xa) : 0.f;
    float vb = (cb < 132) ? (gm * ov[2 * h + 1] + xb) : 0.f;
    pw[h] = (unsigned)f2bf(va) | ((unsigned)f2bf(vb) << 16);
  }
  uint4 pk = {pw[0], pw[1], pw[2], pw[3]};
  *(uint4*)ap = pk;
}

extern "C" void kernel_launch(void* const* d_in, const int* in_sizes, int n_in,
                              void* d_out, int out_size, void* d_ws, size_t ws_size,
                              hipStream_t stream) {
  const float* inp = (const float*)d_in[0];
  const float* Wa  = (const float*)d_in[1];
  const float* gna = (const float*)d_in[2];
  const float* bta = (const float*)d_in[3];
  const float* Wb  = (const float*)d_in[4];
  const float* gnb = (const float*)d_in[5];
  const float* btb = (const float*)d_in[6];
  const float* Wf  = (const float*)d_in[7];
  const float* bf  = (const float*)d_in[8];
  const float* gf  = (const float*)d_in[9];
  const float* bef = (const float*)d_in[10];
  const float* Wg  = (const float*)d_in[11];
  const float* bg  = (const float*)d_in[12];
  const float* gg  = (const float*)d_in[13];
  const float* beg = (const float*)d_in[14];
  const float* Wh  = (const float*)d_in[15];
  const float* bh  = (const float*)d_in[16];
  const float* gh  = (const float*)d_in[17];
  const float* beh = (const float*)d_in[18];
  const float* gamma = (const float*)d_in[19];
  const float* W1  = (const float*)d_in[20];
  const float* b1  = (const float*)d_in[21];
  const float* W2  = (const float*)d_in[22];
  const float* b2  = (const float*)d_in[23];
  float* out = (float*)d_out;

  float* ws = (float*)d_ws;
  float* DIST = ws + OFF_DIST;
  float* PM   = ws + OFF_PM;
  float* QM   = ws + OFF_QM;
  float* HRAW = ws + OFF_HRAW;
  float* FGRAW= ws + OFF_FGRAW;
  unsigned short* OP16 = (unsigned short*)(ws + OFF_OP);
  unsigned short* FGT = (unsigned short*)(ws + OFF_FGT);
  unsigned short* HBB = (unsigned short*)(ws + OFF_HB);
  unsigned short* A16 = (unsigned short*)(ws + OFF_A16);
  unsigned short* X16 = (unsigned short*)(ws + OFF_X16);
  unsigned short* Y1  = (unsigned short*)(ws + OFF_Y1);
  float* LSEB = ws + OFF_LSE;
  float* LSEP = ws + OFF_LSEP;
  float* STATS= ws + OFF_STATS;
  float* ABE  = ws + OFF_ABE;
  float* ABFG = ws + OFF_ABFG;
  float* ABH  = ws + OFF_ABH;
  float* FGP  = ws + OFF_FGP;
  float* BIAS = ws + OFF_BIAS;
  unsigned short* W16 = (unsigned short*)(ws + OFF_W16);
  int*   KNNI = (int*)(ws + OFF_KNN);
  float* XN   = ws + OFF_XN;
  float* SQ   = ws + OFF_SQ;

  // 0. weight prep (independent)
  k_prep<<<421, 256, 0, stream>>>(Wf, Wg, Wh, W1, W2, bf, bg, bh, b1, b2, W16, BIAS);
  // 1-3. normalize, dist, knn
  k_norm<<<16, 256, 0, stream>>>(inp, XN, SQ);
  k_dist<<<dim3(16, 16, 4), 256, 0, stream>>>(XN, SQ, DIST);
  k_knn<<<4096, 64, 0, stream>>>(DIST, KNNI);
  // 4. P/Q m-major (overwrites DIST) ; 5-6. edge BN ; 7. apply -> X16
  k_pq<<<dim3(16, 4, 8), 256, 0, stream>>>(inp, Wa, Wb, PM, QM);
  k_edge_stats<<<dim3(16, 4, 2), 256, 0, stream>>>(PM, QM, KNNI, STATS);
  k_edge_fin<<<2, 256, 0, stream>>>(STATS, gna, bta, gnb, btb, ABE);
  k_edge_apply<<<dim3(1024, 4), 256, 0, stream>>>(PM, QM, KNNI, ABE, X16);
  // 8. f+g conv (Cout 64) and h conv via MFMA (overwrite PM/QM region)
  k_convm<5, 2, 0, false><<<dim3(64, 2, 4), 256, 0, stream>>>(X16, W16 + W16_FG, BIAS + B_FG, FGRAW, nullptr, 64, 0);
  k_convm<5, 3, 2, false><<<dim3(64, 3, 4), 256, 0, stream>>>(X16, W16 + W16_H, BIAS + B_H, HRAW, nullptr, 0, 144);
  // 9. BN stats + cvt to bf16
  k_fgstats<<<64, 256, 0, stream>>>(FGRAW, FGP);
  k_fgfin<<<1, 64, 0, stream>>>(FGP, gf, bef, gg, beg, ABFG);
  k_bnstats<<<130, 256, 0, stream>>>(HRAW, gh, beh, ABH, 144);
  k_cvtFG<<<512, 256, 0, stream>>>(FGRAW, ABFG, FGT);
  k_cvtH<<<2304, 256, 0, stream>>>(HRAW, ABH, HBB);
  // 10. LSE (m-split) + merge ; 11. O-pass ; 12. reduce -> A16
  k_zlse<<<dim3(64, 4, 4), 256, 0, stream>>>(FGT, LSEP);
  k_lsered<<<64, 256, 0, stream>>>(LSEP, LSEB);
  k_omfma<<<dim3(32, 4, 6), 256, 0, stream>>>(FGT, HBB, LSEB, OP16);
  k_ored<<<1280, 256, 0, stream>>>(OP16, X16, gamma, A16);
  // 13-14. final convs (MFMA): conv1 -> Y1 bf16 (over OP), conv2 -> out
  k_convm<5, 8, 1, true><<<dim3(64, 2, 4), 256, 0, stream>>>(A16, W16 + W16_C1, BIAS + B_C1, nullptr, Y1, 256, 0);
  k_convm<8, 4, 2, true><<<dim3(64, 2, 4), 256, 0, stream>>>(Y1, W16 + W16_C2, BIAS + B_C2, out, nullptr, 0, 128);
}

// Round 6
// 352.326 us; speedup vs baseline: 3.7183x; 1.0397x over previous
//
#include <hip/hip_runtime.h>

namespace {
constexpr int NB = 4;      // batch
constexpr int CI = 128;    // input channels
constexpr int NP = 1024;   // points
constexpr int MM = 4096;   // N*UP
constexpr float EPSBN = 1e-5f;
constexpr float LOG2E = 1.4426950408889634f;

constexpr size_t OPS_SH = 2162688;       // Opart split stride in SHORTS (B*MM*132)
// workspace offsets (floats)
constexpr size_t OFF_OP   = 0;           // 6 bf16 splits = 6488064 floats (overlaid: DIST / Pm,Qm / Hraw,FGraw / Y1)
constexpr size_t OFF_DIST = 0;           // 4194304
constexpr size_t OFF_PM   = 0;           // 2097152
constexpr size_t OFF_QM   = 2097152;     // 2097152
constexpr size_t OFF_HRAW = 0;           // 2359296 (B,144,MM) f32
constexpr size_t OFF_FGRAW= 2359296;     // 1048576 (B,MM,64) f32  -> ends 3407872
constexpr size_t OFF_Y1   = 0;           // (B,MM,256) bf16 = 2097152 floats
constexpr size_t OFF_FGT  = 6488064;     // (B,MM,64) bf16 = 524288 floats
constexpr size_t OFF_HB   = 7012352;     // (B,144,MM) bf16 = 1179648 floats
constexpr size_t OFF_A16  = 6488064;     // (B,MM,160) bf16 = 1310720 floats (over FGT/HB after omfma)
constexpr size_t OFF_X16  = 8192000;     // (B,MM,160) bf16 = 1310720 floats
constexpr size_t OFF_LSE  = 9502720;     // 16384
constexpr size_t OFF_LSEP = 9519104;     // 131072
constexpr size_t OFF_STATS= 9650176;     // 65536
constexpr size_t OFF_ABE  = 9715712;     // 1024
constexpr size_t OFF_ABFG = 9716736;     // 128
constexpr size_t OFF_ABH  = 9716864;     // 512
constexpr size_t OFF_FGP  = 9717376;     // 8192
constexpr size_t OFF_BIAS = 9725568;     // 640
constexpr size_t OFF_W16  = 9726208;     // 53504 (107008 shorts)
constexpr size_t OFF_KNN  = 9779712;     // 73728 ints
constexpr size_t OFF_XN   = 9853440;     // (B,128,1024) f32 = 524288 (normalized, ch-major, for fp32 dist)
constexpr size_t OFF_SQ   = 10377728;    // 4096
constexpr size_t OFF_XR   = 10381824;    // (B,1024,128) bf16 raw = 262144 floats
constexpr size_t OFF_WPQ  = 10643968;    // 65536 floats (131072 shorts) -> ends 10709504
// W16 sub-offsets (shorts)
constexpr size_t W16_FG = 0;       // 64x160
constexpr size_t W16_H  = 10240;   // 144x160
constexpr size_t W16_C1 = 33280;   // 256x160
constexpr size_t W16_C2 = 74240;   // 128x256
// BIAS sub-offsets (floats)
constexpr size_t B_FG = 0, B_H = 64, B_C1 = 208, B_C2 = 464;
} // namespace

typedef __attribute__((ext_vector_type(8))) short short8;
typedef __attribute__((ext_vector_type(4))) float f32x4;
#define MFMA16(A, B, C) __builtin_amdgcn_mfma_f32_16x16x32_bf16(A, B, C, 0, 0, 0)

__device__ inline unsigned short f2bf(float x) {
  unsigned int u = __float_as_uint(x);
  unsigned int r = u + 0x7fff + ((u >> 16) & 1);
  return (unsigned short)(r >> 16);
}
__device__ inline float bf2f(unsigned short s) {
  return __uint_as_float(((unsigned int)s) << 16);
}
__device__ inline unsigned cvtpk(float lo, float hi) {
  unsigned r;
  asm("v_cvt_pk_bf16_f32 %0, %1, %2" : "=v"(r) : "v"(lo), "v"(hi));
  return r;
}

// ---------------- prep: conv weights/biases -> padded bf16 ----------------
__global__ __launch_bounds__(256) void k_prep(const float* __restrict__ Wf, const float* __restrict__ Wg,
                                              const float* __restrict__ Wh, const float* __restrict__ W1,
                                              const float* __restrict__ W2, const float* __restrict__ bf,
                                              const float* __restrict__ bg, const float* __restrict__ bh,
                                              const float* __restrict__ b1, const float* __restrict__ b2,
                                              unsigned short* __restrict__ W16, float* __restrict__ BIAS) {
  int i = blockIdx.x * 256 + threadIdx.x;
  if (i < 107008) {
    float v = 0.f;
    if (i < 10240) { int o = i / 160, c = i % 160; if (c < 130) v = (o < 32) ? Wf[o * 130 + c] : Wg[(o - 32) * 130 + c]; }
    else if (i < 33280) { int r = i - 10240; int o = r / 160, c = r % 160; if (o < 130 && c < 130) v = Wh[o * 130 + c]; }
    else if (i < 74240) { int r = i - 33280; int o = r / 160, c = r % 160; if (c < 130) v = W1[o * 130 + c]; }
    else { int r = i - 74240; int o = r / 256, c = r % 256; v = W2[o * 256 + c]; }
    W16[i] = f2bf(v);
  } else if (i < 107648) {
    int j = i - 107008; float v = 0.f;
    if (j < 64) v = (j < 32) ? bf[j] : bg[j - 32];
    else if (j < 208) { int c = j - 64; if (c < 130) v = bh[c]; }
    else if (j < 464) v = b1[j - 208];
    else if (j < 592) v = b2[j - 464];
    BIAS[j] = v;
  }
}

// ---------------- prep2: edge-conv weights -> Wp/Wq bf16 [e][pq][256][128] ----------------
__global__ __launch_bounds__(256) void k_prep2(const float* __restrict__ Wa, const float* __restrict__ Wb,
                                               unsigned short* __restrict__ WPQ) {
  int i = blockIdx.x * 256 + threadIdx.x;  // < 131072
  int e = i >> 16;
  int rem = i & 65535;
  int pq = rem >> 15;
  int rr = rem & 32767;
  int o = rr >> 7, c = rr & 127;
  const float* W = e ? Wb : Wa;
  float w1 = W[o * 256 + c], w2 = W[o * 256 + 128 + c];
  float v = pq ? w2 : (w1 - w2);
  WPQ[i] = f2bf(v);
}

// ---------------- K1: normalize -> fp32 XN ch-major (for dist), raw bf16 n-major, sq ----------------
__global__ __launch_bounds__(256) void k_norm(const float* __restrict__ x,
                                              float* __restrict__ xn,
                                              unsigned short* __restrict__ XR,
                                              float* __restrict__ sq) {
  int t = blockIdx.x * 256 + threadIdx.x;   // b*1024+n
  int b = t >> 10, n = t & 1023;
  const float* xb = x + (size_t)b * CI * NP + n;
  float ss = 0.f;
  #pragma unroll 4
  for (int c = 0; c < CI; ++c) { float v = xb[(size_t)c * NP]; ss += v * v; }
  float inv = 1.f / fmaxf(sqrtf(ss), 1e-12f);
  float* xo = xn + (size_t)b * CI * NP + n;
  float s2 = 0.f;
  for (int c0 = 0; c0 < 128; c0 += 8) {
    unsigned rw[4];
    #pragma unroll
    for (int j = 0; j < 4; ++j) {
      float va = xb[(size_t)(c0 + 2 * j) * NP];
      float vb = xb[(size_t)(c0 + 2 * j + 1) * NP];
      float na = va * inv, nb = vb * inv;
      s2 += na * na + nb * nb;
      xo[(size_t)(c0 + 2 * j) * NP] = na;
      xo[(size_t)(c0 + 2 * j + 1) * NP] = nb;
      rw[j] = (unsigned)f2bf(va) | ((unsigned)f2bf(vb) << 16);
    }
    uint4 r4 = {rw[0], rw[1], rw[2], rw[3]};
    *(uint4*)&XR[(size_t)t * 128 + c0] = r4;
  }
  sq[t] = s2;
}

// ---------------- K2: pairwise distance, fp32 LDS-tiled (exact kNN path) ----------------
__global__ __launch_bounds__(256) void k_dist(const float* __restrict__ xn,
                                              const float* __restrict__ sq,
                                              float* __restrict__ dist) {
  __shared__ float As[32][68], Bs[32][68];
  int t = threadIdx.x;
  int m0 = blockIdx.x * 64, n0 = blockIdx.y * 64, b = blockIdx.z;
  int mg = t & 15, ng = t >> 4;
  float acc[16];
  #pragma unroll
  for (int i = 0; i < 16; ++i) acc[i] = 0.f;
  for (int cc = 0; cc < 128; cc += 32) {
    __syncthreads();
    for (int idx = t; idx < 2048; idx += 256) {
      int c = idx >> 6, j = idx & 63;
      As[c][j] = xn[((size_t)b * CI + cc + c) * NP + n0 + j];
      Bs[c][j] = xn[((size_t)b * CI + cc + c) * NP + m0 + j];
    }
    __syncthreads();
    #pragma unroll
    for (int c = 0; c < 32; ++c) {
      float4 avv = *(const float4*)&As[c][ng * 4];
      float4 bvv = *(const float4*)&Bs[c][mg * 4];
      float a[4] = {avv.x, avv.y, avv.z, avv.w};
      float bb[4] = {bvv.x, bvv.y, bvv.z, bvv.w};
      #pragma unroll
      for (int i = 0; i < 4; ++i)
        #pragma unroll
        for (int j = 0; j < 4; ++j) acc[i * 4 + j] += a[i] * bb[j];
    }
  }
  #pragma unroll
  for (int i = 0; i < 4; ++i) {
    int n = n0 + ng * 4 + i;
    float sn = sq[b * NP + n];
    float4 r;
    r.x = sn + sq[b * NP + m0 + mg * 4 + 0] - 2.f * acc[i * 4 + 0];
    r.y = sn + sq[b * NP + m0 + mg * 4 + 1] - 2.f * acc[i * 4 + 1];
    r.z = sn + sq[b * NP + m0 + mg * 4 + 2] - 2.f * acc[i * 4 + 2];
    r.w = sn + sq[b * NP + m0 + mg * 4 + 3] - 2.f * acc[i * 4 + 3];
    *(float4*)&dist[((size_t)b * NP + n) * NP + m0 + mg * 4] = r;
  }
}

// ---------------- K3: top-18 nearest per row ----------------
__global__ __launch_bounds__(64) void k_knn(const float* __restrict__ dist,
                                            int* __restrict__ knn) {
  int row = blockIdx.x;
  int l = threadIdx.x;
  const float* dr = dist + (size_t)row * NP;
  float d[16];
  #pragma unroll
  for (int i = 0; i < 16; ++i) d[i] = dr[l + 64 * i];
  for (int s = 0; s < 18; ++s) {
    float best = __builtin_inff(); int bslot = -1;
    #pragma unroll
    for (int i = 0; i < 16; ++i) if (d[i] < best) { best = d[i]; bslot = i; }
    int bidx = (bslot >= 0) ? (l + 64 * bslot) : 0x7fffffff;
    float bd = best; int bi = bidx;
    #pragma unroll
    for (int off = 32; off > 0; off >>= 1) {
      float od = __shfl_xor(bd, off);
      int   oi = __shfl_xor(bi, off);
      if (od < bd || (od == bd && oi < bi)) { bd = od; bi = oi; }
    }
    if (l == 0) knn[row * 18 + s] = bi;
    if ((bi & 63) == l) d[bi >> 6] = __builtin_inff();
  }
}

// ---------------- K4: P/Q pre-GEMMs via MFMA, m-major f32 out ----------------
// grid (16 nt, 4 oq, 8 z), 256 thr; z: e=z>>2, b=z&3
__global__ __launch_bounds__(256) void k_pqm(const unsigned short* __restrict__ XR,
                                             const unsigned short* __restrict__ WPQ,
                                             float* __restrict__ Pm,
                                             float* __restrict__ Qm) {
  int t = threadIdx.x; int w = t >> 6; int l = t & 63;
  int lm = l & 15, g = l >> 4;
  int nt = blockIdx.x, oq = blockIdx.y, z = blockIdx.z;
  int e = z >> 2, b = z & 3;
  int srow = nt * 64 + w * 16 + lm;
  const unsigned short* sp = XR + ((size_t)b * 1024 + srow) * 128 + 8 * g;
  const unsigned short* wpp = WPQ + ((size_t)(e * 2 + 0) * 256 + oq * 64 + lm) * 128 + 8 * g;
  const unsigned short* wqq = WPQ + ((size_t)(e * 2 + 1) * 256 + oq * 64 + lm) * 128 + 8 * g;
  f32x4 accp[4], accq[4];
  #pragma unroll
  for (int i = 0; i < 4; ++i) { accp[i] = {0.f, 0.f, 0.f, 0.f}; accq[i] = {0.f, 0.f, 0.f, 0.f}; }
  #pragma unroll
  for (int cc = 0; cc < 4; ++cc) {
    short8 bfr = *(const short8*)(sp + cc * 32);
    #pragma unroll
    for (int ct = 0; ct < 4; ++ct) {
      short8 ap = *(const short8*)(wpp + (size_t)ct * 16 * 128 + cc * 32);
      accp[ct] = MFMA16(ap, bfr, accp[ct]);
      short8 aq = *(const short8*)(wqq + (size_t)ct * 16 * 128 + cc * 32);
      accq[ct] = MFMA16(aq, bfr, accq[ct]);
    }
  }
  int eb = e * 4 + b;
  #pragma unroll
  for (int ct = 0; ct < 4; ++ct) {
    int o0 = oq * 64 + ct * 16 + 4 * g;
    float4 rp = {accp[ct][0], accp[ct][1], accp[ct][2], accp[ct][3]};
    float4 rq = {accq[ct][0], accq[ct][1], accq[ct][2], accq[ct][3]};
    *(float4*)&Pm[((size_t)eb * 1024 + srow) * 256 + o0] = rp;
    *(float4*)&Qm[((size_t)eb * 1024 + srow) * 256 + o0] = rq;
  }
}

// ---------------- K5: edge BN stats partials ----------------
__global__ __launch_bounds__(256) void k_edge_stats(const float* __restrict__ Pm,
                                                    const float* __restrict__ Qm,
                                                    const int* __restrict__ knn,
                                                    float* __restrict__ stats) {
  int o = threadIdx.x;
  int chunk = blockIdx.x, b = blockIdx.y, e = blockIdx.z;
  int eb = e * 4 + b;
  float s = 0.f, s2 = 0.f;
  for (int nn = 0; nn < 64; ++nn) {
    int n = chunk * 64 + nn;
    float p = Pm[((size_t)eb * 1024 + n) * 256 + o];
    const int* kn = knn + (b * 1024 + n) * 18;
    #pragma unroll
    for (int kk = 0; kk < 9; ++kk) {
      int j = kn[e ? 2 * kk : kk];
      float v = p + Qm[((size_t)eb * 1024 + j) * 256 + o];
      s += v; s2 += v * v;
    }
  }
  size_t idx = ((((size_t)e * 4 + b) * 16 + chunk) * 256 + o) * 2;
  stats[idx] = s; stats[idx + 1] = s2;
}

// ---------------- K6: finalize edge BN ----------------
__global__ __launch_bounds__(256) void k_edge_fin(const float* __restrict__ stats,
                                                  const float* __restrict__ gna, const float* __restrict__ bta,
                                                  const float* __restrict__ gnb, const float* __restrict__ btb,
                                                  float* __restrict__ ab) {
  int i = blockIdx.x * 256 + threadIdx.x;
  if (i >= 512) return;
  int e = i >> 8, o = i & 255;
  float s = 0.f, s2 = 0.f;
  for (int b = 0; b < 4; ++b)
    for (int ch = 0; ch < 16; ++ch) {
      size_t idx = ((((size_t)e * 4 + b) * 16 + ch) * 256 + o) * 2;
      s += stats[idx]; s2 += stats[idx + 1];
    }
  float cnt = 4.0f * 1024.0f * 9.0f;
  float mean = s / cnt;
  float var = s2 / cnt - mean * mean;
  float g = e ? gnb[o] : gna[o];
  float bt = e ? btb[o] : bta[o];
  float alpha = g * rsqrtf(var + EPSBN);
  ab[i * 2] = alpha; ab[i * 2 + 1] = bt - mean * alpha;
}

// ---------------- K7: edge apply + max-over-k -> X16 (B,MM,160) bf16 ----------------
__global__ __launch_bounds__(256) void k_edge_apply(const float* __restrict__ Pm,
                                                    const float* __restrict__ Qm,
                                                    const int* __restrict__ knn,
                                                    const float* __restrict__ ab,
                                                    unsigned short* __restrict__ X16) {
  __shared__ int knl[18];
  int t = threadIdx.x;
  int n = blockIdx.x, b = blockIdx.y;
  if (t < 18) knl[t] = knn[(b * 1024 + n) * 18 + t];
  __syncthreads();
  int e = t >> 7, oo = t & 127;
  int eb = e * 4 + b;
  const float* Pr = Pm + ((size_t)eb * 1024 + n) * 256;
  const float* Qb = Qm + (size_t)eb * 1024 * 256;
  float p0 = Pr[oo], p1 = Pr[oo + 128];
  float a0 = ab[(e * 256 + oo) * 2], be0 = ab[(e * 256 + oo) * 2 + 1];
  float a1 = ab[(e * 256 + oo + 128) * 2], be1 = ab[(e * 256 + oo + 128) * 2 + 1];
  float mx0 = -__builtin_inff(), mx1 = -__builtin_inff();
  #pragma unroll
  for (int kk = 0; kk < 9; ++kk) {
    int j = knl[e ? 2 * kk : kk];
    const float* Qr = Qb + (size_t)j * 256;
    mx0 = fmaxf(mx0, fmaf(a0, p0 + Qr[oo], be0));
    mx1 = fmaxf(mx1, fmaf(a1, p1 + Qr[oo + 128], be1));
  }
  int u0 = e << 1, u1 = (e << 1) | 1;
  X16[((size_t)b * MM + 4 * n + u0) * 160 + oo] = f2bf(fmaxf(mx0, 0.f));
  X16[((size_t)b * MM + 4 * n + u1) * 160 + oo] = f2bf(fmaxf(mx1, 0.f));
  if (t < 128) {
    int u = t >> 5, c = 128 + (t & 31);
    int gr = n >> 8;
    float v = (c == 128) ? ((gr < 2) ? -0.2f : 0.2f) : (c == 129) ? ((gr & 1) ? 0.2f : -0.2f) : 0.f;
    X16[((size_t)b * MM + 4 * n + u) * 160 + c] = f2bf(v);
  }
}

// ---------------- MFMA 1x1 conv ----------------
// OUTMODE 0: f32 m-major (dstF, ld=outld) | 1: bf16 m-major relu | 2: f32 ch-major (rows param)
template <int KSTEPS, int CTPER, int OUTMODE, bool RELU>
__global__ __launch_bounds__(256) void k_convm(const unsigned short* __restrict__ src,
                                               const unsigned short* __restrict__ W16,
                                               const float* __restrict__ bias,
                                               float* __restrict__ dstF,
                                               unsigned short* __restrict__ dstB,
                                               int outld, int rows) {
  constexpr int LD = KSTEPS * 32;
  int t = threadIdx.x; int w = t >> 6; int l = t & 63;
  int lm = l & 15, g = l >> 4;
  int b = blockIdx.z; int ct0 = blockIdx.y * CTPER;
  int srow = blockIdx.x * 64 + w * 16 + lm;
  const unsigned short* sp = src + ((size_t)b * MM + srow) * LD + 8 * g;
  const unsigned short* wp = W16 + ((size_t)ct0 * 16 + lm) * LD + 8 * g;
  f32x4 acc[CTPER];
  #pragma unroll
  for (int i = 0; i < CTPER; ++i) acc[i] = {0.f, 0.f, 0.f, 0.f};
  #pragma unroll
  for (int cc = 0; cc < KSTEPS; ++cc) {
    short8 bfr = *(const short8*)(sp + cc * 32);
    #pragma unroll
    for (int ct = 0; ct < CTPER; ++ct) {
      short8 af = *(const short8*)(wp + (size_t)ct * 16 * LD + cc * 32);
      acc[ct] = MFMA16(af, bfr, acc[ct]);
    }
  }
  #pragma unroll
  for (int ct = 0; ct < CTPER; ++ct) {
    int o0 = (ct0 + ct) * 16 + 4 * g;
    float4 bv = *(const float4*)&bias[o0];
    float v[4] = {acc[ct][0] + bv.x, acc[ct][1] + bv.y, acc[ct][2] + bv.z, acc[ct][3] + bv.w};
    if (RELU) { v[0] = fmaxf(v[0], 0.f); v[1] = fmaxf(v[1], 0.f); v[2] = fmaxf(v[2], 0.f); v[3] = fmaxf(v[3], 0.f); }
    if (OUTMODE == 0) {
      float4 r = {v[0], v[1], v[2], v[3]};
      *(float4*)&dstF[((size_t)b * MM + srow) * outld + o0] = r;
    } else if (OUTMODE == 1) {
      uint2 pk;
      pk.x = cvtpk(v[0], v[1]);
      pk.y = cvtpk(v[2], v[3]);
      *(uint2*)&dstB[((size_t)b * MM + srow) * outld + o0] = pk;
    } else {
      #pragma unroll
      for (int r = 0; r < 4; ++r)
        dstF[((size_t)b * rows + o0 + r) * MM + srow] = v[r];
    }
  }
}

// ---------------- f/g BN stats partials over FGraw (B,MM,64) ----------------
__global__ __launch_bounds__(256) void k_fgstats(const float* __restrict__ FGraw,
                                                 float* __restrict__ FGP) {
  __shared__ float red[4][64][2];
  int t = threadIdx.x; int c = t & 63, rq = t >> 6;
  int blk = blockIdx.x;
  float s = 0.f, s2 = 0.f;
  for (int k = 0; k < 64; ++k) {
    int r = blk * 256 + rq + 4 * k;
    float v = FGraw[(size_t)r * 64 + c];
    s += v; s2 += v * v;
  }
  red[rq][c][0] = s; red[rq][c][1] = s2;
  __syncthreads();
  if (t < 64) {
    float a = 0.f, a2 = 0.f;
    #pragma unroll
    for (int q = 0; q < 4; ++q) { a += red[q][t][0]; a2 += red[q][t][1]; }
    FGP[((size_t)blk * 64 + t) * 2] = a; FGP[((size_t)blk * 64 + t) * 2 + 1] = a2;
  }
}

__global__ __launch_bounds__(64) void k_fgfin(const float* __restrict__ FGP,
                                              const float* __restrict__ gf, const float* __restrict__ bef,
                                              const float* __restrict__ gg, const float* __restrict__ beg,
                                              float* __restrict__ ab) {
  int c = threadIdx.x;
  float s = 0.f, s2 = 0.f;
  for (int blk = 0; blk < 64; ++blk) { s += FGP[((size_t)blk * 64 + c) * 2]; s2 += FGP[((size_t)blk * 64 + c) * 2 + 1]; }
  float cnt = 16384.f;
  float mean = s / cnt, var = s2 / cnt - mean * mean;
  float gv = (c < 32) ? gf[c] : gg[c - 32];
  float bv = (c < 32) ? bef[c] : beg[c - 32];
  float alpha = gv * rsqrtf(var + EPSBN);
  ab[c * 2] = alpha; ab[c * 2 + 1] = bv - mean * alpha;
}

// ---------------- H BN stats (ch-major) ----------------
__global__ __launch_bounds__(256) void k_bnstats(const float* __restrict__ src,
                                                 const float* __restrict__ g,
                                                 const float* __restrict__ be,
                                                 float* __restrict__ ab, int ldC) {
  int o = blockIdx.x;
  int t = threadIdx.x;
  float s = 0.f, s2 = 0.f;
  for (int b = 0; b < NB; ++b) {
    const float* r = src + ((size_t)b * ldC + o) * MM;
    for (int m = t; m < MM; m += 256) { float v = r[m]; s += v; s2 += v * v; }
  }
  __shared__ float rs[256], rs2[256];
  rs[t] = s; rs2[t] = s2;
  __syncthreads();
  for (int off = 128; off > 0; off >>= 1) {
    if (t < off) { rs[t] += rs[t + off]; rs2[t] += rs2[t + off]; }
    __syncthreads();
  }
  if (t == 0) {
    float cnt = 16384.0f;
    float mean = rs[0] / cnt, var = rs2[0] / cnt - mean * mean;
    float alpha = g[o] * rsqrtf(var + EPSBN);
    ab[o * 2] = alpha; ab[o * 2 + 1] = be[o] - mean * alpha;
  }
}

// ---------------- cvt FGraw -> FGT bf16 (BN+relu; F channels pre-scaled by LOG2E) ----------------
__global__ __launch_bounds__(256) void k_cvtFG(const float* __restrict__ FGraw,
                                               const float* __restrict__ ab,
                                               unsigned short* __restrict__ FGT) {
  int i = blockIdx.x * 256 + threadIdx.x;  // < 131072
  int row = i >> 3, c0 = (i & 7) * 8;
  float sc = (c0 < 32) ? LOG2E : 1.0f;
  float vv[8];
  float4 u0 = *(const float4*)&FGraw[(size_t)row * 64 + c0];
  float4 u1 = *(const float4*)&FGraw[(size_t)row * 64 + c0 + 4];
  vv[0] = u0.x; vv[1] = u0.y; vv[2] = u0.z; vv[3] = u0.w;
  vv[4] = u1.x; vv[5] = u1.y; vv[6] = u1.z; vv[7] = u1.w;
  uint4 pk;
  unsigned pw[4];
  #pragma unroll
  for (int h = 0; h < 4; ++h) {
    int c = c0 + 2 * h;
    float a0 = ab[c * 2] * sc, b0 = ab[c * 2 + 1] * sc;
    float a1 = ab[(c + 1) * 2] * sc, b1 = ab[(c + 1) * 2 + 1] * sc;
    float x0 = fmaxf(fmaf(a0, vv[2 * h], b0), 0.f);
    float x1 = fmaxf(fmaf(a1, vv[2 * h + 1], b1), 0.f);
    pw[h] = cvtpk(x0, x1);
  }
  pk.x = pw[0]; pk.y = pw[1]; pk.z = pw[2]; pk.w = pw[3];
  *(uint4*)&FGT[(size_t)row * 64 + c0] = pk;
}

// ---------------- cvt Hraw -> HB bf16 (BN+relu, ch-major) ----------------
__global__ __launch_bounds__(256) void k_cvtH(const float* __restrict__ src,
                                              const float* __restrict__ ab,
                                              unsigned short* __restrict__ dst) {
  int i = blockIdx.x * 256 + threadIdx.x;  // (b*144 + c)*1024 + m4
  int m4 = i & 1023; int c = (i >> 10) % 144; int b = i / (144 * 1024);
  ushort4 ov = {0, 0, 0, 0};
  if (c < 130) {
    float4 v = *(const float4*)&src[((size_t)b * 144 + c) * MM + m4 * 4];
    float a = ab[c * 2], be = ab[c * 2 + 1];
    ov.x = f2bf(fmaxf(fmaf(a, v.x, be), 0.f));
    ov.y = f2bf(fmaxf(fmaf(a, v.y, be), 0.f));
    ov.z = f2bf(fmaxf(fmaf(a, v.z, be), 0.f));
    ov.w = f2bf(fmaxf(fmaf(a, v.w, be), 0.f));
  }
  *(ushort4*)&dst[((size_t)b * 144 + c) * MM + m4 * 4] = ov;
}

// ---------------- K-LSE: S in log2 domain (F pre-scaled); defer-max online ----------------
__global__ __launch_bounds__(256) void k_zlse(const unsigned short* __restrict__ FGT,
                                              float* __restrict__ LSEP) {
  int t = threadIdx.x; int w = t >> 6; int l = t & 63;
  int b = blockIdx.z; int ms = blockIdx.y;
  int n0 = blockIdx.x * 64 + w * 16;
  int lm = l & 15, g = l >> 4;
  f32x4 z4 = {0.f, 0.f, 0.f, 0.f};
  short8 af = *(const short8*)&FGT[((size_t)b * MM + n0 + lm) * 64 + 32 + 8 * g];
  float rm[4], zz[4];
  #pragma unroll
  for (int r = 0; r < 4; ++r) { rm[r] = -__builtin_inff(); zz[r] = 0.f; }
  for (int it = 0; it < 16; ++it) {
    int m0 = ms * 1024 + it * 64;
    short8 bfr[4];
    #pragma unroll
    for (int mi = 0; mi < 4; ++mi)
      bfr[mi] = *(const short8*)&FGT[((size_t)b * MM + m0 + mi * 16 + lm) * 64 + 8 * g];
    f32x4 d[4];
    #pragma unroll
    for (int mi = 0; mi < 4; ++mi) d[mi] = MFMA16(af, bfr[mi], z4);
    #pragma unroll
    for (int r = 0; r < 4; ++r) {
      float tm = fmaxf(fmaxf(d[0][r], d[1][r]), fmaxf(d[2][r], d[3][r]));
      float nm = fmaxf(rm[r], tm);
      zz[r] = zz[r] * exp2f(rm[r] - nm)
            + exp2f(d[0][r] - nm) + exp2f(d[1][r] - nm)
            + exp2f(d[2][r] - nm) + exp2f(d[3][r] - nm);
      rm[r] = nm;
    }
  }
  #pragma unroll
  for (int off = 1; off < 16; off <<= 1) {
    #pragma unroll
    for (int r = 0; r < 4; ++r) {
      float om = __shfl_xor(rm[r], off);
      float oz = __shfl_xor(zz[r], off);
      float nm = fmaxf(rm[r], om);
      zz[r] = zz[r] * exp2f(rm[r] - nm) + oz * exp2f(om - nm);
      rm[r] = nm;
    }
  }
  if (lm == 0) {
    #pragma unroll
    for (int r = 0; r < 4; ++r) {
      int n = n0 + 4 * g + r;
      size_t idx = ((size_t)ms * 16384 + (size_t)b * MM + n) * 2;
      LSEP[idx] = rm[r]; LSEP[idx + 1] = zz[r];
    }
  }
}

// ---------------- merge LSE partials ----------------
__global__ __launch_bounds__(256) void k_lsered(const float* __restrict__ LSEP,
                                                float* __restrict__ LSE) {
  int bn = blockIdx.x * 256 + threadIdx.x;  // < 16384
  float rm = -__builtin_inff(), zz = 0.f;
  #pragma unroll
  for (int ms = 0; ms < 4; ++ms) {
    float m = LSEP[((size_t)ms * 16384 + bn) * 2];
    float z = LSEP[((size_t)ms * 16384 + bn) * 2 + 1];
    float nm = fmaxf(rm, m);
    zz = zz * exp2f(rm - nm) + z * exp2f(m - nm);
    rm = nm;
  }
  LSE[bn] = rm + log2f(zz);
}

// ---------------- K-O: MFMA O-pass, 2 m-tiles/wave, 6 n-splits, bf16 partials ----------------
// grid (32 mblocks, 4 b, 6 splits), 256 thr (4 waves)
__global__ __launch_bounds__(256) void k_omfma(const unsigned short* __restrict__ FGT,
                                               const unsigned short* __restrict__ HB,
                                               const float* __restrict__ LSE,
                                               unsigned short* __restrict__ Opart) {
  int t = threadIdx.x; int w = t >> 6; int l = t & 63;
  int b = blockIdx.y; int split = blockIdx.z;
  int lm = l & 15, g = l >> 4;
  int mcol0 = blockIdx.x * 128 + w * 32 + lm;
  int mcol1 = mcol0 + 16;
  f32x4 z4 = {0.f, 0.f, 0.f, 0.f};
  short8 Ff0 = *(const short8*)&FGT[((size_t)b * MM + mcol0) * 64 + 8 * g];
  short8 Ff1 = *(const short8*)&FGT[((size_t)b * MM + mcol1) * 64 + 8 * g];
  f32x4 acc0[9], acc1[9];
  #pragma unroll
  for (int ct = 0; ct < 9; ++ct) { acc0[ct] = z4; acc1[ct] = z4; }
  const int nchunks = (split < 2) ? 22 : 21;
  const int startc = split * 21 + ((split < 2) ? split : 2);
  const int start = startc * 32;
  const int end = start + nchunks * 32;
  const unsigned short* gptr = FGT + ((size_t)b * MM + lm) * 64 + 32 + 8 * g;
  const unsigned short* hbase = HB + ((size_t)b * 144 + lm) * MM + 8 * g;
  const float* lbase = LSE + (size_t)b * MM + 4 * g;
  int src01 = lm + 16 * (2 * (g & 1));
  int src23 = src01 + 16;
  bool hi = g >= 2;

  short8 a0 = *(const short8*)(gptr + (size_t)start * 64);
  short8 a1 = *(const short8*)(gptr + (size_t)(start + 16) * 64);
  float4 l0 = *(const float4*)(lbase + start);
  float4 l1 = *(const float4*)(lbase + start + 16);

  for (int n0 = start; n0 < end; n0 += 32) {
    const unsigned short* hp = hbase + n0;
    short8 hf[9];
    #pragma unroll
    for (int ct = 0; ct < 9; ++ct) hf[ct] = *(const short8*)(hp + (size_t)ct * 16 * MM);
    f32x4 s00 = MFMA16(a0, Ff0, z4);
    f32x4 s10 = MFMA16(a1, Ff0, z4);
    f32x4 s01 = MFMA16(a0, Ff1, z4);
    f32x4 s11 = MFMA16(a1, Ff1, z4);
    int nn = (n0 + 32 < end) ? (n0 + 32) : start;
    short8 na0 = *(const short8*)(gptr + (size_t)nn * 64);
    short8 na1 = *(const short8*)(gptr + (size_t)(nn + 16) * 64);
    float4 nl0 = *(const float4*)(lbase + nn);
    float4 nl1 = *(const float4*)(lbase + nn + 16);
    // p = exp2(s - lse2) -> packed bf16 pairs (cvt_pk)
    float le0[4] = {l0.x, l0.y, l0.z, l0.w};
    float le1[4] = {l1.x, l1.y, l1.z, l1.w};
    unsigned pk00[2], pk10[2], pk01[2], pk11[2];
    #pragma unroll
    for (int h2 = 0; h2 < 2; ++h2) {
      float e00a = exp2f(s00[2 * h2] - le0[2 * h2]);
      float e00b = exp2f(s00[2 * h2 + 1] - le0[2 * h2 + 1]);
      float e10a = exp2f(s10[2 * h2] - le1[2 * h2]);
      float e10b = exp2f(s10[2 * h2 + 1] - le1[2 * h2 + 1]);
      float e01a = exp2f(s01[2 * h2] - le0[2 * h2]);
      float e01b = exp2f(s01[2 * h2 + 1] - le0[2 * h2 + 1]);
      float e11a = exp2f(s11[2 * h2] - le1[2 * h2]);
      float e11b = exp2f(s11[2 * h2 + 1] - le1[2 * h2 + 1]);
      pk00[h2] = cvtpk(e00a, e00b);
      pk10[h2] = cvtpk(e10a, e10b);
      pk01[h2] = cvtpk(e01a, e01b);
      pk11[h2] = cvtpk(e11a, e11b);
    }
    a0 = na0; a1 = na1; l0 = nl0; l1 = nl1;
    // register P-transpose m-tile 0
    unsigned a0w = (unsigned)__shfl((int)pk00[0], src01);
    unsigned b0w = (unsigned)__shfl((int)pk10[0], src01);
    unsigned a1w = (unsigned)__shfl((int)pk00[1], src01);
    unsigned b1w = (unsigned)__shfl((int)pk10[1], src01);
    unsigned a2w = (unsigned)__shfl((int)pk00[0], src23);
    unsigned b2w = (unsigned)__shfl((int)pk10[0], src23);
    unsigned a3w = (unsigned)__shfl((int)pk00[1], src23);
    unsigned b3w = (unsigned)__shfl((int)pk10[1], src23);
    union { unsigned u[4]; short8 s; } bu0;
    bu0.u[0] = hi ? b0w : a0w; bu0.u[1] = hi ? b1w : a1w;
    bu0.u[2] = hi ? b2w : a2w; bu0.u[3] = hi ? b3w : a3w;
    short8 bfrag0 = bu0.s;
    // register P-transpose m-tile 1
    unsigned c0w = (unsigned)__shfl((int)pk01[0], src01);
    unsigned d0w = (unsigned)__shfl((int)pk11[0], src01);
    unsigned c1w = (unsigned)__shfl((int)pk01[1], src01);
    unsigned d1w = (unsigned)__shfl((int)pk11[1], src01);
    unsigned c2w = (unsigned)__shfl((int)pk01[0], src23);
    unsigned d2w = (unsigned)__shfl((int)pk11[0], src23);
    unsigned c3w = (unsigned)__shfl((int)pk01[1], src23);
    unsigned d3w = (unsigned)__shfl((int)pk11[1], src23);
    union { unsigned u[4]; short8 s; } bu1;
    bu1.u[0] = hi ? d0w : c0w; bu1.u[1] = hi ? d1w : c1w;
    bu1.u[2] = hi ? d2w : c2w; bu1.u[3] = hi ? d3w : c3w;
    short8 bfrag1 = bu1.s;
    #pragma unroll
    for (int ct = 0; ct < 9; ++ct) {
      acc0[ct] = MFMA16(hf[ct], bfrag0, acc0[ct]);
      acc1[ct] = MFMA16(hf[ct], bfrag1, acc1[ct]);
    }
  }
  unsigned short* op0 = Opart + (size_t)split * OPS_SH + ((size_t)b * MM + mcol0) * 132;
  unsigned short* op1 = Opart + (size_t)split * OPS_SH + ((size_t)b * MM + mcol1) * 132;
  #pragma unroll
  for (int ct = 0; ct < 9; ++ct) {
    int c0 = ct * 16 + 4 * g;
    if (c0 < 132) {
      uint2 p0, p1;
      p0.x = cvtpk(acc0[ct][0], acc0[ct][1]);
      p0.y = cvtpk(acc0[ct][2], acc0[ct][3]);
      p1.x = cvtpk(acc1[ct][0], acc1[ct][1]);
      p1.y = cvtpk(acc1[ct][2], acc1[ct][3]);
      *(uint2*)&op0[c0] = p0;
      *(uint2*)&op1[c0] = p1;
    }
  }
}

// ---------------- O reduce: A16 = bf16(gamma*sum(Oparts) + X) ----------------
__global__ __launch_bounds__(256) void k_ored(const unsigned short* __restrict__ Op,
                                              const unsigned short* __restrict__ X16,
                                              const float* __restrict__ gma,
                                              unsigned short* __restrict__ A16) {
  int i = blockIdx.x * 256 + threadIdx.x;  // < 327680
  int row = i / 20, c8 = i % 20;
  int c0 = c8 * 8;
  unsigned short* ap = A16 + (size_t)row * 160 + c0;
  if (c0 >= 136) {
    uint4 z = {0, 0, 0, 0};
    *(uint4*)ap = z;
    return;
  }
  float gm = gma[0];
  float ov[8] = {0.f, 0.f, 0.f, 0.f, 0.f, 0.f, 0.f, 0.f};
  #pragma unroll
  for (int s = 0; s < 6; ++s) {
    const unsigned short* base = Op + (size_t)s * OPS_SH + (size_t)row * 132 + c0;
    uint2 u = *(const uint2*)base;
    ov[0] += bf2f((unsigned short)(u.x & 0xffff));
    ov[1] += bf2f((unsigned short)(u.x >> 16));
    ov[2] += bf2f((unsigned short)(u.y & 0xffff));
    ov[3] += bf2f((unsigned short)(u.y >> 16));
    if (c0 + 4 < 132) {
      uint2 v = *(const uint2*)(base + 4);
      ov[4] += bf2f((unsigned short)(v.x & 0xffff));
      ov[5] += bf2f((unsigned short)(v.x >> 16));
      ov[6] += bf2f((unsigned short)(v.y & 0xffff));
      ov[7] += bf2f((unsigned short)(v.y >> 16));
    }
  }
  short8 xv = *(const short8*)(X16 + (size_t)row * 160 + c0);
  unsigned pw[4];
  #pragma unroll
  for (int h = 0; h < 4; ++h) {
    int ca = c0 + 2 * h, cb = c0 + 2 * h + 1;
    float xa = bf2f((unsigned short)xv[2 * h]);
    float xb = bf2f((unsigned short)xv[2 * h + 1]);
    float va = (ca < 132) ? (gm * ov[2 * h] + xa) : 0.f;
    float vb = (cb < 132) ? (gm * ov[2 * h + 1] + xb) : 0.f;
    pw[h] = (unsigned)f2bf(va) | ((unsigned)f2bf(vb) << 16);
  }
  uint4 pk = {pw[0], pw[1], pw[2], pw[3]};
  *(uint4*)ap = pk;
}

extern "C" void kernel_launch(void* const* d_in, const int* in_sizes, int n_in,
                              void* d_out, int out_size, void* d_ws, size_t ws_size,
                              hipStream_t stream) {
  const float* inp = (const float*)d_in[0];
  const float* Wa  = (const float*)d_in[1];
  const float* gna = (const float*)d_in[2];
  const float* bta = (const float*)d_in[3];
  const float* Wb  = (const float*)d_in[4];
  const float* gnb = (const float*)d_in[5];
  const float* btb = (const float*)d_in[6];
  const float* Wf  = (const float*)d_in[7];
  const float* bf  = (const float*)d_in[8];
  const float* gf  = (const float*)d_in[9];
  const float* bef = (const float*)d_in[10];
  const float* Wg  = (const float*)d_in[11];
  const float* bg  = (const float*)d_in[12];
  const float* gg  = (const float*)d_in[13];
  const float* beg = (const float*)d_in[14];
  const float* Wh  = (const float*)d_in[15];
  const float* bh  = (const float*)d_in[16];
  const float* gh  = (const float*)d_in[17];
  const float* beh = (const float*)d_in[18];
  const float* gamma = (const float*)d_in[19];
  const float* W1  = (const float*)d_in[20];
  const float* b1  = (const float*)d_in[21];
  const float* W2  = (const float*)d_in[22];
  const float* b2  = (const float*)d_in[23];
  float* out = (float*)d_out;

  float* ws = (float*)d_ws;
  float* DIST = ws + OFF_DIST;
  float* PM   = ws + OFF_PM;
  float* QM   = ws + OFF_QM;
  float* HRAW = ws + OFF_HRAW;
  float* FGRAW= ws + OFF_FGRAW;
  unsigned short* OP16 = (unsigned short*)(ws + OFF_OP);
  unsigned short* FGT = (unsigned short*)(ws + OFF_FGT);
  unsigned short* HBB = (unsigned short*)(ws + OFF_HB);
  unsigned short* A16 = (unsigned short*)(ws + OFF_A16);
  unsigned short* X16 = (unsigned short*)(ws + OFF_X16);
  unsigned short* Y1  = (unsigned short*)(ws + OFF_Y1);
  float* LSEB = ws + OFF_LSE;
  float* LSEP = ws + OFF_LSEP;
  float* STATS= ws + OFF_STATS;
  float* ABE  = ws + OFF_ABE;
  float* ABFG = ws + OFF_ABFG;
  float* ABH  = ws + OFF_ABH;
  float* FGP  = ws + OFF_FGP;
  float* BIAS = ws + OFF_BIAS;
  unsigned short* W16 = (unsigned short*)(ws + OFF_W16);
  int*   KNNI = (int*)(ws + OFF_KNN);
  float* XN   = ws + OFF_XN;
  unsigned short* XR = (unsigned short*)(ws + OFF_XR);
  unsigned short* WPQ = (unsigned short*)(ws + OFF_WPQ);
  float* SQ   = ws + OFF_SQ;

  // 0. weight prep
  k_prep<<<421, 256, 0, stream>>>(Wf, Wg, Wh, W1, W2, bf, bg, bh, b1, b2, W16, BIAS);
  k_prep2<<<512, 256, 0, stream>>>(Wa, Wb, WPQ);
  // 1-3. normalize (fp32 XN + bf16 XR), fp32 dist (exact kNN path), knn
  k_norm<<<16, 256, 0, stream>>>(inp, XN, XR, SQ);
  k_dist<<<dim3(16, 16, 4), 256, 0, stream>>>(XN, SQ, DIST);
  k_knn<<<4096, 64, 0, stream>>>(DIST, KNNI);
  // 4. P/Q MFMA (overwrites DIST) ; 5-6. edge BN ; 7. apply -> X16
  k_pqm<<<dim3(16, 4, 8), 256, 0, stream>>>(XR, WPQ, PM, QM);
  k_edge_stats<<<dim3(16, 4, 2), 256, 0, stream>>>(PM, QM, KNNI, STATS);
  k_edge_fin<<<2, 256, 0, stream>>>(STATS, gna, bta, gnb, btb, ABE);
  k_edge_apply<<<dim3(1024, 4), 256, 0, stream>>>(PM, QM, KNNI, ABE, X16);
  // 8. f+g conv and h conv via MFMA (overwrite PM/QM region)
  k_convm<5, 2, 0, false><<<dim3(64, 2, 4), 256, 0, stream>>>(X16, W16 + W16_FG, BIAS + B_FG, FGRAW, nullptr, 64, 0);
  k_convm<5, 3, 2, false><<<dim3(64, 3, 4), 256, 0, stream>>>(X16, W16 + W16_H, BIAS + B_H, HRAW, nullptr, 0, 144);
  // 9. BN stats + cvt to bf16
  k_fgstats<<<64, 256, 0, stream>>>(FGRAW, FGP);
  k_fgfin<<<1, 64, 0, stream>>>(FGP, gf, bef, gg, beg, ABFG);
  k_bnstats<<<130, 256, 0, stream>>>(HRAW, gh, beh, ABH, 144);
  k_cvtFG<<<512, 256, 0, stream>>>(FGRAW, ABFG, FGT);
  k_cvtH<<<2304, 256, 0, stream>>>(HRAW, ABH, HBB);
  // 10. LSE ; 11. O-pass ; 12. reduce -> A16
  k_zlse<<<dim3(64, 4, 4), 256, 0, stream>>>(FGT, LSEP);
  k_lsered<<<64, 256, 0, stream>>>(LSEP, LSEB);
  k_omfma<<<dim3(32, 4, 6), 256, 0, stream>>>(FGT, HBB, LSEB, OP16);
  k_ored<<<1280, 256, 0, stream>>>(OP16, X16, gamma, A16);
  // 13-14. final convs (MFMA)
  k_convm<5, 8, 1, true><<<dim3(64, 2, 4), 256, 0, stream>>>(A16, W16 + W16_C1, BIAS + B_C1, nullptr, Y1, 256, 0);
  k_convm<8, 4, 2, true><<<dim3(64, 2, 4), 256, 0, stream>>>(Y1, W16 + W16_C2, BIAS + B_C2, out, nullptr, 0, 128);
}

// Round 8
// 338.058 us; speedup vs baseline: 3.8752x; 1.0422x over previous
//
#include <hip/hip_runtime.h>

namespace {
constexpr int NB = 4;      // batch
constexpr int CI = 128;    // input channels
constexpr int NP = 1024;   // points
constexpr int MM = 4096;   // N*UP
constexpr float EPSBN = 1e-5f;
constexpr float LOG2E = 1.4426950408889634f;

constexpr size_t OPS_SH = 2162688;       // Opart split stride in SHORTS (B*MM*132)
// workspace offsets (floats)
constexpr size_t OFF_OP   = 0;           // 6 bf16 splits = 6488064 floats (overlaid: DIST / Pm,Qm / FGR16 / Y1)
constexpr size_t OFF_DIST = 0;           // 4194304
constexpr size_t OFF_PM   = 0;           // 2097152
constexpr size_t OFF_QM   = 2097152;     // 2097152
constexpr size_t OFF_FGR  = 2359296;     // (B,MM,64) bf16 raw = 524288 floats -> ends 2883584 (inside dead QM)
constexpr size_t OFF_Y1   = 0;           // (B,MM,256) bf16 = 2097152 floats
constexpr size_t OFF_FGT  = 6488064;     // (B,MM,64) bf16 = 524288 floats
constexpr size_t OFF_HB   = 7012352;     // (B,144,MM) bf16 = 1179648 floats (raw then BN'd in place)
constexpr size_t OFF_A16  = 6488064;     // (B,MM,160) bf16 = 1310720 floats (over FGT/HB after omfma)
constexpr size_t OFF_X16  = 8192000;     // (B,MM,160) bf16 = 1310720 floats
constexpr size_t OFF_LSE  = 9502720;     // 16384
constexpr size_t OFF_LSEP = 9519104;     // 131072
constexpr size_t OFF_STATS= 9650176;     // 65536
constexpr size_t OFF_ABE  = 9715712;     // 1024
constexpr size_t OFF_ABFG = 9716736;     // 128
constexpr size_t OFF_ABH  = 9716864;     // 512
constexpr size_t OFF_FGP  = 9717376;     // 8192
constexpr size_t OFF_BIAS = 9725568;     // 640
constexpr size_t OFF_W16  = 9726208;     // 53504 (107008 shorts)
constexpr size_t OFF_KNN  = 9779712;     // 73728 ints
constexpr size_t OFF_XN   = 9853440;     // (B,128,1024) f32 = 524288 (normalized, ch-major, for fp32 dist)
constexpr size_t OFF_SQ   = 10377728;    // 4096
constexpr size_t OFF_XR   = 10381824;    // (B,1024,128) bf16 raw = 262144 floats
constexpr size_t OFF_WPQ  = 10643968;    // 65536 floats (131072 shorts) -> ends 10709504
// W16 sub-offsets (shorts)
constexpr size_t W16_FG = 0;       // 64x160
constexpr size_t W16_H  = 10240;   // 144x160
constexpr size_t W16_C1 = 33280;   // 256x160
constexpr size_t W16_C2 = 74240;   // 128x256
// BIAS sub-offsets (floats)
constexpr size_t B_FG = 0, B_H = 64, B_C1 = 208, B_C2 = 464;
} // namespace

typedef __attribute__((ext_vector_type(8))) short short8;
typedef __attribute__((ext_vector_type(4))) float f32x4;
#define MFMA16(A, B, C) __builtin_amdgcn_mfma_f32_16x16x32_bf16(A, B, C, 0, 0, 0)

__device__ inline unsigned short f2bf(float x) {
  unsigned int u = __float_as_uint(x);
  unsigned int r = u + 0x7fff + ((u >> 16) & 1);
  return (unsigned short)(r >> 16);
}
__device__ inline float bf2f(unsigned short s) {
  return __uint_as_float(((unsigned int)s) << 16);
}
__device__ inline unsigned cvtpk(float lo, float hi) {
  unsigned r;
  asm("v_cvt_pk_bf16_f32 %0, %1, %2" : "=v"(r) : "v"(lo), "v"(hi));
  return r;
}

// ---------------- prep: conv weights/biases + edge Wp/Wq -> bf16 ----------------
__global__ __launch_bounds__(256) void k_prep(const float* __restrict__ Wf, const float* __restrict__ Wg,
                                              const float* __restrict__ Wh, const float* __restrict__ W1,
                                              const float* __restrict__ W2, const float* __restrict__ bf,
                                              const float* __restrict__ bg, const float* __restrict__ bh,
                                              const float* __restrict__ b1, const float* __restrict__ b2,
                                              const float* __restrict__ Wa, const float* __restrict__ Wb,
                                              unsigned short* __restrict__ W16, float* __restrict__ BIAS,
                                              unsigned short* __restrict__ WPQ) {
  int i = blockIdx.x * 256 + threadIdx.x;
  if (i < 107008) {
    float v = 0.f;
    if (i < 10240) { int o = i / 160, c = i % 160; if (c < 130) v = (o < 32) ? Wf[o * 130 + c] : Wg[(o - 32) * 130 + c]; }
    else if (i < 33280) { int r = i - 10240; int o = r / 160, c = r % 160; if (o < 130 && c < 130) v = Wh[o * 130 + c]; }
    else if (i < 74240) { int r = i - 33280; int o = r / 160, c = r % 160; if (c < 130) v = W1[o * 130 + c]; }
    else { int r = i - 74240; int o = r / 256, c = r % 256; v = W2[o * 256 + c]; }
    W16[i] = f2bf(v);
  } else if (i < 107648) {
    int j = i - 107008; float v = 0.f;
    if (j < 64) v = (j < 32) ? bf[j] : bg[j - 32];
    else if (j < 208) { int c = j - 64; if (c < 130) v = bh[c]; }
    else if (j < 464) v = b1[j - 208];
    else if (j < 592) v = b2[j - 464];
    BIAS[j] = v;
  } else if (i < 238720) {
    int j = i - 107648;
    int e = j >> 16;
    int rem = j & 65535;
    int pq = rem >> 15;
    int rr = rem & 32767;
    int o = rr >> 7, c = rr & 127;
    const float* W = e ? Wb : Wa;
    float w1 = W[o * 256 + c], w2 = W[o * 256 + 128 + c];
    float v = pq ? w2 : (w1 - w2);
    WPQ[j] = f2bf(v);
  }
}

// ---------------- K1: normalize -> fp32 XN ch-major (for dist), raw bf16 n-major, sq ----------------
__global__ __launch_bounds__(256) void k_norm(const float* __restrict__ x,
                                              float* __restrict__ xn,
                                              unsigned short* __restrict__ XR,
                                              float* __restrict__ sq) {
  int t = blockIdx.x * 256 + threadIdx.x;   // b*1024+n
  int b = t >> 10, n = t & 1023;
  const float* xb = x + (size_t)b * CI * NP + n;
  float ss = 0.f;
  #pragma unroll 4
  for (int c = 0; c < CI; ++c) { float v = xb[(size_t)c * NP]; ss += v * v; }
  float inv = 1.f / fmaxf(sqrtf(ss), 1e-12f);
  float* xo = xn + (size_t)b * CI * NP + n;
  float s2 = 0.f;
  for (int c0 = 0; c0 < 128; c0 += 8) {
    unsigned rw[4];
    #pragma unroll
    for (int j = 0; j < 4; ++j) {
      float va = xb[(size_t)(c0 + 2 * j) * NP];
      float vb = xb[(size_t)(c0 + 2 * j + 1) * NP];
      float na = va * inv, nb = vb * inv;
      s2 += na * na + nb * nb;
      xo[(size_t)(c0 + 2 * j) * NP] = na;
      xo[(size_t)(c0 + 2 * j + 1) * NP] = nb;
      rw[j] = (unsigned)f2bf(va) | ((unsigned)f2bf(vb) << 16);
    }
    uint4 r4 = {rw[0], rw[1], rw[2], rw[3]};
    *(uint4*)&XR[(size_t)t * 128 + c0] = r4;
  }
  sq[t] = s2;
}

// ---------------- K2: pairwise distance, fp32 LDS-tiled (exact kNN path) ----------------
__global__ __launch_bounds__(256) void k_dist(const float* __restrict__ xn,
                                              const float* __restrict__ sq,
                                              float* __restrict__ dist) {
  __shared__ float As[32][68], Bs[32][68];
  int t = threadIdx.x;
  int m0 = blockIdx.x * 64, n0 = blockIdx.y * 64, b = blockIdx.z;
  int mg = t & 15, ng = t >> 4;
  float acc[16];
  #pragma unroll
  for (int i = 0; i < 16; ++i) acc[i] = 0.f;
  for (int cc = 0; cc < 128; cc += 32) {
    __syncthreads();
    for (int idx = t; idx < 2048; idx += 256) {
      int c = idx >> 6, j = idx & 63;
      As[c][j] = xn[((size_t)b * CI + cc + c) * NP + n0 + j];
      Bs[c][j] = xn[((size_t)b * CI + cc + c) * NP + m0 + j];
    }
    __syncthreads();
    #pragma unroll
    for (int c = 0; c < 32; ++c) {
      float4 avv = *(const float4*)&As[c][ng * 4];
      float4 bvv = *(const float4*)&Bs[c][mg * 4];
      float a[4] = {avv.x, avv.y, avv.z, avv.w};
      float bb[4] = {bvv.x, bvv.y, bvv.z, bvv.w};
      #pragma unroll
      for (int i = 0; i < 4; ++i)
        #pragma unroll
        for (int j = 0; j < 4; ++j) acc[i * 4 + j] += a[i] * bb[j];
    }
  }
  #pragma unroll
  for (int i = 0; i < 4; ++i) {
    int n = n0 + ng * 4 + i;
    float sn = sq[b * NP + n];
    float4 r;
    r.x = sn + sq[b * NP + m0 + mg * 4 + 0] - 2.f * acc[i * 4 + 0];
    r.y = sn + sq[b * NP + m0 + mg * 4 + 1] - 2.f * acc[i * 4 + 1];
    r.z = sn + sq[b * NP + m0 + mg * 4 + 2] - 2.f * acc[i * 4 + 2];
    r.w = sn + sq[b * NP + m0 + mg * 4 + 3] - 2.f * acc[i * 4 + 3];
    *(float4*)&dist[((size_t)b * NP + n) * NP + m0 + mg * 4] = r;
  }
}

// ---------------- K3: top-18 nearest per row ----------------
__global__ __launch_bounds__(64) void k_knn(const float* __restrict__ dist,
                                            int* __restrict__ knn) {
  int row = blockIdx.x;
  int l = threadIdx.x;
  const float* dr = dist + (size_t)row * NP;
  float d[16];
  #pragma unroll
  for (int i = 0; i < 16; ++i) d[i] = dr[l + 64 * i];
  for (int s = 0; s < 18; ++s) {
    float best = __builtin_inff(); int bslot = -1;
    #pragma unroll
    for (int i = 0; i < 16; ++i) if (d[i] < best) { best = d[i]; bslot = i; }
    int bidx = (bslot >= 0) ? (l + 64 * bslot) : 0x7fffffff;
    float bd = best; int bi = bidx;
    #pragma unroll
    for (int off = 32; off > 0; off >>= 1) {
      float od = __shfl_xor(bd, off);
      int   oi = __shfl_xor(bi, off);
      if (od < bd || (od == bd && oi < bi)) { bd = od; bi = oi; }
    }
    if (l == 0) knn[row * 18 + s] = bi;
    if ((bi & 63) == l) d[bi >> 6] = __builtin_inff();
  }
}

// ---------------- K4: P/Q pre-GEMMs via MFMA, m-major f32 out ----------------
__global__ __launch_bounds__(256) void k_pqm(const unsigned short* __restrict__ XR,
                                             const unsigned short* __restrict__ WPQ,
                                             float* __restrict__ Pm,
                                             float* __restrict__ Qm) {
  int t = threadIdx.x; int w = t >> 6; int l = t & 63;
  int lm = l & 15, g = l >> 4;
  int nt = blockIdx.x, oq = blockIdx.y, z = blockIdx.z;
  int e = z >> 2, b = z & 3;
  int srow = nt * 64 + w * 16 + lm;
  const unsigned short* sp = XR + ((size_t)b * 1024 + srow) * 128 + 8 * g;
  const unsigned short* wpp = WPQ + ((size_t)(e * 2 + 0) * 256 + oq * 64 + lm) * 128 + 8 * g;
  const unsigned short* wqq = WPQ + ((size_t)(e * 2 + 1) * 256 + oq * 64 + lm) * 128 + 8 * g;
  f32x4 accp[4], accq[4];
  #pragma unroll
  for (int i = 0; i < 4; ++i) { accp[i] = {0.f, 0.f, 0.f, 0.f}; accq[i] = {0.f, 0.f, 0.f, 0.f}; }
  #pragma unroll
  for (int cc = 0; cc < 4; ++cc) {
    short8 bfr = *(const short8*)(sp + cc * 32);
    #pragma unroll
    for (int ct = 0; ct < 4; ++ct) {
      short8 ap = *(const short8*)(wpp + (size_t)ct * 16 * 128 + cc * 32);
      accp[ct] = MFMA16(ap, bfr, accp[ct]);
      short8 aq = *(const short8*)(wqq + (size_t)ct * 16 * 128 + cc * 32);
      accq[ct] = MFMA16(aq, bfr, accq[ct]);
    }
  }
  int eb = e * 4 + b;
  #pragma unroll
  for (int ct = 0; ct < 4; ++ct) {
    int o0 = oq * 64 + ct * 16 + 4 * g;
    float4 rp = {accp[ct][0], accp[ct][1], accp[ct][2], accp[ct][3]};
    float4 rq = {accq[ct][0], accq[ct][1], accq[ct][2], accq[ct][3]};
    *(float4*)&Pm[((size_t)eb * 1024 + srow) * 256 + o0] = rp;
    *(float4*)&Qm[((size_t)eb * 1024 + srow) * 256 + o0] = rq;
  }
}

// ---------------- K5: edge BN stats partials ----------------
__global__ __launch_bounds__(256) void k_edge_stats(const float* __restrict__ Pm,
                                                    const float* __restrict__ Qm,
                                                    const int* __restrict__ knn,
                                                    float* __restrict__ stats) {
  int o = threadIdx.x;
  int chunk = blockIdx.x, b = blockIdx.y, e = blockIdx.z;
  int eb = e * 4 + b;
  float s = 0.f, s2 = 0.f;
  for (int nn = 0; nn < 64; ++nn) {
    int n = chunk * 64 + nn;
    float p = Pm[((size_t)eb * 1024 + n) * 256 + o];
    const int* kn = knn + (b * 1024 + n) * 18;
    #pragma unroll
    for (int kk = 0; kk < 9; ++kk) {
      int j = kn[e ? 2 * kk : kk];
      float v = p + Qm[((size_t)eb * 1024 + j) * 256 + o];
      s += v; s2 += v * v;
    }
  }
  size_t idx = ((((size_t)e * 4 + b) * 16 + chunk) * 256 + o) * 2;
  stats[idx] = s; stats[idx + 1] = s2;
}

// ---------------- K6: finalize edge BN ----------------
__global__ __launch_bounds__(256) void k_edge_fin(const float* __restrict__ stats,
                                                  const float* __restrict__ gna, const float* __restrict__ bta,
                                                  const float* __restrict__ gnb, const float* __restrict__ btb,
                                                  float* __restrict__ ab) {
  int i = blockIdx.x * 256 + threadIdx.x;
  if (i >= 512) return;
  int e = i >> 8, o = i & 255;
  float s = 0.f, s2 = 0.f;
  for (int b = 0; b < 4; ++b)
    for (int ch = 0; ch < 16; ++ch) {
      size_t idx = ((((size_t)e * 4 + b) * 16 + ch) * 256 + o) * 2;
      s += stats[idx]; s2 += stats[idx + 1];
    }
  float cnt = 4.0f * 1024.0f * 9.0f;
  float mean = s / cnt;
  float var = s2 / cnt - mean * mean;
  float g = e ? gnb[o] : gna[o];
  float bt = e ? btb[o] : bta[o];
  float alpha = g * rsqrtf(var + EPSBN);
  ab[i * 2] = alpha; ab[i * 2 + 1] = bt - mean * alpha;
}

// ---------------- K7: edge apply + max-over-k -> X16 (B,MM,160) bf16 ----------------
__global__ __launch_bounds__(256) void k_edge_apply(const float* __restrict__ Pm,
                                                    const float* __restrict__ Qm,
                                                    const int* __restrict__ knn,
                                                    const float* __restrict__ ab,
                                                    unsigned short* __restrict__ X16) {
  __shared__ int knl[18];
  int t = threadIdx.x;
  int n = blockIdx.x, b = blockIdx.y;
  if (t < 18) knl[t] = knn[(b * 1024 + n) * 18 + t];
  __syncthreads();
  int e = t >> 7, oo = t & 127;
  int eb = e * 4 + b;
  const float* Pr = Pm + ((size_t)eb * 1024 + n) * 256;
  const float* Qb = Qm + (size_t)eb * 1024 * 256;
  float p0 = Pr[oo], p1 = Pr[oo + 128];
  float a0 = ab[(e * 256 + oo) * 2], be0 = ab[(e * 256 + oo) * 2 + 1];
  float a1 = ab[(e * 256 + oo + 128) * 2], be1 = ab[(e * 256 + oo + 128) * 2 + 1];
  float mx0 = -__builtin_inff(), mx1 = -__builtin_inff();
  #pragma unroll
  for (int kk = 0; kk < 9; ++kk) {
    int j = knl[e ? 2 * kk : kk];
    const float* Qr = Qb + (size_t)j * 256;
    mx0 = fmaxf(mx0, fmaf(a0, p0 + Qr[oo], be0));
    mx1 = fmaxf(mx1, fmaf(a1, p1 + Qr[oo + 128], be1));
  }
  int u0 = e << 1, u1 = (e << 1) | 1;
  X16[((size_t)b * MM + 4 * n + u0) * 160 + oo] = f2bf(fmaxf(mx0, 0.f));
  X16[((size_t)b * MM + 4 * n + u1) * 160 + oo] = f2bf(fmaxf(mx1, 0.f));
  if (t < 128) {
    int u = t >> 5, c = 128 + (t & 31);
    int gr = n >> 8;
    float v = (c == 128) ? ((gr < 2) ? -0.2f : 0.2f) : (c == 129) ? ((gr & 1) ? 0.2f : -0.2f) : 0.f;
    X16[((size_t)b * MM + 4 * n + u) * 160 + c] = f2bf(v);
  }
}

// ---------------- MFMA 1x1 conv ----------------
// OUTMODE 0: f32 m-major | 1: bf16 m-major | 2: f32 ch-major | 3: bf16 ch-major
template <int KSTEPS, int CTPER, int OUTMODE, bool RELU>
__global__ __launch_bounds__(256) void k_convm(const unsigned short* __restrict__ src,
                                               const unsigned short* __restrict__ W16,
                                               const float* __restrict__ bias,
                                               float* __restrict__ dstF,
                                               unsigned short* __restrict__ dstB,
                                               int outld, int rows) {
  constexpr int LD = KSTEPS * 32;
  int t = threadIdx.x; int w = t >> 6; int l = t & 63;
  int lm = l & 15, g = l >> 4;
  int b = blockIdx.z; int ct0 = blockIdx.y * CTPER;
  int srow = blockIdx.x * 64 + w * 16 + lm;
  const unsigned short* sp = src + ((size_t)b * MM + srow) * LD + 8 * g;
  const unsigned short* wp = W16 + ((size_t)ct0 * 16 + lm) * LD + 8 * g;
  f32x4 acc[CTPER];
  #pragma unroll
  for (int i = 0; i < CTPER; ++i) acc[i] = {0.f, 0.f, 0.f, 0.f};
  #pragma unroll
  for (int cc = 0; cc < KSTEPS; ++cc) {
    short8 bfr = *(const short8*)(sp + cc * 32);
    #pragma unroll
    for (int ct = 0; ct < CTPER; ++ct) {
      short8 af = *(const short8*)(wp + (size_t)ct * 16 * LD + cc * 32);
      acc[ct] = MFMA16(af, bfr, acc[ct]);
    }
  }
  #pragma unroll
  for (int ct = 0; ct < CTPER; ++ct) {
    int o0 = (ct0 + ct) * 16 + 4 * g;
    float4 bv = *(const float4*)&bias[o0];
    float v[4] = {acc[ct][0] + bv.x, acc[ct][1] + bv.y, acc[ct][2] + bv.z, acc[ct][3] + bv.w};
    if (RELU) { v[0] = fmaxf(v[0], 0.f); v[1] = fmaxf(v[1], 0.f); v[2] = fmaxf(v[2], 0.f); v[3] = fmaxf(v[3], 0.f); }
    if (OUTMODE == 0) {
      float4 r = {v[0], v[1], v[2], v[3]};
      *(float4*)&dstF[((size_t)b * MM + srow) * outld + o0] = r;
    } else if (OUTMODE == 1) {
      uint2 pk;
      pk.x = cvtpk(v[0], v[1]);
      pk.y = cvtpk(v[2], v[3]);
      *(uint2*)&dstB[((size_t)b * MM + srow) * outld + o0] = pk;
    } else if (OUTMODE == 2) {
      #pragma unroll
      for (int r = 0; r < 4; ++r)
        dstF[((size_t)b * rows + o0 + r) * MM + srow] = v[r];
    } else {
      #pragma unroll
      for (int r = 0; r < 4; ++r)
        dstB[((size_t)b * rows + o0 + r) * MM + srow] = f2bf(v[r]);
    }
  }
}

// ---------------- f/g BN stats partials over FGR16 (B,MM,64) bf16 ----------------
__global__ __launch_bounds__(256) void k_fgstats(const unsigned short* __restrict__ FGR,
                                                 float* __restrict__ FGP) {
  __shared__ float red[4][64][2];
  int t = threadIdx.x; int c = t & 63, rq = t >> 6;
  int blk = blockIdx.x;
  float s = 0.f, s2 = 0.f;
  for (int k = 0; k < 64; ++k) {
    int r = blk * 256 + rq + 4 * k;
    float v = bf2f(FGR[(size_t)r * 64 + c]);
    s += v; s2 += v * v;
  }
  red[rq][c][0] = s; red[rq][c][1] = s2;
  __syncthreads();
  if (t < 64) {
    float a = 0.f, a2 = 0.f;
    #pragma unroll
    for (int q = 0; q < 4; ++q) { a += red[q][t][0]; a2 += red[q][t][1]; }
    FGP[((size_t)blk * 64 + t) * 2] = a; FGP[((size_t)blk * 64 + t) * 2 + 1] = a2;
  }
}

__global__ __launch_bounds__(64) void k_fgfin(const float* __restrict__ FGP,
                                              const float* __restrict__ gf, const float* __restrict__ bef,
                                              const float* __restrict__ gg, const float* __restrict__ beg,
                                              float* __restrict__ ab) {
  int c = threadIdx.x;
  float s = 0.f, s2 = 0.f;
  for (int blk = 0; blk < 64; ++blk) { s += FGP[((size_t)blk * 64 + c) * 2]; s2 += FGP[((size_t)blk * 64 + c) * 2 + 1]; }
  float cnt = 16384.f;
  float mean = s / cnt, var = s2 / cnt - mean * mean;
  float gv = (c < 32) ? gf[c] : gg[c - 32];
  float bv = (c < 32) ? bef[c] : beg[c - 32];
  float alpha = gv * rsqrtf(var + EPSBN);
  ab[c * 2] = alpha; ab[c * 2 + 1] = bv - mean * alpha;
}

// ---------------- apply BN+relu (+log2e on F) : FGR16 -> FGT ----------------
__global__ __launch_bounds__(256) void k_applyFG(const unsigned short* __restrict__ FGR,
                                                 const float* __restrict__ ab,
                                                 unsigned short* __restrict__ FGT) {
  int i = blockIdx.x * 256 + threadIdx.x;  // < 131072 (16384 rows x 8 chunks)
  int row = i >> 3, c0 = (i & 7) * 8;
  float sc = (c0 < 32) ? LOG2E : 1.0f;
  uint4 u = *(const uint4*)&FGR[(size_t)row * 64 + c0];
  unsigned uw[4] = {u.x, u.y, u.z, u.w};
  unsigned pw[4];
  #pragma unroll
  for (int h = 0; h < 4; ++h) {
    int c = c0 + 2 * h;
    float a0 = ab[c * 2] * sc, b0 = ab[c * 2 + 1] * sc;
    float a1 = ab[(c + 1) * 2] * sc, b1 = ab[(c + 1) * 2 + 1] * sc;
    float v0 = bf2f((unsigned short)(uw[h] & 0xffff));
    float v1 = bf2f((unsigned short)(uw[h] >> 16));
    float x0 = fmaxf(fmaf(a0, v0, b0), 0.f);
    float x1 = fmaxf(fmaf(a1, v1, b1), 0.f);
    pw[h] = cvtpk(x0, x1);
  }
  uint4 pk = {pw[0], pw[1], pw[2], pw[3]};
  *(uint4*)&FGT[(size_t)row * 64 + c0] = pk;
}

// ---------------- H BN stats + finalize (ch-major bf16 raw), grid 130 ----------------
__global__ __launch_bounds__(256) void k_bnstatsH(const unsigned short* __restrict__ HBR,
                                                  const float* __restrict__ g,
                                                  const float* __restrict__ be,
                                                  float* __restrict__ ab) {
  int o = blockIdx.x;  // < 130
  int t = threadIdx.x;
  float s = 0.f, s2 = 0.f;
  for (int b = 0; b < NB; ++b) {
    const unsigned short* r = HBR + ((size_t)b * 144 + o) * MM;
    for (int m = t * 8; m < MM; m += 2048) {
      uint4 u = *(const uint4*)&r[m];
      unsigned uw[4] = {u.x, u.y, u.z, u.w};
      #pragma unroll
      for (int h = 0; h < 4; ++h) {
        float v0 = bf2f((unsigned short)(uw[h] & 0xffff));
        float v1 = bf2f((unsigned short)(uw[h] >> 16));
        s += v0 + v1; s2 += v0 * v0 + v1 * v1;
      }
    }
  }
  __shared__ float rs[256], rs2[256];
  rs[t] = s; rs2[t] = s2;
  __syncthreads();
  for (int off = 128; off > 0; off >>= 1) {
    if (t < off) { rs[t] += rs[t + off]; rs2[t] += rs2[t + off]; }
    __syncthreads();
  }
  if (t == 0) {
    float cnt = 16384.0f;
    float mean = rs[0] / cnt, var = rs2[0] / cnt - mean * mean;
    float alpha = g[o] * rsqrtf(var + EPSBN);
    ab[o * 2] = alpha; ab[o * 2 + 1] = be[o] - mean * alpha;
  }
}

// ---------------- H apply BN+relu in place (zero pad channels) ----------------
__global__ __launch_bounds__(256) void k_applyH(unsigned short* __restrict__ HBR,
                                                const float* __restrict__ ab) {
  int i = blockIdx.x * 256 + threadIdx.x;  // < 294912
  int c = (i >> 9) % 144;
  unsigned short* p = HBR + (size_t)i * 8;
  if (c >= 130) {
    uint4 z = {0, 0, 0, 0};
    *(uint4*)p = z;
    return;
  }
  float a = ab[c * 2], be = ab[c * 2 + 1];
  uint4 u = *(const uint4*)p;
  unsigned uw[4] = {u.x, u.y, u.z, u.w};
  unsigned pw[4];
  #pragma unroll
  for (int h = 0; h < 4; ++h) {
    float v0 = bf2f((unsigned short)(uw[h] & 0xffff));
    float v1 = bf2f((unsigned short)(uw[h] >> 16));
    float x0 = fmaxf(fmaf(a, v0, be), 0.f);
    float x1 = fmaxf(fmaf(a, v1, be), 0.f);
    pw[h] = cvtpk(x0, x1);
  }
  uint4 pk = {pw[0], pw[1], pw[2], pw[3]};
  *(uint4*)p = pk;
}

// ---------------- K-LSE: S in log2 domain (F pre-scaled); defer-max online ----------------
__global__ __launch_bounds__(256) void k_zlse(const unsigned short* __restrict__ FGT,
                                              float* __restrict__ LSEP) {
  int t = threadIdx.x; int w = t >> 6; int l = t & 63;
  int b = blockIdx.z; int ms = blockIdx.y;
  int n0 = blockIdx.x * 64 + w * 16;
  int lm = l & 15, g = l >> 4;
  f32x4 z4 = {0.f, 0.f, 0.f, 0.f};
  short8 af = *(const short8*)&FGT[((size_t)b * MM + n0 + lm) * 64 + 32 + 8 * g];
  float rm[4], zz[4];
  #pragma unroll
  for (int r = 0; r < 4; ++r) { rm[r] = -__builtin_inff(); zz[r] = 0.f; }
  for (int it = 0; it < 16; ++it) {
    int m0 = ms * 1024 + it * 64;
    short8 bfr[4];
    #pragma unroll
    for (int mi = 0; mi < 4; ++mi)
      bfr[mi] = *(const short8*)&FGT[((size_t)b * MM + m0 + mi * 16 + lm) * 64 + 8 * g];
    f32x4 d[4];
    #pragma unroll
    for (int mi = 0; mi < 4; ++mi) d[mi] = MFMA16(af, bfr[mi], z4);
    #pragma unroll
    for (int r = 0; r < 4; ++r) {
      float tm = fmaxf(fmaxf(d[0][r], d[1][r]), fmaxf(d[2][r], d[3][r]));
      float nm = fmaxf(rm[r], tm);
      zz[r] = zz[r] * exp2f(rm[r] - nm)
            + exp2f(d[0][r] - nm) + exp2f(d[1][r] - nm)
            + exp2f(d[2][r] - nm) + exp2f(d[3][r] - nm);
      rm[r] = nm;
    }
  }
  #pragma unroll
  for (int off = 1; off < 16; off <<= 1) {
    #pragma unroll
    for (int r = 0; r < 4; ++r) {
      float om = __shfl_xor(rm[r], off);
      float oz = __shfl_xor(zz[r], off);
      float nm = fmaxf(rm[r], om);
      zz[r] = zz[r] * exp2f(rm[r] - nm) + oz * exp2f(om - nm);
      rm[r] = nm;
    }
  }
  if (lm == 0) {
    #pragma unroll
    for (int r = 0; r < 4; ++r) {
      int n = n0 + 4 * g + r;
      size_t idx = ((size_t)ms * 16384 + (size_t)b * MM + n) * 2;
      LSEP[idx] = rm[r]; LSEP[idx + 1] = zz[r];
    }
  }
}

// ---------------- merge LSE partials ----------------
__global__ __launch_bounds__(256) void k_lsered(const float* __restrict__ LSEP,
                                                float* __restrict__ LSE) {
  int bn = blockIdx.x * 256 + threadIdx.x;  // < 16384
  float rm = -__builtin_inff(), zz = 0.f;
  #pragma unroll
  for (int ms = 0; ms < 4; ++ms) {
    float m = LSEP[((size_t)ms * 16384 + bn) * 2];
    float z = LSEP[((size_t)ms * 16384 + bn) * 2 + 1];
    float nm = fmaxf(rm, m);
    zz = zz * exp2f(rm - nm) + z * exp2f(m - nm);
    rm = nm;
  }
  LSE[bn] = rm + log2f(zz);
}

// ---------------- K-O: MFMA O-pass, software-pipelined (S one chunk ahead) ----------------
// grid (32 mblocks, 4 b, 6 splits), 256 thr (4 waves)
__global__ __launch_bounds__(256) void k_omfma(const unsigned short* __restrict__ FGT,
                                               const unsigned short* __restrict__ HB,
                                               const float* __restrict__ LSE,
                                               unsigned short* __restrict__ Opart) {
  int t = threadIdx.x; int w = t >> 6; int l = t & 63;
  int b = blockIdx.y; int split = blockIdx.z;
  int lm = l & 15, g = l >> 4;
  int mcol0 = blockIdx.x * 128 + w * 32 + lm;
  int mcol1 = mcol0 + 16;
  f32x4 z4 = {0.f, 0.f, 0.f, 0.f};
  short8 Ff0 = *(const short8*)&FGT[((size_t)b * MM + mcol0) * 64 + 8 * g];
  short8 Ff1 = *(const short8*)&FGT[((size_t)b * MM + mcol1) * 64 + 8 * g];
  f32x4 acc0[9], acc1[9];
  #pragma unroll
  for (int ct = 0; ct < 9; ++ct) { acc0[ct] = z4; acc1[ct] = z4; }
  const int nchunks = (split < 2) ? 22 : 21;
  const int startc = split * 21 + ((split < 2) ? split : 2);
  const int start = startc * 32;
  const int span = nchunks * 32;
  const int end = start + span;
  const unsigned short* gptr = FGT + ((size_t)b * MM + lm) * 64 + 32 + 8 * g;
  const unsigned short* hbase = HB + ((size_t)b * 144 + lm) * MM + 8 * g;
  const float* lbase = LSE + (size_t)b * MM + 4 * g;
  int src01 = lm + 16 * (2 * (g & 1));
  int src23 = src01 + 16;
  bool hi = g >= 2;

  // preamble: S for chunk 0, prefetch G/LSE for chunk 1
  short8 a0 = *(const short8*)(gptr + (size_t)start * 64);
  short8 a1 = *(const short8*)(gptr + (size_t)(start + 16) * 64);
  float4 l0c = *(const float4*)(lbase + start);
  float4 l1c = *(const float4*)(lbase + start + 16);
  f32x4 s00 = MFMA16(a0, Ff0, z4);
  f32x4 s10 = MFMA16(a1, Ff0, z4);
  f32x4 s01 = MFMA16(a0, Ff1, z4);
  f32x4 s11 = MFMA16(a1, Ff1, z4);
  int n1 = start + 32; if (n1 >= end) n1 = start;
  short8 a0n = *(const short8*)(gptr + (size_t)n1 * 64);
  short8 a1n = *(const short8*)(gptr + (size_t)(n1 + 16) * 64);
  float4 l0n = *(const float4*)(lbase + n1);
  float4 l1n = *(const float4*)(lbase + n1 + 16);

  for (int n0 = start; n0 < end; n0 += 32) {
    // H fragments for current chunk
    const unsigned short* hp = hbase + n0;
    short8 hf[9];
    #pragma unroll
    for (int ct = 0; ct < 9; ++ct) hf[ct] = *(const short8*)(hp + (size_t)ct * 16 * MM);
    // depth-2 prefetch of G/LSE (chunk i+2)
    int n2 = n0 + 64; if (n2 >= end) n2 -= span;
    short8 a0f = *(const short8*)(gptr + (size_t)n2 * 64);
    short8 a1f = *(const short8*)(gptr + (size_t)(n2 + 16) * 64);
    float4 l0f = *(const float4*)(lbase + n2);
    float4 l1f = *(const float4*)(lbase + n2 + 16);
    // VALU: p = exp2(s - lse) for CURRENT chunk (s fully retired last iter)
    float le0[4] = {l0c.x, l0c.y, l0c.z, l0c.w};
    float le1[4] = {l1c.x, l1c.y, l1c.z, l1c.w};
    unsigned pk00[2], pk10[2], pk01[2], pk11[2];
    #pragma unroll
    for (int h2 = 0; h2 < 2; ++h2) {
      float e00a = exp2f(s00[2 * h2] - le0[2 * h2]);
      float e00b = exp2f(s00[2 * h2 + 1] - le0[2 * h2 + 1]);
      float e10a = exp2f(s10[2 * h2] - le1[2 * h2]);
      float e10b = exp2f(s10[2 * h2 + 1] - le1[2 * h2 + 1]);
      float e01a = exp2f(s01[2 * h2] - le0[2 * h2]);
      float e01b = exp2f(s01[2 * h2 + 1] - le0[2 * h2 + 1]);
      float e11a = exp2f(s11[2 * h2] - le1[2 * h2]);
      float e11b = exp2f(s11[2 * h2 + 1] - le1[2 * h2 + 1]);
      pk00[h2] = cvtpk(e00a, e00b);
      pk10[h2] = cvtpk(e10a, e10b);
      pk01[h2] = cvtpk(e01a, e01b);
      pk11[h2] = cvtpk(e11a, e11b);
    }
    // S MFMAs for NEXT chunk (a0n/a1n loaded one full iteration ago) — overlaps VALU above
    f32x4 t00 = MFMA16(a0n, Ff0, z4);
    f32x4 t10 = MFMA16(a1n, Ff0, z4);
    f32x4 t01 = MFMA16(a0n, Ff1, z4);
    f32x4 t11 = MFMA16(a1n, Ff1, z4);
    // register P-transpose m-tile 0
    unsigned a0w = (unsigned)__shfl((int)pk00[0], src01);
    unsigned b0w = (unsigned)__shfl((int)pk10[0], src01);
    unsigned a1w = (unsigned)__shfl((int)pk00[1], src01);
    unsigned b1w = (unsigned)__shfl((int)pk10[1], src01);
    unsigned a2w = (unsigned)__shfl((int)pk00[0], src23);
    unsigned b2w = (unsigned)__shfl((int)pk10[0], src23);
    unsigned a3w = (unsigned)__shfl((int)pk00[1], src23);
    unsigned b3w = (unsigned)__shfl((int)pk10[1], src23);
    union { unsigned u[4]; short8 s; } bu0;
    bu0.u[0] = hi ? b0w : a0w; bu0.u[1] = hi ? b1w : a1w;
    bu0.u[2] = hi ? b2w : a2w; bu0.u[3] = hi ? b3w : a3w;
    short8 bfrag0 = bu0.s;
    // register P-transpose m-tile 1
    unsigned c0w = (unsigned)__shfl((int)pk01[0], src01);
    unsigned d0w = (unsigned)__shfl((int)pk11[0], src01);
    unsigned c1w = (unsigned)__shfl((int)pk01[1], src01);
    unsigned d1w = (unsigned)__shfl((int)pk11[1], src01);
    unsigned c2w = (unsigned)__shfl((int)pk01[0], src23);
    unsigned d2w = (unsigned)__shfl((int)pk11[0], src23);
    unsigned c3w = (unsigned)__shfl((int)pk01[1], src23);
    unsigned d3w = (unsigned)__shfl((int)pk11[1], src23);
    union { unsigned u[4]; short8 s; } bu1;
    bu1.u[0] = hi ? d0w : c0w; bu1.u[1] = hi ? d1w : c1w;
    bu1.u[2] = hi ? d2w : c2w; bu1.u[3] = hi ? d3w : c3w;
    short8 bfrag1 = bu1.s;
    // PV MFMAs (current chunk)
    #pragma unroll
    for (int ct = 0; ct < 9; ++ct) {
      acc0[ct] = MFMA16(hf[ct], bfrag0, acc0[ct]);
      acc1[ct] = MFMA16(hf[ct], bfrag1, acc1[ct]);
    }
    // rotate pipeline registers
    s00 = t00; s10 = t10; s01 = t01; s11 = t11;
    l0c = l0n; l1c = l1n; l0n = l0f; l1n = l1f;
    a0n = a0f; a1n = a1f;
  }
  unsigned short* op0 = Opart + (size_t)split * OPS_SH + ((size_t)b * MM + mcol0) * 132;
  unsigned short* op1 = Opart + (size_t)split * OPS_SH + ((size_t)b * MM + mcol1) * 132;
  #pragma unroll
  for (int ct = 0; ct < 9; ++ct) {
    int c0 = ct * 16 + 4 * g;
    if (c0 < 132) {
      uint2 p0, p1;
      p0.x = cvtpk(acc0[ct][0], acc0[ct][1]);
      p0.y = cvtpk(acc0[ct][2], acc0[ct][3]);
      p1.x = cvtpk(acc1[ct][0], acc1[ct][1]);
      p1.y = cvtpk(acc1[ct][2], acc1[ct][3]);
      *(uint2*)&op0[c0] = p0;
      *(uint2*)&op1[c0] = p1;
    }
  }
}

// ---------------- O reduce: A16 = bf16(gamma*sum(Oparts) + X) ----------------
__global__ __launch_bounds__(256) void k_ored(const unsigned short* __restrict__ Op,
                                              const unsigned short* __restrict__ X16,
                                              const float* __restrict__ gma,
                                              unsigned short* __restrict__ A16) {
  int i = blockIdx.x * 256 + threadIdx.x;  // < 327680
  int row = i / 20, c8 = i % 20;
  int c0 = c8 * 8;
  unsigned short* ap = A16 + (size_t)row * 160 + c0;
  if (c0 >= 136) {
    uint4 z = {0, 0, 0, 0};
    *(uint4*)ap = z;
    return;
  }
  float gm = gma[0];
  float ov[8] = {0.f, 0.f, 0.f, 0.f, 0.f, 0.f, 0.f, 0.f};
  #pragma unroll
  for (int s = 0; s < 6; ++s) {
    const unsigned short* base = Op + (size_t)s * OPS_SH + (size_t)row * 132 + c0;
    uint2 u = *(const uint2*)base;
    ov[0] += bf2f((unsigned short)(u.x & 0xffff));
    ov[1] += bf2f((unsigned short)(u.x >> 16));
    ov[2] += bf2f((unsigned short)(u.y & 0xffff));
    ov[3] += bf2f((unsigned short)(u.y >> 16));
    if (c0 + 4 < 132) {
      uint2 v = *(const uint2*)(base + 4);
      ov[4] += bf2f((unsigned short)(v.x & 0xffff));
      ov[5] += bf2f((unsigned short)(v.x >> 16));
      ov[6] += bf2f((unsigned short)(v.y & 0xffff));
      ov[7] += bf2f((unsigned short)(v.y >> 16));
    }
  }
  short8 xv = *(const short8*)(X16 + (size_t)row * 160 + c0);
  unsigned pw[4];
  #pragma unroll
  for (int h = 0; h < 4; ++h) {
    int ca = c0 + 2 * h, cb = c0 + 2 * h + 1;
    float xa = bf2f((unsigned short)xv[2 * h]);
    float xb = bf2f((unsigned short)xv[2 * h + 1]);
    float va = (ca < 132) ? (gm * ov[2 * h] + xa) : 0.f;
    float vb = (cb < 132) ? (gm * ov[2 * h + 1] + xb) : 0.f;
    pw[h] = (unsigned)f2bf(va) | ((unsigned)f2bf(vb) << 16);
  }
  uint4 pk = {pw[0], pw[1], pw[2], pw[3]};
  *(uint4*)ap = pk;
}

extern "C" void kernel_launch(void* const* d_in, const int* in_sizes, int n_in,
                              void* d_out, int out_size, void* d_ws, size_t ws_size,
                              hipStream_t stream) {
  const float* inp = (const float*)d_in[0];
  const float* Wa  = (const float*)d_in[1];
  const float* gna = (const float*)d_in[2];
  const float* bta = (const float*)d_in[3];
  const float* Wb  = (const float*)d_in[4];
  const float* gnb = (const float*)d_in[5];
  const float* btb = (const float*)d_in[6];
  const float* Wf  = (const float*)d_in[7];
  const float* bf  = (const float*)d_in[8];
  const float* gf  = (const float*)d_in[9];
  const float* bef = (const float*)d_in[10];
  const float* Wg  = (const float*)d_in[11];
  const float* bg  = (const float*)d_in[12];
  const float* gg  = (const float*)d_in[13];
  const float* beg = (const float*)d_in[14];
  const float* Wh  = (const float*)d_in[15];
  const float* bh  = (const float*)d_in[16];
  const float* gh  = (const float*)d_in[17];
  const float* beh = (const float*)d_in[18];
  const float* gamma = (const float*)d_in[19];
  const float* W1  = (const float*)d_in[20];
  const float* b1  = (const float*)d_in[21];
  const float* W2  = (const float*)d_in[22];
  const float* b2  = (const float*)d_in[23];
  float* out = (float*)d_out;

  float* ws = (float*)d_ws;
  float* DIST = ws + OFF_DIST;
  float* PM   = ws + OFF_PM;
  float* QM   = ws + OFF_QM;
  unsigned short* FGR = (unsigned short*)(ws + OFF_FGR);
  unsigned short* OP16 = (unsigned short*)(ws + OFF_OP);
  unsigned short* FGT = (unsigned short*)(ws + OFF_FGT);
  unsigned short* HBR = (unsigned short*)(ws + OFF_HB);
  unsigned short* A16 = (unsigned short*)(ws + OFF_A16);
  unsigned short* X16 = (unsigned short*)(ws + OFF_X16);
  unsigned short* Y1  = (unsigned short*)(ws + OFF_Y1);
  float* LSEB = ws + OFF_LSE;
  float* LSEP = ws + OFF_LSEP;
  float* STATS= ws + OFF_STATS;
  float* ABE  = ws + OFF_ABE;
  float* ABFG = ws + OFF_ABFG;
  float* ABH  = ws + OFF_ABH;
  float* FGP  = ws + OFF_FGP;
  float* BIAS = ws + OFF_BIAS;
  unsigned short* W16 = (unsigned short*)(ws + OFF_W16);
  int*   KNNI = (int*)(ws + OFF_KNN);
  float* XN   = ws + OFF_XN;
  unsigned short* XR = (unsigned short*)(ws + OFF_XR);
  unsigned short* WPQ = (unsigned short*)(ws + OFF_WPQ);
  float* SQ   = ws + OFF_SQ;

  // 0. weight prep (merged)
  k_prep<<<933, 256, 0, stream>>>(Wf, Wg, Wh, W1, W2, bf, bg, bh, b1, b2, Wa, Wb, W16, BIAS, WPQ);
  // 1-3. normalize (fp32 XN + bf16 XR), fp32 dist (exact kNN path), knn
  k_norm<<<16, 256, 0, stream>>>(inp, XN, XR, SQ);
  k_dist<<<dim3(16, 16, 4), 256, 0, stream>>>(XN, SQ, DIST);
  k_knn<<<4096, 64, 0, stream>>>(DIST, KNNI);
  // 4. P/Q MFMA (overwrites DIST) ; 5-6. edge BN ; 7. apply -> X16
  k_pqm<<<dim3(16, 4, 8), 256, 0, stream>>>(XR, WPQ, PM, QM);
  k_edge_stats<<<dim3(16, 4, 2), 256, 0, stream>>>(PM, QM, KNNI, STATS);
  k_edge_fin<<<2, 256, 0, stream>>>(STATS, gna, bta, gnb, btb, ABE);
  k_edge_apply<<<dim3(1024, 4), 256, 0, stream>>>(PM, QM, KNNI, ABE, X16);
  // 8. f+g conv (bf16 raw m-major) and h conv (bf16 raw ch-major)
  k_convm<5, 2, 1, false><<<dim3(64, 2, 4), 256, 0, stream>>>(X16, W16 + W16_FG, BIAS + B_FG, nullptr, FGR, 64, 0);
  k_convm<5, 3, 3, false><<<dim3(64, 3, 4), 256, 0, stream>>>(X16, W16 + W16_H, BIAS + B_H, nullptr, HBR, 0, 144);
  // 9. BN stats + apply (bf16-native, H in place)
  k_fgstats<<<64, 256, 0, stream>>>(FGR, FGP);
  k_fgfin<<<1, 64, 0, stream>>>(FGP, gf, bef, gg, beg, ABFG);
  k_bnstatsH<<<130, 256, 0, stream>>>(HBR, gh, beh, ABH);
  k_applyFG<<<512, 256, 0, stream>>>(FGR, ABFG, FGT);
  k_applyH<<<1152, 256, 0, stream>>>(HBR, ABH);
  // 10. LSE ; 11. O-pass (pipelined) ; 12. reduce -> A16
  k_zlse<<<dim3(64, 4, 4), 256, 0, stream>>>(FGT, LSEP);
  k_lsered<<<64, 256, 0, stream>>>(LSEP, LSEB);
  k_omfma<<<dim3(32, 4, 6), 256, 0, stream>>>(FGT, HBR, LSEB, OP16);
  k_ored<<<1280, 256, 0, stream>>>(OP16, X16, gamma, A16);
  // 13-14. final convs (MFMA)
  k_convm<5, 8, 1, true><<<dim3(64, 2, 4), 256, 0, stream>>>(A16, W16 + W16_C1, BIAS + B_C1, nullptr, Y1, 256, 0);
  k_convm<8, 4, 2, true><<<dim3(64, 2, 4), 256, 0, stream>>>(Y1, W16 + W16_C2, BIAS + B_C2, out, nullptr, 0, 128);
}